// Round 1
// baseline (3962.960 us; speedup 1.0000x reference)
//
#include <hip/hip_runtime.h>

// ---------------- constants ----------------
__constant__ float c_lo[8] = {-0.010597401784997278f, 0.032883011666982945f,
                              0.030841381835986965f, -0.18703481171888114f,
                              -0.02798376941698385f, 0.6308807679295904f,
                              0.7148465705525415f,  0.23037781330885523f};
__constant__ float c_hi[8] = {-0.23037781330885523f, 0.7148465705525415f,
                              -0.6308807679295904f, -0.02798376941698385f,
                              0.18703481171888114f, 0.030841381835986965f,
                              -0.032883011666982945f, -0.010597401784997278f};

// ---------------- 1x1 conv (GEMM): out[b,co,n] = bias[co] + sum_ci W[co,ci]*in[b,ci,n]
__global__ __launch_bounds__(256) void conv1x1_k(
    const float* __restrict__ in, long inB,
    const float* __restrict__ W, int ldw,
    const float* __restrict__ bias,
    float* __restrict__ out, long outB,
    int Cin, int N)
{
    __shared__ float xs[64 * 64];
    __shared__ float ws[64 * 68];
    const int n0 = blockIdx.x * 64, co0 = blockIdx.y * 64, b = blockIdx.z;
    const int tid = threadIdx.x;
    const int tn = tid & 15, tco = tid >> 4;
    const int r = tid >> 6, c = tid & 63;
    const float* inb = in + (long)b * inB;
    float acc[4][4] = {};
    for (int c0 = 0; c0 < Cin; c0 += 64) {
        __syncthreads();
        #pragma unroll
        for (int rr = 0; rr < 64; rr += 4) {
            xs[(rr + r) * 64 + c] = inb[(long)(c0 + rr + r) * N + n0 + c];
            ws[c * 68 + rr + r]   = W[(long)(co0 + rr + r) * ldw + c0 + c];
        }
        __syncthreads();
        #pragma unroll 4
        for (int ci = 0; ci < 64; ++ci) {
            const float4 x4 = *(const float4*)&xs[ci * 64 + tn * 4];
            const float4 w4 = *(const float4*)&ws[ci * 68 + tco * 4];
            acc[0][0] += w4.x * x4.x; acc[0][1] += w4.x * x4.y; acc[0][2] += w4.x * x4.z; acc[0][3] += w4.x * x4.w;
            acc[1][0] += w4.y * x4.x; acc[1][1] += w4.y * x4.y; acc[1][2] += w4.y * x4.z; acc[1][3] += w4.y * x4.w;
            acc[2][0] += w4.z * x4.x; acc[2][1] += w4.z * x4.y; acc[2][2] += w4.z * x4.z; acc[2][3] += w4.z * x4.w;
            acc[3][0] += w4.w * x4.x; acc[3][1] += w4.w * x4.y; acc[3][2] += w4.w * x4.z; acc[3][3] += w4.w * x4.w;
        }
    }
    float* outb = out + (long)b * outB + n0 + tn * 4;
    #pragma unroll
    for (int i = 0; i < 4; ++i) {
        const int co = co0 + tco * 4 + i;
        const float bb = bias[co];
        float4 v;
        v.x = acc[i][0] + bb; v.y = acc[i][1] + bb; v.z = acc[i][2] + bb; v.w = acc[i][3] + bb;
        *(float4*)&outb[(long)co * N] = v;
    }
}

// ---------------- branch conv: K taps, same padding; Cin=Cout=128
__global__ __launch_bounds__(256) void branch_conv_k(
    const float* __restrict__ in, long inB,
    const float* __restrict__ W,   // (128,128,K)
    const float* __restrict__ bias,
    float* __restrict__ out, long outB,
    int N, int K, int pad)
{
    __shared__ float xs[64 * 72];
    __shared__ float ws[64 * 68];
    const int n0 = blockIdx.x * 64, co0 = blockIdx.y * 64, b = blockIdx.z;
    const int tid = threadIdx.x;
    const int tn = tid & 15, tco = tid >> 4;
    const int r = tid >> 6, c = tid & 63;
    const float* inb = in + (long)b * inB;
    const int Cin = 128;
    float acc[4][4] = {};
    for (int c0 = 0; c0 < Cin; c0 += 64) {
        for (int k = 0; k < K; ++k) {
            __syncthreads();
            if (k == 0) {
                const int Wd = 64 + 2 * pad;
                for (int rr = 0; rr < 64; rr += 4) {
                    for (int cc = c; cc < Wd; cc += 64) {
                        int n = n0 + cc - pad;
                        xs[(rr + r) * 72 + cc] =
                            (n >= 0 && n < N) ? inb[(long)(c0 + rr + r) * N + n] : 0.0f;
                    }
                }
            }
            #pragma unroll
            for (int rr = 0; rr < 64; rr += 4)
                ws[c * 68 + rr + r] = W[((long)(co0 + rr + r) * Cin + c0 + c) * K + k];
            __syncthreads();
            #pragma unroll 4
            for (int ci = 0; ci < 64; ++ci) {
                const float4 w4 = *(const float4*)&ws[ci * 68 + tco * 4];
                const float* xrow = &xs[ci * 72 + tn * 4 + k];
                const float x0 = xrow[0], x1 = xrow[1], x2 = xrow[2], x3 = xrow[3];
                acc[0][0] += w4.x * x0; acc[0][1] += w4.x * x1; acc[0][2] += w4.x * x2; acc[0][3] += w4.x * x3;
                acc[1][0] += w4.y * x0; acc[1][1] += w4.y * x1; acc[1][2] += w4.y * x2; acc[1][3] += w4.y * x3;
                acc[2][0] += w4.z * x0; acc[2][1] += w4.z * x1; acc[2][2] += w4.z * x2; acc[2][3] += w4.z * x3;
                acc[3][0] += w4.w * x0; acc[3][1] += w4.w * x1; acc[3][2] += w4.w * x2; acc[3][3] += w4.w * x3;
            }
        }
    }
    float* outb = out + (long)b * outB + n0 + tn * 4;
    #pragma unroll
    for (int i = 0; i < 4; ++i) {
        const int co = co0 + tco * 4 + i;
        const float bb = bias[co];
        float4 v;
        v.x = acc[i][0] + bb; v.y = acc[i][1] + bb; v.z = acc[i][2] + bb; v.w = acc[i][3] + bb;
        *(float4*)&outb[(long)co * N] = v;
    }
}

// ---------------- BN stats: one block per channel; t is (64, C, N)
__global__ __launch_bounds__(256) void bn_stats_k(
    const float* __restrict__ t, float* __restrict__ stats, int C, int N)
{
    const int c = blockIdx.x, tid = threadIdx.x;
    __shared__ float sbuf[256], qbuf[256];
    float s = 0.f, q = 0.f;
    for (int i = tid; i < 64 * 1024; i += 256) {
        int b = i >> 10, n = i & 1023;
        float v = t[((long)b * C + c) * N + n];
        s += v; q += v * v;
    }
    sbuf[tid] = s; qbuf[tid] = q;
    __syncthreads();
    for (int off = 128; off > 0; off >>= 1) {
        if (tid < off) { sbuf[tid] += sbuf[tid + off]; qbuf[tid] += qbuf[tid + off]; }
        __syncthreads();
    }
    if (tid == 0) {
        const float inv = 1.0f / 65536.0f;
        float mu = sbuf[0] * inv;
        float var = qbuf[0] * inv - mu * mu;
        stats[c] = mu;
        stats[C + c] = rsqrtf(var + 1e-5f);
    }
}

// ---------------- BN apply + ReLU (in place); t is (64,128,1024)
__global__ __launch_bounds__(256) void bn_apply_k(
    float* __restrict__ t, const float* __restrict__ stats,
    const float* __restrict__ g, const float* __restrict__ be)
{
    long i = (long)blockIdx.x * 256 + threadIdx.x;
    int c = (int)((i >> 10) & 127);
    float v = (t[i] - stats[c]) * stats[128 + c] * g[c] + be[c];
    t[i] = v > 0.f ? v : 0.f;
}

// ---------------- DWT: a[m] = sum_j x_sym[2m+1-j]*LO[j]; d likewise with HI
__global__ __launch_bounds__(256) void dwt_k(
    const float* __restrict__ x, float* __restrict__ a, float* __restrict__ d,
    int n_in, int n_out)
{
    const int row = blockIdx.y;
    const int m = blockIdx.x * 256 + threadIdx.x;
    if (m >= n_out) return;
    const float* xr = x + (long)row * n_in;
    float sa = 0.f, sd = 0.f;
    #pragma unroll
    for (int j = 0; j < 8; ++j) {
        int t = 2 * m + 1 - j;
        t = (t < 0) ? (-t - 1) : t;
        t = (t >= n_in) ? (2 * n_in - 1 - t) : t;
        const float v = xr[t];
        sa += v * c_lo[j];
        sd += v * c_hi[j];
    }
    a[(long)row * n_out + m] = sa;
    d[(long)row * n_out + m] = sd;
}

// ---------------- IDWT (zero-stuffed transposed conv + slice)
// z[m] = sum_{k: (m+k-1) even, j=(m+k-1)/2 in [0,nc)} LO[k]*lo[j] + HI[k]*hi[j]
__global__ __launch_bounds__(256) void idwt_k(
    const float* __restrict__ lo, const float* __restrict__ hi,
    float* __restrict__ z, int nc, int n_out, long zB, int zN)
{
    const int row = blockIdx.y;
    const int m = blockIdx.x * 256 + threadIdx.x;
    if (m >= n_out) return;
    const float* lor = lo ? lo + (long)row * nc : nullptr;
    const float* hir = hi ? hi + (long)row * nc : nullptr;
    float s = 0.f;
    #pragma unroll
    for (int k = 0; k < 8; ++k) {
        int t = m + k - 1;
        if (t & 1) continue;
        int j = t >> 1;
        if (j >= nc) continue;
        if (lor) s += c_lo[k] * lor[j];
        if (hir) s += c_hi[k] * hir[j];
    }
    z[(long)(row >> 7) * zB + (long)(row & 127) * zN + m] = s;
}

// ---------------- branch prefix (shorts) / suffix (longs) sums, in place
__global__ __launch_bounds__(256) void cumsum_k(
    float* __restrict__ S, float* __restrict__ L, int N)
{
    long i = (long)blockIdx.x * 256 + threadIdx.x;   // over 64*128*1024
    int b = (int)(i >> 17);
    int c = (int)((i >> 10) & 127);
    int n = (int)(i & 1023);
    long base = ((long)b * 512 + c) * N + n;
    const long st = 128L * N;
    float s0 = S[base], s1 = S[base + st], s2 = S[base + 2 * st], s3 = S[base + 3 * st];
    S[base + st] = s1 + s0;
    S[base + 2 * st] = s2 + s1 + s0;
    S[base + 3 * st] = s3 + s2 + s1 + s0;
    float l0 = L[base], l1 = L[base + st], l2 = L[base + 2 * st], l3 = L[base + 3 * st];
    L[base + 2 * st] = l2 + l3;
    L[base + st] = l1 + l2 + l3;
    L[base] = l0 + l1 + l2 + l3;
}

// ---------------- precompute fused weights: US/UL[co, 128*br+c] = sum_q wfus[co,128br+q]*wpf[q, c or 128+c]
__global__ __launch_bounds__(256) void make_U_k(
    const float* __restrict__ wf, const float* __restrict__ wp,
    float* __restrict__ US, float* __restrict__ UL)
{
    int idx = blockIdx.x * 256 + threadIdx.x;     // 512*512
    int co = idx >> 9, c = idx & 511;
    int br = c >> 7, cc = c & 127;
    float s = 0.f, l = 0.f;
    for (int q = 0; q < 128; ++q) {
        float f = wf[(long)co * 512 + br * 128 + q];
        s += f * wp[q * 256 + cc];
        l += f * wp[q * 256 + 128 + cc];
    }
    US[(long)co * 512 + c] = s;
    UL[(long)co * 512 + c] = l;
}

__global__ __launch_bounds__(256) void make_bias2_k(
    const float* __restrict__ wf, const float* __restrict__ bpf,
    const float* __restrict__ bfus, float* __restrict__ b2)
{
    int co = blockIdx.x * 256 + threadIdx.x;
    if (co >= 512) return;
    float s = bfus[co];
    for (int j = 0; j < 512; ++j) s += wf[(long)co * 512 + j] * bpf[j & 127];
    b2[co] = s;
}

// ---------------- fused pf+fus output GEMM (1024 inputs) + bias2 + identity
__global__ __launch_bounds__(256) void fused_out_k(
    const float* __restrict__ S, const float* __restrict__ Lg,
    const float* __restrict__ US, const float* __restrict__ UL,
    const float* __restrict__ bias2, const float* __restrict__ x,
    float* __restrict__ out, int N)
{
    __shared__ float xs[64 * 64];
    __shared__ float ws[64 * 68];
    const int n0 = blockIdx.x * 64, co0 = blockIdx.y * 64, b = blockIdx.z;
    const int tid = threadIdx.x;
    const int tn = tid & 15, tco = tid >> 4;
    const int r = tid >> 6, c = tid & 63;
    float acc[4][4] = {};
    for (int pass = 0; pass < 2; ++pass) {
        const float* in = pass ? Lg : S;
        const float* W  = pass ? UL : US;
        const float* inb = in + (long)b * 512 * N;
        for (int c0 = 0; c0 < 512; c0 += 64) {
            __syncthreads();
            #pragma unroll
            for (int rr = 0; rr < 64; rr += 4) {
                xs[(rr + r) * 64 + c] = inb[(long)(c0 + rr + r) * N + n0 + c];
                ws[c * 68 + rr + r]   = W[(long)(co0 + rr + r) * 512 + c0 + c];
            }
            __syncthreads();
            #pragma unroll 4
            for (int ci = 0; ci < 64; ++ci) {
                const float4 x4 = *(const float4*)&xs[ci * 64 + tn * 4];
                const float4 w4 = *(const float4*)&ws[ci * 68 + tco * 4];
                acc[0][0] += w4.x * x4.x; acc[0][1] += w4.x * x4.y; acc[0][2] += w4.x * x4.z; acc[0][3] += w4.x * x4.w;
                acc[1][0] += w4.y * x4.x; acc[1][1] += w4.y * x4.y; acc[1][2] += w4.y * x4.z; acc[1][3] += w4.y * x4.w;
                acc[2][0] += w4.z * x4.x; acc[2][1] += w4.z * x4.y; acc[2][2] += w4.z * x4.z; acc[2][3] += w4.z * x4.w;
                acc[3][0] += w4.w * x4.x; acc[3][1] += w4.w * x4.y; acc[3][2] += w4.w * x4.z; acc[3][3] += w4.w * x4.w;
            }
        }
    }
    const float* xb = x + (long)b * 512 * N + n0 + tn * 4;
    float* outb = out + (long)b * 512 * N + n0 + tn * 4;
    #pragma unroll
    for (int i = 0; i < 4; ++i) {
        const int co = co0 + tco * 4 + i;
        const float bb = bias2[co];
        const float4 xv = *(const float4*)&xb[(long)co * N];
        float4 v;
        v.x = acc[i][0] + bb + xv.x; v.y = acc[i][1] + bb + xv.y;
        v.z = acc[i][2] + bb + xv.z; v.w = acc[i][3] + bb + xv.w;
        *(float4*)&outb[(long)co * N] = v;
    }
}

extern "C" void kernel_launch(void* const* d_in, const int* in_sizes, int n_in,
                              void* d_out, int out_size, void* d_ws, size_t ws_size,
                              hipStream_t stream)
{
    const float* x      = (const float*)d_in[0];
    const float* w_init = (const float*)d_in[1];
    const float* b_init = (const float*)d_in[2];
    const float* w_pf   = (const float*)d_in[3];
    const float* b_pf   = (const float*)d_in[4];
    const float* w_fus  = (const float*)d_in[5];
    const float* b_fus  = (const float*)d_in[6];
    const float *w_b[4], *b_b[4], *g_b[4], *be_b[4];
    for (int i = 0; i < 4; ++i) {
        w_b[i]  = (const float*)d_in[7 + 4 * i];
        b_b[i]  = (const float*)d_in[8 + 4 * i];
        g_b[i]  = (const float*)d_in[9 + 4 * i];
        be_b[i] = (const float*)d_in[10 + 4 * i];
    }
    float* ws = (float*)d_ws;
    float* h   = ws;
    float* Sb  = h   + 33554432L;
    float* Lb  = Sb  + 33554432L;
    float* t   = Lb  + 33554432L;
    float* a1  = t   + 8388608L;
    float* d1  = a1  + 4218880L;
    float* a2  = d1  + 4218880L;
    float* d2  = a2  + 2138112L;
    float* la1 = d2  + 2138112L;
    float* sa1 = la1 + 4218880L;
    float* US  = sa1 + 4218880L;
    float* UL  = US  + 262144L;
    float* b2  = UL  + 262144L;
    float* st  = b2  + 512L;
    float* outf = (float*)d_out;

    const int KS_[4] = {3, 5, 7, 9};
    const int N = 1024;

    make_U_k<<<1024, 256, 0, stream>>>(w_fus, w_pf, US, UL);
    make_bias2_k<<<2, 256, 0, stream>>>(w_fus, b_pf, b_fus, b2);
    conv1x1_k<<<dim3(16, 8, 64), 256, 0, stream>>>(x, 512L * N, w_init, 512, b_init,
                                                   h, 512L * N, 512, N);
    for (int br = 0; br < 4; ++br) {
        const int K = KS_[br], pad = K / 2;
        branch_conv_k<<<dim3(16, 2, 64), 256, 0, stream>>>(
            h + (long)128 * br * N, 512L * N, w_b[br], b_b[br], t, 128L * N, N, K, pad);
        bn_stats_k<<<128, 256, 0, stream>>>(t, st, 128, N);
        bn_apply_k<<<32768, 256, 0, stream>>>(t, st, g_b[br], be_b[br]);
        dwt_k<<<dim3(3, 8192), 256, 0, stream>>>(t, a1, d1, 1024, 515);
        dwt_k<<<dim3(2, 8192), 256, 0, stream>>>(a1, a2, d2, 515, 261);
        idwt_k<<<dim3(3, 8192), 256, 0, stream>>>(a2, nullptr, la1, 261, 515, 128L * 515, 515);
        idwt_k<<<dim3(3, 8192), 256, 0, stream>>>(nullptr, d2, sa1, 261, 515, 128L * 515, 515);
        idwt_k<<<dim3(4, 8192), 256, 0, stream>>>(la1, nullptr, Lb + (long)128 * br * N, 515, 1024, 512L * N, N);
        idwt_k<<<dim3(4, 8192), 256, 0, stream>>>(sa1, d1, Sb + (long)128 * br * N, 515, 1024, 512L * N, N);
    }
    cumsum_k<<<32768, 256, 0, stream>>>(Sb, Lb, N);
    fused_out_k<<<dim3(16, 8, 64), 256, 0, stream>>>(Sb, Lb, US, UL, b2, x, outf, N);
}

// Round 3
// 683.542 us; speedup vs baseline: 5.7977x; 5.7977x over previous
//
#include <hip/hip_runtime.h>

typedef float  f32x4 __attribute__((ext_vector_type(4)));
typedef short  s16x8 __attribute__((ext_vector_type(8)));
typedef short  s16x4 __attribute__((ext_vector_type(4)));
typedef unsigned short u16;

// ---------------- db4 filters ----------------
__constant__ float c_lo[8] = {-0.010597401784997278f, 0.032883011666982945f,
                              0.030841381835986965f, -0.18703481171888114f,
                              -0.02798376941698385f, 0.6308807679295904f,
                              0.7148465705525415f,  0.23037781330885523f};
__constant__ float c_hi[8] = {-0.23037781330885523f, 0.7148465705525415f,
                              -0.6308807679295904f, -0.02798376941698385f,
                              0.18703481171888114f, 0.030841381835986965f,
                              -0.032883011666982945f, -0.010597401784997278f};

__device__ __forceinline__ u16 f2bf(float f) {
    unsigned u = __float_as_uint(f);
    u += 0x7fffu + ((u >> 16) & 1u);
    return (u16)(u >> 16);
}
__device__ __forceinline__ float bf2f(u16 h) {
    return __uint_as_float(((unsigned)h) << 16);
}
__device__ __forceinline__ int lds_chunk(int row, int g) {
    return row * 4 + (g ^ ((row >> 1) & 3));
}

// ================= generic NT MFMA GEMM =================
// D[i][j] = sum_k A[i][k]*B[j][k]; store bf16 at D + bb*dB + j*dj + i (+bias[i])
__global__ __launch_bounds__(256) void gemm_nt_k(
    const u16* __restrict__ A, long aB, int lda,
    const u16* __restrict__ B, long bB, int ldb,
    int K,
    u16* __restrict__ D, long dB, int dj,
    const float* __restrict__ bias)
{
    __shared__ s16x8 As[512];
    __shared__ s16x8 Bs[512];
    const int j0 = blockIdx.x * 128, i0 = blockIdx.y * 128;
    const long bb = blockIdx.z;
    const u16* Ab = A + bb * aB;
    const u16* Bb = B + bb * bB;
    const int tid = threadIdx.x;
    const int srow = tid >> 2, sg = tid & 3;
    const int l = tid & 63, w = tid >> 6;
    const int wi = (w >> 1) * 64, wj = (w & 1) * 64;
    const int lr = l & 15, lg = l >> 4;
    f32x4 acc[4][4] = {};
    for (int k0 = 0; k0 < K; k0 += 32) {
        __syncthreads();
        #pragma unroll
        for (int it = 0; it < 2; ++it) {
            int row = srow + it * 64;
            As[lds_chunk(row, sg)] = *(const s16x8*)(Ab + (long)(i0 + row) * lda + k0 + sg * 8);
            Bs[lds_chunk(row, sg)] = *(const s16x8*)(Bb + (long)(j0 + row) * ldb + k0 + sg * 8);
        }
        __syncthreads();
        s16x8 af[4], bf[4];
        #pragma unroll
        for (int f = 0; f < 4; ++f) {
            af[f] = As[lds_chunk(wi + f * 16 + lr, lg)];
            bf[f] = Bs[lds_chunk(wj + f * 16 + lr, lg)];
        }
        #pragma unroll
        for (int fi = 0; fi < 4; ++fi)
            #pragma unroll
            for (int fj = 0; fj < 4; ++fj)
                acc[fi][fj] = __builtin_amdgcn_mfma_f32_16x16x32_bf16(af[fi], bf[fj], acc[fi][fj], 0, 0, 0);
    }
    u16* Db = D + bb * dB;
    #pragma unroll
    for (int fi = 0; fi < 4; ++fi) {
        const int i = i0 + wi + fi * 16 + lg * 4;
        float b0 = 0, b1 = 0, b2v = 0, b3 = 0;
        if (bias) { b0 = bias[i]; b1 = bias[i + 1]; b2v = bias[i + 2]; b3 = bias[i + 3]; }
        #pragma unroll
        for (int fj = 0; fj < 4; ++fj) {
            const int j = j0 + wj + fj * 16 + lr;
            f32x4 d = acc[fi][fj];
            s16x4 o;
            o[0] = (short)f2bf(d[0] + b0); o[1] = (short)f2bf(d[1] + b1);
            o[2] = (short)f2bf(d[2] + b2v); o[3] = (short)f2bf(d[3] + b3);
            *(s16x4*)(Db + (long)j * dj + i) = o;
        }
    }
}

// ================= branch conv (im2col over taps) =================
// D[co][n] = sum_tap sum_ci Wp[co][tap*128+ci] * H[n+tap-pad][ci]
__global__ __launch_bounds__(256) void gemm_branch_k(
    const u16* __restrict__ Wp, int taps, int pad,
    const u16* __restrict__ H, long hB,
    u16* __restrict__ D, long dB)
{
    __shared__ s16x8 As[512];
    __shared__ s16x8 Bs[512];
    const int j0 = blockIdx.x * 128;
    const long bb = blockIdx.z;
    const u16* Hb = H + bb * hB;
    const int tid = threadIdx.x;
    const int srow = tid >> 2, sg = tid & 3;
    const int l = tid & 63, w = tid >> 6;
    const int wi = (w >> 1) * 64, wj = (w & 1) * 64;
    const int lr = l & 15, lg = l >> 4;
    const int lda = taps * 128;
    const int K = taps * 128;
    f32x4 acc[4][4] = {};
    for (int k0 = 0; k0 < K; k0 += 32) {
        const int tap = k0 >> 7, kc = k0 & 127;
        const int shift = tap - pad;
        __syncthreads();
        #pragma unroll
        for (int it = 0; it < 2; ++it) {
            int row = srow + it * 64;
            As[lds_chunk(row, sg)] = *(const s16x8*)(Wp + (long)row * lda + k0 + sg * 8);
            int n = j0 + row + shift;
            s16x8 v = {0, 0, 0, 0, 0, 0, 0, 0};
            if (n >= 0 && n < 1024)
                v = *(const s16x8*)(Hb + (long)n * 512 + kc + sg * 8);
            Bs[lds_chunk(row, sg)] = v;
        }
        __syncthreads();
        s16x8 af[4], bf[4];
        #pragma unroll
        for (int f = 0; f < 4; ++f) {
            af[f] = As[lds_chunk(wi + f * 16 + lr, lg)];
            bf[f] = Bs[lds_chunk(wj + f * 16 + lr, lg)];
        }
        #pragma unroll
        for (int fi = 0; fi < 4; ++fi)
            #pragma unroll
            for (int fj = 0; fj < 4; ++fj)
                acc[fi][fj] = __builtin_amdgcn_mfma_f32_16x16x32_bf16(af[fi], bf[fj], acc[fi][fj], 0, 0, 0);
    }
    u16* Db = D + bb * dB;
    #pragma unroll
    for (int fi = 0; fi < 4; ++fi) {
        const int i = wi + fi * 16 + lg * 4;
        #pragma unroll
        for (int fj = 0; fj < 4; ++fj) {
            const int j = j0 + wj + fj * 16 + lr;
            f32x4 d = acc[fi][fj];
            s16x4 o;
            o[0] = (short)f2bf(d[0]); o[1] = (short)f2bf(d[1]);
            o[2] = (short)f2bf(d[2]); o[3] = (short)f2bf(d[3]);
            *(s16x4*)(Db + (long)j * 512 + i) = o;
        }
    }
}

// ================= time-axis GEMM (band-limited, dual pass, f32 out) =================
// out[bb][co=j][n=i] = b2[j] + x[..] + sum_m MS[i][m]*PS[bb][j][m] + ML[i][m]*PL[bb][j][m]
__global__ __launch_bounds__(256) void gemm_time_k(
    const u16* __restrict__ MS, const u16* __restrict__ ML,
    const u16* __restrict__ PS, const u16* __restrict__ PL,
    const float* __restrict__ b2, const float* __restrict__ X,
    float* __restrict__ OUT)
{
    __shared__ s16x8 As[512];
    __shared__ s16x8 Bs[512];
    const int j0 = blockIdx.x * 128;   // co tile
    const int i0 = blockIdx.y * 128;   // n tile
    const long bb = blockIdx.z;
    const int tid = threadIdx.x;
    const int srow = tid >> 2, sg = tid & 3;
    const int l = tid & 63, w = tid >> 6;
    const int wi = (w >> 1) * 64, wj = (w & 1) * 64;
    const int lr = l & 15, lg = l >> 4;
    const int klo = (i0 - 96) > 0 ? (i0 - 96) : 0;
    const int khi = (i0 + 224) < 1024 ? (i0 + 224) : 1024;
    f32x4 acc[4][4] = {};
    for (int pass = 0; pass < 2; ++pass) {
        const u16* A = pass ? ML : MS;
        const u16* B = (pass ? PL : PS) + bb * 524288;
        for (int k0 = klo; k0 < khi; k0 += 32) {
            __syncthreads();
            #pragma unroll
            for (int it = 0; it < 2; ++it) {
                int row = srow + it * 64;
                As[lds_chunk(row, sg)] = *(const s16x8*)(A + (long)(i0 + row) * 1024 + k0 + sg * 8);
                Bs[lds_chunk(row, sg)] = *(const s16x8*)(B + (long)(j0 + row) * 1024 + k0 + sg * 8);
            }
            __syncthreads();
            s16x8 af[4], bf[4];
            #pragma unroll
            for (int f = 0; f < 4; ++f) {
                af[f] = As[lds_chunk(wi + f * 16 + lr, lg)];
                bf[f] = Bs[lds_chunk(wj + f * 16 + lr, lg)];
            }
            #pragma unroll
            for (int fi = 0; fi < 4; ++fi)
                #pragma unroll
                for (int fj = 0; fj < 4; ++fj)
                    acc[fi][fj] = __builtin_amdgcn_mfma_f32_16x16x32_bf16(af[fi], bf[fj], acc[fi][fj], 0, 0, 0);
        }
    }
    float* Ob = OUT + bb * 524288;
    const float* Xb = X + bb * 524288;
    #pragma unroll
    for (int fi = 0; fi < 4; ++fi) {
        const int i = i0 + wi + fi * 16 + lg * 4;
        #pragma unroll
        for (int fj = 0; fj < 4; ++fj) {
            const int j = j0 + wj + fj * 16 + lr;
            const long a = (long)j * 1024 + i;
            f32x4 d = acc[fi][fj];
            const float bj = b2[j];
            f32x4 xv = *(const f32x4*)(Xb + a);
            f32x4 o;
            o[0] = d[0] + bj + xv[0]; o[1] = d[1] + bj + xv[1];
            o[2] = d[2] + bj + xv[2]; o[3] = d[3] + bj + xv[3];
            *(f32x4*)(Ob + a) = o;
        }
    }
}

// ================= packing / small kernels =================
__global__ __launch_bounds__(256) void cast_bf_k(const float* __restrict__ s, u16* __restrict__ d, int n)
{
    int i = blockIdx.x * 256 + threadIdx.x;
    if (i < n) d[i] = f2bf(s[i]);
}

// d[co*(taps*128) + tap*128 + ci] = s[(co*128+ci)*taps + tap]   (w_b is (co,ci,tap))
__global__ __launch_bounds__(256) void pack_wb2_k(const float* __restrict__ s, u16* __restrict__ d, int taps)
{
    int i = blockIdx.x * 256 + threadIdx.x;
    if (i >= taps * 16384) return;
    int stride = taps * 128;
    int co = i / stride;
    int rem = i - co * stride;
    int tap = rem >> 7, ci = rem & 127;
    d[i] = f2bf(s[(long)(co * 128 + ci) * taps + tap]);
}

// USc[co][128b+cc] = suffix-sum_b of (wfus_b . wpf_S); ULc = prefix-sum of (wfus_b . wpf_L)
__global__ __launch_bounds__(256) void make_Ucum_k(
    const float* __restrict__ wf, const float* __restrict__ wp,
    u16* __restrict__ USc, u16* __restrict__ ULc)
{
    int gid = blockIdx.x * 256 + threadIdx.x;   // 512*128
    int co = gid >> 7, cc = gid & 127;
    float us[4], ul[4];
    #pragma unroll
    for (int b = 0; b < 4; ++b) {
        float s = 0.f, t = 0.f;
        for (int q = 0; q < 128; ++q) {
            float f = wf[(long)co * 512 + b * 128 + q];
            s += f * wp[q * 256 + cc];
            t += f * wp[q * 256 + 128 + cc];
        }
        us[b] = s; ul[b] = t;
    }
    float suf = 0.f;
    for (int b = 3; b >= 0; --b) { suf += us[b]; USc[(long)co * 512 + b * 128 + cc] = f2bf(suf); }
    float pre = 0.f;
    for (int b = 0; b < 4; ++b) { pre += ul[b]; ULc[(long)co * 512 + b * 128 + cc] = f2bf(pre); }
}

__global__ __launch_bounds__(256) void make_bias2_k(
    const float* __restrict__ wf, const float* __restrict__ bpf,
    const float* __restrict__ bfus, float* __restrict__ b2)
{
    int co = blockIdx.x * 256 + threadIdx.x;
    if (co >= 512) return;
    float s = bfus[co];
    for (int j = 0; j < 512; ++j) s += wf[(long)co * 512 + j] * bpf[j & 127];
    b2[co] = s;
}

__global__ __launch_bounds__(256) void eye_k(float* __restrict__ I)
{
    int i = blockIdx.x * 256 + threadIdx.x;
    I[i] = ((i >> 10) == (i & 1023)) ? 1.0f : 0.0f;
}

__global__ __launch_bounds__(256) void zero_k(float* __restrict__ p, int n)
{
    int i = blockIdx.x * 256 + threadIdx.x;
    if (i < n) p[i] = 0.f;
}

// ---------------- DWT / IDWT (f32, used only for M-build on identity) ----------------
__global__ __launch_bounds__(256) void dwt_k(
    const float* __restrict__ x, float* __restrict__ a, float* __restrict__ d,
    int n_in, int n_out)
{
    const int row = blockIdx.y;
    const int m = blockIdx.x * 256 + threadIdx.x;
    if (m >= n_out) return;
    const float* xr = x + (long)row * n_in;
    float sa = 0.f, sd = 0.f;
    #pragma unroll
    for (int j = 0; j < 8; ++j) {
        int t = 2 * m + 1 - j;
        t = (t < 0) ? (-t - 1) : t;
        t = (t >= n_in) ? (2 * n_in - 1 - t) : t;
        const float v = xr[t];
        sa += v * c_lo[j];
        sd += v * c_hi[j];
    }
    a[(long)row * n_out + m] = sa;
    d[(long)row * n_out + m] = sd;
}

__global__ __launch_bounds__(256) void idwt_k(
    const float* __restrict__ lo, const float* __restrict__ hi,
    float* __restrict__ z, int nc, int n_out, long zB, int zN)
{
    const int row = blockIdx.y;
    const int m = blockIdx.x * 256 + threadIdx.x;
    if (m >= n_out) return;
    const float* lor = lo ? lo + (long)row * nc : nullptr;
    const float* hir = hi ? hi + (long)row * nc : nullptr;
    float s = 0.f;
    #pragma unroll
    for (int k = 0; k < 8; ++k) {
        int t = m + k - 1;
        if (t & 1) continue;
        int j = t >> 1;
        if (j >= nc) continue;
        if (lor) s += c_lo[k] * lor[j];
        if (hir) s += c_hi[k] * hir[j];
    }
    z[(long)(row >> 7) * zB + (long)(row & 127) * zN + m] = s;
}

// ---------------- transposes ----------------
// MrowS[n][m] = bf16(Sid[m][n]); z-dim picks (Sid->MrowS) or (Lid->MrowL)
__global__ __launch_bounds__(256) void trM_k(
    const float* __restrict__ S, const float* __restrict__ L,
    u16* __restrict__ MS, u16* __restrict__ ML)
{
    __shared__ float sh[32][33];
    const float* src = blockIdx.z ? L : S;
    u16* dst = blockIdx.z ? ML : MS;
    const int n0 = blockIdx.x * 32, m0 = blockIdx.y * 32;
    const int tx = threadIdx.x, ty = threadIdx.y;
    #pragma unroll
    for (int k = 0; k < 4; ++k)
        sh[ty + 8 * k][tx] = src[(long)(m0 + ty + 8 * k) * 1024 + n0 + tx];
    __syncthreads();
    #pragma unroll
    for (int k = 0; k < 4; ++k)
        dst[(long)(n0 + ty + 8 * k) * 1024 + m0 + tx] = f2bf(sh[tx][ty + 8 * k]);
}

// xcl[bb][n][c] = bf16(x[bb][c][n])
__global__ __launch_bounds__(256) void trX_k(const float* __restrict__ x, u16* __restrict__ xcl)
{
    __shared__ float sh[32][33];
    const int n0 = blockIdx.x * 32, c0 = blockIdx.y * 32;
    const long bb = blockIdx.z;
    const int tx = threadIdx.x, ty = threadIdx.y;
    const float* xb = x + bb * 524288;
    u16* ob = xcl + bb * 524288;
    #pragma unroll
    for (int k = 0; k < 4; ++k)
        sh[ty + 8 * k][tx] = xb[(long)(c0 + ty + 8 * k) * 1024 + n0 + tx];
    __syncthreads();
    #pragma unroll
    for (int k = 0; k < 4; ++k)
        ob[(long)(n0 + ty + 8 * k) * 512 + c0 + tx] = f2bf(sh[tx][ty + 8 * k]);
}

// ---------------- BN ----------------
__global__ __launch_bounds__(256) void bn_stats_k(const u16* __restrict__ Y, float* __restrict__ st)
{
    __shared__ float ss[128][16];
    __shared__ float sq[128][16];
    const int t = threadIdx.x;
    const int chg = t & 15, rl = t >> 4;
    const long r0 = (long)blockIdx.x * 256;
    float s[8] = {}, q[8] = {};
    for (int k = 0; k < 16; ++k) {
        long r = r0 + rl + k * 16;
        s16x8 v = *(const s16x8*)(Y + r * 512 + chg * 8);
        #pragma unroll
        for (int e = 0; e < 8; ++e) { float f = bf2f((u16)v[e]); s[e] += f; q[e] += f * f; }
    }
    #pragma unroll
    for (int e = 0; e < 8; ++e) { ss[chg * 8 + e][rl] = s[e]; sq[chg * 8 + e][rl] = q[e]; }
    __syncthreads();
    if (t < 128) {
        float a = 0, b = 0;
        #pragma unroll
        for (int k = 0; k < 16; ++k) { a += ss[t][k]; b += sq[t][k]; }
        atomicAdd(st + t, a); atomicAdd(st + 128 + t, b);
    }
}

__global__ __launch_bounds__(256) void bn_apply_k(
    u16* __restrict__ Y, const float* __restrict__ st,
    const float* __restrict__ g, const float* __restrict__ be)
{
    __shared__ float sc[128];
    __shared__ float sh[128];
    const int t = threadIdx.x;
    if (t < 128) {
        float mu = st[t] * (1.0f / 65536.0f);
        float var = st[128 + t] * (1.0f / 65536.0f) - mu * mu;
        float rs = rsqrtf(var + 1e-5f);
        float a = rs * g[t];
        sc[t] = a; sh[t] = be[t] - mu * a;
    }
    __syncthreads();
    long gid = (long)blockIdx.x * 256 + t;
    long r = gid >> 4; int chg = (int)(gid & 15);
    u16* p = Y + r * 512 + chg * 8;
    s16x8 v = *(const s16x8*)p;
    #pragma unroll
    for (int e = 0; e < 8; ++e) {
        int c = chg * 8 + e;
        float f = bf2f((u16)v[e]) * sc[c] + sh[c];
        v[e] = (short)f2bf(f > 0.f ? f : 0.f);
    }
    *(s16x8*)p = v;
}

// =====================================================================
extern "C" void kernel_launch(void* const* d_in, const int* in_sizes, int n_in,
                              void* d_out, int out_size, void* d_ws, size_t ws_size,
                              hipStream_t stream)
{
    const float* x      = (const float*)d_in[0];
    const float* w_init = (const float*)d_in[1];
    const float* b_init = (const float*)d_in[2];
    const float* w_pf   = (const float*)d_in[3];
    const float* b_pf   = (const float*)d_in[4];
    const float* w_fus  = (const float*)d_in[5];
    const float* b_fus  = (const float*)d_in[6];
    const float *w_b[4], *g_b[4], *be_b[4];
    for (int i = 0; i < 4; ++i) {
        w_b[i]  = (const float*)d_in[7 + 4 * i];
        g_b[i]  = (const float*)d_in[9 + 4 * i];
        be_b[i] = (const float*)d_in[10 + 4 * i];
    }
    float* outf = (float*)d_out;

    char* p = (char*)d_ws;
    u16* xcl   = (u16*)p;  p += 67108864;
    u16* h     = (u16*)p;  p += 67108864;
    u16* Y     = (u16*)p;  p += 67108864;
    u16* PS    = (u16*)p;  p += 67108864;
    u16* PL    = (u16*)p;  p += 67108864;
    u16* Wi    = (u16*)p;  p += 524288;
    u16* Wp    = (u16*)p;  p += 786432;
    u16* USc   = (u16*)p;  p += 524288;
    u16* ULc   = (u16*)p;  p += 524288;
    u16* MrowS = (u16*)p;  p += 2097152;
    u16* MrowL = (u16*)p;  p += 2097152;
    float* eye = (float*)p; p += 4194304;
    float* Sid = (float*)p; p += 4194304;
    float* Lid = (float*)p; p += 4194304;
    float* a1  = (float*)p; p += 2109440;
    float* d1  = (float*)p; p += 2109440;
    float* a2  = (float*)p; p += 1069056;
    float* d2  = (float*)p; p += 1069056;
    float* la1 = (float*)p; p += 2109440;
    float* sa1 = (float*)p; p += 2109440;
    float* b2  = (float*)p; p += 2048;
    float* st  = (float*)p; p += 4096;

    const int KS_[4] = {3, 5, 7, 9};
    const long wpOff[4] = {0, 3 * 16384L, 8 * 16384L, 15 * 16384L};

    // ---- weight packing / fused-weight precompute ----
    cast_bf_k<<<1024, 256, 0, stream>>>(w_init, Wi, 262144);
    for (int br = 0; br < 4; ++br)
        pack_wb2_k<<<(KS_[br] * 16384 + 255) / 256, 256, 0, stream>>>(w_b[br], Wp + wpOff[br], KS_[br]);
    make_Ucum_k<<<256, 256, 0, stream>>>(w_fus, w_pf, USc, ULc);
    make_bias2_k<<<2, 256, 0, stream>>>(w_fus, b_pf, b_fus, b2);

    // ---- build wavelet operators M_S, M_L from identity ----
    eye_k<<<4096, 256, 0, stream>>>(eye);
    dwt_k<<<dim3(3, 1024), 256, 0, stream>>>(eye, a1, d1, 1024, 515);
    dwt_k<<<dim3(2, 1024), 256, 0, stream>>>(a1, a2, d2, 515, 261);
    idwt_k<<<dim3(3, 1024), 256, 0, stream>>>(a2, nullptr, la1, 261, 515, 65920, 515);
    idwt_k<<<dim3(3, 1024), 256, 0, stream>>>(nullptr, d2, sa1, 261, 515, 65920, 515);
    idwt_k<<<dim3(4, 1024), 256, 0, stream>>>(la1, nullptr, Lid, 515, 1024, 131072, 1024);
    idwt_k<<<dim3(4, 1024), 256, 0, stream>>>(sa1, d1, Sid, 515, 1024, 131072, 1024);
    trM_k<<<dim3(32, 32, 2), dim3(32, 8), 0, stream>>>(Sid, Lid, MrowS, MrowL);

    // ---- activations: transpose to channel-last bf16 ----
    trX_k<<<dim3(32, 16, 64), dim3(32, 8), 0, stream>>>(x, xcl);

    // ---- conv1x1: h[n][co] = Wi x + b_init ----
    gemm_nt_k<<<dim3(8, 4, 64), 256, 0, stream>>>(Wi, 0, 512, xcl, 524288, 512, 512,
                                                  h, 524288, 512, b_init);

    // ---- branches: conv(taps) -> BN(stats,apply)+ReLU, into Y ----
    zero_k<<<4, 256, 0, stream>>>(st, 1024);
    for (int br = 0; br < 4; ++br) {
        gemm_branch_k<<<dim3(8, 1, 64), 256, 0, stream>>>(
            Wp + wpOff[br], KS_[br], KS_[br] / 2, h + 128 * br, 524288, Y + 128 * br, 524288);
        bn_stats_k<<<256, 256, 0, stream>>>(Y + 128 * br, st + br * 256);
        bn_apply_k<<<4096, 256, 0, stream>>>(Y + 128 * br, st + br * 256, g_b[br], be_b[br]);
    }

    // ---- P_S = Y . USc^T ; P_L = Y . ULc^T (channel-first outputs) ----
    gemm_nt_k<<<dim3(4, 8, 64), 256, 0, stream>>>(Y, 524288, 512, USc, 0, 512, 512,
                                                  PS, 524288, 1024, nullptr);
    gemm_nt_k<<<dim3(4, 8, 64), 256, 0, stream>>>(Y, 524288, 512, ULc, 0, 512, 512,
                                                  PL, 524288, 1024, nullptr);

    // ---- out = M_S.PS^T + M_L.PL^T + b2 + x ----
    gemm_time_k<<<dim3(4, 8, 64), 256, 0, stream>>>(MrowS, MrowL, PS, PL, b2, x, outf);
}

// Round 4
// 606.356 us; speedup vs baseline: 6.5357x; 1.1273x over previous
//
#include <hip/hip_runtime.h>

typedef float  f32x4 __attribute__((ext_vector_type(4)));
typedef short  s16x8 __attribute__((ext_vector_type(8)));
typedef short  s16x4 __attribute__((ext_vector_type(4)));
typedef unsigned short u16;

struct PtrQuad { const float* p[4]; };

// ---------------- db4 filters ----------------
__constant__ float c_lo[8] = {-0.010597401784997278f, 0.032883011666982945f,
                              0.030841381835986965f, -0.18703481171888114f,
                              -0.02798376941698385f, 0.6308807679295904f,
                              0.7148465705525415f,  0.23037781330885523f};
__constant__ float c_hi[8] = {-0.23037781330885523f, 0.7148465705525415f,
                              -0.6308807679295904f, -0.02798376941698385f,
                              0.18703481171888114f, 0.030841381835986965f,
                              -0.032883011666982945f, -0.010597401784997278f};

__device__ __forceinline__ u16 f2bf(float f) {
    unsigned u = __float_as_uint(f);
    u += 0x7fffu + ((u >> 16) & 1u);
    return (u16)(u >> 16);
}
__device__ __forceinline__ float bf2f(u16 h) {
    return __uint_as_float(((unsigned)h) << 16);
}
__device__ __forceinline__ int lds_chunk(int row, int g) {
    return row * 4 + (g ^ ((row >> 1) & 3));
}

// ================= generic NT MFMA GEMM (used for conv1x1) =================
__global__ __launch_bounds__(256) void gemm_nt_k(
    const u16* __restrict__ A, long aB, int lda,
    const u16* __restrict__ B, long bB, int ldb,
    int K,
    u16* __restrict__ D, long dB, int dj,
    const float* __restrict__ bias)
{
    __shared__ s16x8 As[512];
    __shared__ s16x8 Bs[512];
    const int j0 = blockIdx.x * 128, i0 = blockIdx.y * 128;
    const long bb = blockIdx.z;
    const u16* Ab = A + bb * aB;
    const u16* Bb = B + bb * bB;
    const int tid = threadIdx.x;
    const int srow = tid >> 2, sg = tid & 3;
    const int l = tid & 63, w = tid >> 6;
    const int wi = (w >> 1) * 64, wj = (w & 1) * 64;
    const int lr = l & 15, lg = l >> 4;
    f32x4 acc[4][4] = {};
    for (int k0 = 0; k0 < K; k0 += 32) {
        __syncthreads();
        #pragma unroll
        for (int it = 0; it < 2; ++it) {
            int row = srow + it * 64;
            As[lds_chunk(row, sg)] = *(const s16x8*)(Ab + (long)(i0 + row) * lda + k0 + sg * 8);
            Bs[lds_chunk(row, sg)] = *(const s16x8*)(Bb + (long)(j0 + row) * ldb + k0 + sg * 8);
        }
        __syncthreads();
        s16x8 af[4], bf[4];
        #pragma unroll
        for (int f = 0; f < 4; ++f) {
            af[f] = As[lds_chunk(wi + f * 16 + lr, lg)];
            bf[f] = Bs[lds_chunk(wj + f * 16 + lr, lg)];
        }
        #pragma unroll
        for (int fi = 0; fi < 4; ++fi)
            #pragma unroll
            for (int fj = 0; fj < 4; ++fj)
                acc[fi][fj] = __builtin_amdgcn_mfma_f32_16x16x32_bf16(af[fi], bf[fj], acc[fi][fj], 0, 0, 0);
    }
    u16* Db = D + bb * dB;
    #pragma unroll
    for (int fi = 0; fi < 4; ++fi) {
        const int i = i0 + wi + fi * 16 + lg * 4;
        float b0 = 0, b1 = 0, b2v = 0, b3 = 0;
        if (bias) { b0 = bias[i]; b1 = bias[i + 1]; b2v = bias[i + 2]; b3 = bias[i + 3]; }
        #pragma unroll
        for (int fj = 0; fj < 4; ++fj) {
            const int j = j0 + wj + fj * 16 + lr;
            f32x4 d = acc[fi][fj];
            s16x4 o;
            o[0] = (short)f2bf(d[0] + b0); o[1] = (short)f2bf(d[1] + b1);
            o[2] = (short)f2bf(d[2] + b2v); o[3] = (short)f2bf(d[3] + b3);
            *(s16x4*)(Db + (long)j * dj + i) = o;
        }
    }
}

// ================= merged branch conv (all 4 branches, one launch) =================
// blockIdx.y = br; taps = 3+2*br; D[co][n] for channels [128br,128br+128)
__global__ __launch_bounds__(256) void gemm_branch4_k(
    const u16* __restrict__ WpAll,
    const u16* __restrict__ H,
    u16* __restrict__ Y)
{
    __shared__ s16x8 As[512];
    __shared__ s16x8 Bs[512];
    const int j0 = blockIdx.x * 128;
    const int br = blockIdx.y;
    const long bb = blockIdx.z;
    const int taps = 3 + 2 * br;
    const int pad = 1 + br;
    const u16* Wp = WpAll + (long)(br * br + 2 * br) * 16384;
    const u16* Hb = H + bb * 524288 + 128 * br;
    const int tid = threadIdx.x;
    const int srow = tid >> 2, sg = tid & 3;
    const int l = tid & 63, w = tid >> 6;
    const int wi = (w >> 1) * 64, wj = (w & 1) * 64;
    const int lr = l & 15, lg = l >> 4;
    const int lda = taps * 128;
    const int K = taps * 128;
    f32x4 acc[4][4] = {};
    for (int k0 = 0; k0 < K; k0 += 32) {
        const int tap = k0 >> 7, kc = k0 & 127;
        const int shift = tap - pad;
        __syncthreads();
        #pragma unroll
        for (int it = 0; it < 2; ++it) {
            int row = srow + it * 64;
            As[lds_chunk(row, sg)] = *(const s16x8*)(Wp + (long)row * lda + k0 + sg * 8);
            int n = j0 + row + shift;
            s16x8 v = {0, 0, 0, 0, 0, 0, 0, 0};
            if (n >= 0 && n < 1024)
                v = *(const s16x8*)(Hb + (long)n * 512 + kc + sg * 8);
            Bs[lds_chunk(row, sg)] = v;
        }
        __syncthreads();
        s16x8 af[4], bf[4];
        #pragma unroll
        for (int f = 0; f < 4; ++f) {
            af[f] = As[lds_chunk(wi + f * 16 + lr, lg)];
            bf[f] = Bs[lds_chunk(wj + f * 16 + lr, lg)];
        }
        #pragma unroll
        for (int fi = 0; fi < 4; ++fi)
            #pragma unroll
            for (int fj = 0; fj < 4; ++fj)
                acc[fi][fj] = __builtin_amdgcn_mfma_f32_16x16x32_bf16(af[fi], bf[fj], acc[fi][fj], 0, 0, 0);
    }
    u16* Db = Y + bb * 524288 + 128 * br;
    #pragma unroll
    for (int fi = 0; fi < 4; ++fi) {
        const int i = wi + fi * 16 + lg * 4;
        #pragma unroll
        for (int fj = 0; fj < 4; ++fj) {
            const int j = j0 + wj + fj * 16 + lr;
            f32x4 d = acc[fi][fj];
            s16x4 o;
            o[0] = (short)f2bf(d[0]); o[1] = (short)f2bf(d[1]);
            o[2] = (short)f2bf(d[2]); o[3] = (short)f2bf(d[3]);
            *(s16x4*)(Db + (long)j * 512 + i) = o;
        }
    }
}

// ================= PS+PL combined GEMM with fused BN+ReLU on A =================
// A = raw Y (BN applied in-register), B = [USc;ULc] (1024x512),
// D = PSL[bb][j(0..1023)][m(0..1023)]
__global__ __launch_bounds__(256) void gemm_psl_k(
    const u16* __restrict__ Yraw,
    const u16* __restrict__ Bmat,
    const float* __restrict__ scsh,   // [0,512)=scale, [512,1024)=shift
    u16* __restrict__ PSL)
{
    __shared__ s16x8 As[512];
    __shared__ s16x8 Bs[512];
    __shared__ float scs[512];
    __shared__ float shs[512];
    // XCD-aware bijective swizzle: grid 8x8x64 = 4096 = 8*512
    int flat = blockIdx.x + 8 * (blockIdx.y + 8 * blockIdx.z);
    int swz = (flat & 7) * 512 + (flat >> 3);
    const int j0 = (swz & 7) * 128;
    const int i0 = ((swz >> 3) & 7) * 128;
    const long bb = swz >> 6;
    const int tid = threadIdx.x;
    #pragma unroll
    for (int q = 0; q < 2; ++q) {
        scs[tid + q * 256] = scsh[tid + q * 256];
        shs[tid + q * 256] = scsh[512 + tid + q * 256];
    }
    const u16* Ab = Yraw + bb * 524288;
    const int srow = tid >> 2, sg = tid & 3;
    const int l = tid & 63, w = tid >> 6;
    const int wi = (w >> 1) * 64, wj = (w & 1) * 64;
    const int lr = l & 15, lg = l >> 4;
    f32x4 acc[4][4] = {};
    for (int k0 = 0; k0 < 512; k0 += 32) {
        __syncthreads();
        #pragma unroll
        for (int it = 0; it < 2; ++it) {
            int row = srow + it * 64;
            s16x8 v = *(const s16x8*)(Ab + (long)(i0 + row) * 512 + k0 + sg * 8);
            #pragma unroll
            for (int e = 0; e < 8; ++e) {
                int cch = k0 + sg * 8 + e;
                float f = bf2f((u16)v[e]) * scs[cch] + shs[cch];
                v[e] = (short)f2bf(f > 0.f ? f : 0.f);
            }
            As[lds_chunk(row, sg)] = v;
            Bs[lds_chunk(row, sg)] = *(const s16x8*)(Bmat + (long)(j0 + row) * 512 + k0 + sg * 8);
        }
        __syncthreads();
        s16x8 af[4], bf[4];
        #pragma unroll
        for (int f = 0; f < 4; ++f) {
            af[f] = As[lds_chunk(wi + f * 16 + lr, lg)];
            bf[f] = Bs[lds_chunk(wj + f * 16 + lr, lg)];
        }
        #pragma unroll
        for (int fi = 0; fi < 4; ++fi)
            #pragma unroll
            for (int fj = 0; fj < 4; ++fj)
                acc[fi][fj] = __builtin_amdgcn_mfma_f32_16x16x32_bf16(af[fi], bf[fj], acc[fi][fj], 0, 0, 0);
    }
    u16* Db = PSL + bb * 1048576;
    #pragma unroll
    for (int fi = 0; fi < 4; ++fi) {
        const int i = i0 + wi + fi * 16 + lg * 4;
        #pragma unroll
        for (int fj = 0; fj < 4; ++fj) {
            const int j = j0 + wj + fj * 16 + lr;
            f32x4 d = acc[fi][fj];
            s16x4 o;
            o[0] = (short)f2bf(d[0]); o[1] = (short)f2bf(d[1]);
            o[2] = (short)f2bf(d[2]); o[3] = (short)f2bf(d[3]);
            *(s16x4*)(Db + (long)j * 1024 + i) = o;
        }
    }
}

// ================= time-axis GEMM (band-limited, dual pass, f32 out) =================
__global__ __launch_bounds__(256) void gemm_time_k(
    const u16* __restrict__ MS, const u16* __restrict__ ML,
    const u16* __restrict__ PSL,
    const float* __restrict__ b2, const float* __restrict__ X,
    float* __restrict__ OUT)
{
    __shared__ s16x8 As[512];
    __shared__ s16x8 Bs[512];
    // XCD-aware bijective swizzle: grid 4x8x64 = 2048 = 8*256
    int flat = blockIdx.x + 4 * (blockIdx.y + 8 * blockIdx.z);
    int swz = (flat & 7) * 256 + (flat >> 3);
    const int j0 = (swz & 3) * 128;          // co tile
    const int i0 = ((swz >> 2) & 7) * 128;   // n tile
    const long bb = swz >> 5;
    const int tid = threadIdx.x;
    const int srow = tid >> 2, sg = tid & 3;
    const int l = tid & 63, w = tid >> 6;
    const int wi = (w >> 1) * 64, wj = (w & 1) * 64;
    const int lr = l & 15, lg = l >> 4;
    const int klo = (i0 - 96) > 0 ? (i0 - 96) : 0;
    const int khi = (i0 + 224) < 1024 ? (i0 + 224) : 1024;
    f32x4 acc[4][4] = {};
    for (int pass = 0; pass < 2; ++pass) {
        const u16* A = pass ? ML : MS;
        const u16* B = PSL + bb * 1048576 + (long)pass * 524288;
        for (int k0 = klo; k0 < khi; k0 += 32) {
            __syncthreads();
            #pragma unroll
            for (int it = 0; it < 2; ++it) {
                int row = srow + it * 64;
                As[lds_chunk(row, sg)] = *(const s16x8*)(A + (long)(i0 + row) * 1024 + k0 + sg * 8);
                Bs[lds_chunk(row, sg)] = *(const s16x8*)(B + (long)(j0 + row) * 1024 + k0 + sg * 8);
            }
            __syncthreads();
            s16x8 af[4], bf[4];
            #pragma unroll
            for (int f = 0; f < 4; ++f) {
                af[f] = As[lds_chunk(wi + f * 16 + lr, lg)];
                bf[f] = Bs[lds_chunk(wj + f * 16 + lr, lg)];
            }
            #pragma unroll
            for (int fi = 0; fi < 4; ++fi)
                #pragma unroll
                for (int fj = 0; fj < 4; ++fj)
                    acc[fi][fj] = __builtin_amdgcn_mfma_f32_16x16x32_bf16(af[fi], bf[fj], acc[fi][fj], 0, 0, 0);
        }
    }
    float* Ob = OUT + bb * 524288;
    const float* Xb = X + bb * 524288;
    #pragma unroll
    for (int fi = 0; fi < 4; ++fi) {
        const int i = i0 + wi + fi * 16 + lg * 4;
        #pragma unroll
        for (int fj = 0; fj < 4; ++fj) {
            const int j = j0 + wj + fj * 16 + lr;
            const long a = (long)j * 1024 + i;
            f32x4 d = acc[fi][fj];
            const float bj = b2[j];
            f32x4 xv = *(const f32x4*)(Xb + a);
            f32x4 o;
            o[0] = d[0] + bj + xv[0]; o[1] = d[1] + bj + xv[1];
            o[2] = d[2] + bj + xv[2]; o[3] = d[3] + bj + xv[3];
            *(f32x4*)(Ob + a) = o;
        }
    }
}

// ================= packing / small kernels =================
__global__ __launch_bounds__(256) void cast_bf_k(const float* __restrict__ s, u16* __restrict__ d, int n)
{
    int i = blockIdx.x * 256 + threadIdx.x;
    if (i < n) d[i] = f2bf(s[i]);
}

// d[co*(taps*128) + tap*128 + ci] = s[(co*128+ci)*taps + tap]   (w_b is (co,ci,tap))
__global__ __launch_bounds__(256) void pack_wb2_k(const float* __restrict__ s, u16* __restrict__ d, int taps)
{
    int i = blockIdx.x * 256 + threadIdx.x;
    if (i >= taps * 16384) return;
    int stride = taps * 128;
    int co = i / stride;
    int rem = i - co * stride;
    int tap = rem >> 7, ci = rem & 127;
    d[i] = f2bf(s[(long)(co * 128 + ci) * taps + tap]);
}

// USc[co][128b+cc] = suffix-sum_b of (wfus_b . wpf_S); ULc = prefix-sum of (wfus_b . wpf_L)
__global__ __launch_bounds__(256) void make_Ucum_k(
    const float* __restrict__ wf, const float* __restrict__ wp,
    u16* __restrict__ USc, u16* __restrict__ ULc)
{
    int gid = blockIdx.x * 256 + threadIdx.x;   // 512*128
    int co = gid >> 7, cc = gid & 127;
    float us[4], ul[4];
    #pragma unroll
    for (int b = 0; b < 4; ++b) {
        float s = 0.f, t = 0.f;
        for (int q = 0; q < 128; ++q) {
            float f = wf[(long)co * 512 + b * 128 + q];
            s += f * wp[q * 256 + cc];
            t += f * wp[q * 256 + 128 + cc];
        }
        us[b] = s; ul[b] = t;
    }
    float suf = 0.f;
    for (int b = 3; b >= 0; --b) { suf += us[b]; USc[(long)co * 512 + b * 128 + cc] = f2bf(suf); }
    float pre = 0.f;
    for (int b = 0; b < 4; ++b) { pre += ul[b]; ULc[(long)co * 512 + b * 128 + cc] = f2bf(pre); }
}

__global__ __launch_bounds__(256) void make_bias2_k(
    const float* __restrict__ wf, const float* __restrict__ bpf,
    const float* __restrict__ bfus, float* __restrict__ b2)
{
    int co = blockIdx.x * 256 + threadIdx.x;
    if (co >= 512) return;
    float s = bfus[co];
    for (int j = 0; j < 512; ++j) s += wf[(long)co * 512 + j] * bpf[j & 127];
    b2[co] = s;
}

__global__ __launch_bounds__(256) void eye_k(float* __restrict__ I)
{
    int i = blockIdx.x * 256 + threadIdx.x;
    I[i] = ((i >> 10) == (i & 1023)) ? 1.0f : 0.0f;
}

__global__ __launch_bounds__(256) void zero_k(float* __restrict__ p, int n)
{
    int i = blockIdx.x * 256 + threadIdx.x;
    if (i < n) p[i] = 0.f;
}

// ---------------- DWT / IDWT (f32, used only for M-build on identity) ----------------
__global__ __launch_bounds__(256) void dwt_k(
    const float* __restrict__ x, float* __restrict__ a, float* __restrict__ d,
    int n_in, int n_out)
{
    const int row = blockIdx.y;
    const int m = blockIdx.x * 256 + threadIdx.x;
    if (m >= n_out) return;
    const float* xr = x + (long)row * n_in;
    float sa = 0.f, sd = 0.f;
    #pragma unroll
    for (int j = 0; j < 8; ++j) {
        int t = 2 * m + 1 - j;
        t = (t < 0) ? (-t - 1) : t;
        t = (t >= n_in) ? (2 * n_in - 1 - t) : t;
        const float v = xr[t];
        sa += v * c_lo[j];
        sd += v * c_hi[j];
    }
    a[(long)row * n_out + m] = sa;
    d[(long)row * n_out + m] = sd;
}

__global__ __launch_bounds__(256) void idwt_k(
    const float* __restrict__ lo, const float* __restrict__ hi,
    float* __restrict__ z, int nc, int n_out, long zB, int zN)
{
    const int row = blockIdx.y;
    const int m = blockIdx.x * 256 + threadIdx.x;
    if (m >= n_out) return;
    const float* lor = lo ? lo + (long)row * nc : nullptr;
    const float* hir = hi ? hi + (long)row * nc : nullptr;
    float s = 0.f;
    #pragma unroll
    for (int k = 0; k < 8; ++k) {
        int t = m + k - 1;
        if (t & 1) continue;
        int j = t >> 1;
        if (j >= nc) continue;
        if (lor) s += c_lo[k] * lor[j];
        if (hir) s += c_hi[k] * hir[j];
    }
    z[(long)(row >> 7) * zB + (long)(row & 127) * zN + m] = s;
}

// ---------------- transposes ----------------
__global__ __launch_bounds__(256) void trM_k(
    const float* __restrict__ S, const float* __restrict__ L,
    u16* __restrict__ MS, u16* __restrict__ ML)
{
    __shared__ float sh[32][33];
    const float* src = blockIdx.z ? L : S;
    u16* dst = blockIdx.z ? ML : MS;
    const int n0 = blockIdx.x * 32, m0 = blockIdx.y * 32;
    const int tx = threadIdx.x, ty = threadIdx.y;
    #pragma unroll
    for (int k = 0; k < 4; ++k)
        sh[ty + 8 * k][tx] = src[(long)(m0 + ty + 8 * k) * 1024 + n0 + tx];
    __syncthreads();
    #pragma unroll
    for (int k = 0; k < 4; ++k)
        dst[(long)(n0 + ty + 8 * k) * 1024 + m0 + tx] = f2bf(sh[tx][ty + 8 * k]);
}

// xcl[bb][n][c] = bf16(x[bb][c][n])
__global__ __launch_bounds__(256) void trX_k(const float* __restrict__ x, u16* __restrict__ xcl)
{
    __shared__ float sh[32][33];
    const int n0 = blockIdx.x * 32, c0 = blockIdx.y * 32;
    const long bb = blockIdx.z;
    const int tx = threadIdx.x, ty = threadIdx.y;
    const float* xb = x + bb * 524288;
    u16* ob = xcl + bb * 524288;
    #pragma unroll
    for (int k = 0; k < 4; ++k)
        sh[ty + 8 * k][tx] = xb[(long)(c0 + ty + 8 * k) * 1024 + n0 + tx];
    __syncthreads();
    #pragma unroll
    for (int k = 0; k < 4; ++k)
        ob[(long)(n0 + ty + 8 * k) * 512 + c0 + tx] = f2bf(sh[tx][ty + 8 * k]);
}

// ---------------- BN ----------------
// blockIdx.y = branch
__global__ __launch_bounds__(256) void bn_stats_k(const u16* __restrict__ Y, float* __restrict__ st)
{
    __shared__ float ss[128][16];
    __shared__ float sq[128][16];
    const int br = blockIdx.y;
    const u16* Yb = Y + 128 * br;
    float* stb = st + br * 256;
    const int t = threadIdx.x;
    const int chg = t & 15, rl = t >> 4;
    const long r0 = (long)blockIdx.x * 256;
    float s[8] = {}, q[8] = {};
    for (int k = 0; k < 16; ++k) {
        long r = r0 + rl + k * 16;
        s16x8 v = *(const s16x8*)(Yb + r * 512 + chg * 8);
        #pragma unroll
        for (int e = 0; e < 8; ++e) { float f = bf2f((u16)v[e]); s[e] += f; q[e] += f * f; }
    }
    #pragma unroll
    for (int e = 0; e < 8; ++e) { ss[chg * 8 + e][rl] = s[e]; sq[chg * 8 + e][rl] = q[e]; }
    __syncthreads();
    if (t < 128) {
        float a = 0, b = 0;
        #pragma unroll
        for (int k = 0; k < 16; ++k) { a += ss[t][k]; b += sq[t][k]; }
        atomicAdd(stb + t, a); atomicAdd(stb + 128 + t, b);
    }
}

// scsh[c] = scale, scsh[512+c] = shift, c in [0,512)
__global__ __launch_bounds__(256) void bn_coef_k(
    const float* __restrict__ st, PtrQuad g, PtrQuad be, float* __restrict__ scsh)
{
    int c = blockIdx.x * 256 + threadIdx.x;
    if (c >= 512) return;
    int br = c >> 7, cc = c & 127;
    float mu = st[br * 256 + cc] * (1.0f / 65536.0f);
    float var = st[br * 256 + 128 + cc] * (1.0f / 65536.0f) - mu * mu;
    float sc = g.p[br][cc] * rsqrtf(var + 1e-5f);
    scsh[c] = sc;
    scsh[512 + c] = be.p[br][cc] - mu * sc;
}

// =====================================================================
extern "C" void kernel_launch(void* const* d_in, const int* in_sizes, int n_in,
                              void* d_out, int out_size, void* d_ws, size_t ws_size,
                              hipStream_t stream)
{
    const float* x      = (const float*)d_in[0];
    const float* w_init = (const float*)d_in[1];
    const float* b_init = (const float*)d_in[2];
    const float* w_pf   = (const float*)d_in[3];
    const float* b_pf   = (const float*)d_in[4];
    const float* w_fus  = (const float*)d_in[5];
    const float* b_fus  = (const float*)d_in[6];
    const float *w_b[4];
    PtrQuad g, be;
    for (int i = 0; i < 4; ++i) {
        w_b[i]  = (const float*)d_in[7 + 4 * i];
        g.p[i]  = (const float*)d_in[9 + 4 * i];
        be.p[i] = (const float*)d_in[10 + 4 * i];
    }
    float* outf = (float*)d_out;

    char* p = (char*)d_ws;
    u16* xcl   = (u16*)p;  p += 67108864;
    u16* h     = (u16*)p;  p += 67108864;
    u16* Y     = (u16*)p;  p += 67108864;
    u16* PSL   = (u16*)p;  p += 134217728;
    u16* Wi    = (u16*)p;  p += 524288;
    u16* Wp    = (u16*)p;  p += 786432;
    u16* UScULc= (u16*)p;  p += 1048576;
    u16* MrowS = (u16*)p;  p += 2097152;
    u16* MrowL = (u16*)p;  p += 2097152;
    float* eye = (float*)p; p += 4194304;
    float* Sid = (float*)p; p += 4194304;
    float* Lid = (float*)p; p += 4194304;
    float* a1  = (float*)p; p += 2109440;
    float* d1  = (float*)p; p += 2109440;
    float* a2  = (float*)p; p += 1069056;
    float* d2  = (float*)p; p += 1069056;
    float* la1 = (float*)p; p += 2109440;
    float* sa1 = (float*)p; p += 2109440;
    float* b2  = (float*)p; p += 2048;
    float* st  = (float*)p; p += 4096;
    float* scsh= (float*)p; p += 4096;

    const int KS_[4] = {3, 5, 7, 9};
    const long wpOff[4] = {0, 3 * 16384L, 8 * 16384L, 15 * 16384L};

    // ---- weight packing / fused-weight precompute ----
    cast_bf_k<<<1024, 256, 0, stream>>>(w_init, Wi, 262144);
    for (int br = 0; br < 4; ++br)
        pack_wb2_k<<<(KS_[br] * 16384 + 255) / 256, 256, 0, stream>>>(w_b[br], Wp + wpOff[br], KS_[br]);
    make_Ucum_k<<<256, 256, 0, stream>>>(w_fus, w_pf, UScULc, UScULc + 262144);
    make_bias2_k<<<2, 256, 0, stream>>>(w_fus, b_pf, b_fus, b2);

    // ---- build wavelet operators M_S, M_L from identity ----
    eye_k<<<4096, 256, 0, stream>>>(eye);
    dwt_k<<<dim3(3, 1024), 256, 0, stream>>>(eye, a1, d1, 1024, 515);
    dwt_k<<<dim3(2, 1024), 256, 0, stream>>>(a1, a2, d2, 515, 261);
    idwt_k<<<dim3(3, 1024), 256, 0, stream>>>(a2, nullptr, la1, 261, 515, 65920, 515);
    idwt_k<<<dim3(3, 1024), 256, 0, stream>>>(nullptr, d2, sa1, 261, 515, 65920, 515);
    idwt_k<<<dim3(4, 1024), 256, 0, stream>>>(la1, nullptr, Lid, 515, 1024, 131072, 1024);
    idwt_k<<<dim3(4, 1024), 256, 0, stream>>>(sa1, d1, Sid, 515, 1024, 131072, 1024);
    trM_k<<<dim3(32, 32, 2), dim3(32, 8), 0, stream>>>(Sid, Lid, MrowS, MrowL);

    // ---- activations: transpose to channel-last bf16 ----
    trX_k<<<dim3(32, 16, 64), dim3(32, 8), 0, stream>>>(x, xcl);

    // ---- conv1x1: h[n][co] = Wi x + b_init ----
    gemm_nt_k<<<dim3(8, 4, 64), 256, 0, stream>>>(Wi, 0, 512, xcl, 524288, 512, 512,
                                                  h, 524288, 512, b_init);

    // ---- branches: conv(taps) all-in-one; raw Y out ----
    zero_k<<<4, 256, 0, stream>>>(st, 1024);
    gemm_branch4_k<<<dim3(8, 4, 64), 256, 0, stream>>>(Wp, h, Y);

    // ---- BN stats (all branches) + coefficients ----
    bn_stats_k<<<dim3(256, 4), 256, 0, stream>>>(Y, st);
    bn_coef_k<<<2, 256, 0, stream>>>(st, g, be, scsh);

    // ---- PSL = [BN_ReLU(Y)] . [USc;ULc]^T (one launch, BN fused on A) ----
    gemm_psl_k<<<dim3(8, 8, 64), 256, 0, stream>>>(Y, UScULc, scsh, PSL);

    // ---- out = M_S.PS^T + M_L.PL^T + b2 + x ----
    gemm_time_k<<<dim3(4, 8, 64), 256, 0, stream>>>(MrowS, MrowL, PSL, b2, x, outf);
}

// Round 5
// 571.464 us; speedup vs baseline: 6.9348x; 1.0611x over previous
//
#include <hip/hip_runtime.h>

typedef float  f32x4 __attribute__((ext_vector_type(4)));
typedef short  s16x8 __attribute__((ext_vector_type(8)));
typedef short  s16x4 __attribute__((ext_vector_type(4)));
typedef unsigned short u16;

struct PtrQuad { const float* p[4]; };

// ---------------- db4 filters ----------------
__constant__ float c_lo[8] = {-0.010597401784997278f, 0.032883011666982945f,
                              0.030841381835986965f, -0.18703481171888114f,
                              -0.02798376941698385f, 0.6308807679295904f,
                              0.7148465705525415f,  0.23037781330885523f};
__constant__ float c_hi[8] = {-0.23037781330885523f, 0.7148465705525415f,
                              -0.6308807679295904f, -0.02798376941698385f,
                              0.18703481171888114f, 0.030841381835986965f,
                              -0.032883011666982945f, -0.010597401784997278f};

__device__ __forceinline__ u16 f2bf(float f) {
    unsigned u = __float_as_uint(f);
    u += 0x7fffu + ((u >> 16) & 1u);
    return (u16)(u >> 16);
}
__device__ __forceinline__ float bf2f(u16 h) {
    return __uint_as_float(((unsigned)h) << 16);
}
__device__ __forceinline__ int lds_chunk(int row, int g) {
    return row * 4 + (g ^ ((row >> 1) & 3));
}
// async 16B global->LDS; LDS dest = wave-uniform base + lane*16 (linear).
__device__ __forceinline__ void gload16(void* lds, const void* g) {
    __builtin_amdgcn_global_load_lds(
        (__attribute__((address_space(1))) const void*)g,
        (__attribute__((address_space(3))) void*)lds,
        16, 0, 0);
}

// ================= generic NT MFMA GEMM (used for conv1x1) =================
// D[i][j] = sum_k A[i][k]*B[j][k]; store bf16 at D + bb*dB + j*dj + i (+bias[i])
__global__ __launch_bounds__(256) void gemm_nt_k(
    const u16* __restrict__ A, long aB, int lda,
    const u16* __restrict__ B, long bB, int ldb,
    int K,
    u16* __restrict__ D, long dB, int dj,
    const float* __restrict__ bias)
{
    __shared__ s16x8 As[512];
    __shared__ s16x8 Bs[512];
    const int j0 = blockIdx.x * 128, i0 = blockIdx.y * 128;
    const long bb = blockIdx.z;
    const u16* Ab = A + bb * aB;
    const u16* Bb = B + bb * bB;
    const int tid = threadIdx.x;
    const int srow = tid >> 2, sg = tid & 3;
    const int ssg = sg ^ ((srow >> 1) & 3);
    const int l = tid & 63, w = tid >> 6;
    const int wi = (w >> 1) * 64, wj = (w & 1) * 64;
    const int lr = l & 15, lg = l >> 4;
    char* lA0 = (char*)As + w * 1024;
    char* lA1 = (char*)As + 4096 + w * 1024;
    char* lB0 = (char*)Bs + w * 1024;
    char* lB1 = (char*)Bs + 4096 + w * 1024;
    f32x4 acc[4][4] = {};
    for (int k0 = 0; k0 < K; k0 += 32) {
        __syncthreads();
        gload16(lA0, Ab + (long)(i0 + srow) * lda + k0 + ssg * 8);
        gload16(lA1, Ab + (long)(i0 + srow + 64) * lda + k0 + ssg * 8);
        gload16(lB0, Bb + (long)(j0 + srow) * ldb + k0 + ssg * 8);
        gload16(lB1, Bb + (long)(j0 + srow + 64) * ldb + k0 + ssg * 8);
        __syncthreads();
        s16x8 af[4], bf[4];
        #pragma unroll
        for (int f = 0; f < 4; ++f) {
            af[f] = As[lds_chunk(wi + f * 16 + lr, lg)];
            bf[f] = Bs[lds_chunk(wj + f * 16 + lr, lg)];
        }
        #pragma unroll
        for (int fi = 0; fi < 4; ++fi)
            #pragma unroll
            for (int fj = 0; fj < 4; ++fj)
                acc[fi][fj] = __builtin_amdgcn_mfma_f32_16x16x32_bf16(af[fi], bf[fj], acc[fi][fj], 0, 0, 0);
    }
    u16* Db = D + bb * dB;
    #pragma unroll
    for (int fi = 0; fi < 4; ++fi) {
        const int i = i0 + wi + fi * 16 + lg * 4;
        float b0 = 0, b1 = 0, b2v = 0, b3 = 0;
        if (bias) { b0 = bias[i]; b1 = bias[i + 1]; b2v = bias[i + 2]; b3 = bias[i + 3]; }
        #pragma unroll
        for (int fj = 0; fj < 4; ++fj) {
            const int j = j0 + wj + fj * 16 + lr;
            f32x4 d = acc[fi][fj];
            s16x4 o;
            o[0] = (short)f2bf(d[0] + b0); o[1] = (short)f2bf(d[1] + b1);
            o[2] = (short)f2bf(d[2] + b2v); o[3] = (short)f2bf(d[3] + b3);
            *(s16x4*)(Db + (long)j * dj + i) = o;
        }
    }
}

// ================= merged branch conv (all 4 branches, one launch) =================
// blockIdx.y = br; taps = 3+2*br; OOB rows redirected to zeroed zbuf line
__global__ __launch_bounds__(256) void gemm_branch4_k(
    const u16* __restrict__ WpAll,
    const u16* __restrict__ H,
    u16* __restrict__ Y,
    const u16* __restrict__ zbuf)
{
    __shared__ s16x8 As[512];
    __shared__ s16x8 Bs[512];
    const int j0 = blockIdx.x * 128;
    const int br = blockIdx.y;
    const long bb = blockIdx.z;
    const int taps = 3 + 2 * br;
    const int pad = 1 + br;
    const u16* Wp = WpAll + (long)(br * br + 2 * br) * 16384;
    const u16* Hb = H + bb * 524288 + 128 * br;
    const int tid = threadIdx.x;
    const int srow = tid >> 2, sg = tid & 3;
    const int ssg = sg ^ ((srow >> 1) & 3);
    const int l = tid & 63, w = tid >> 6;
    const int wi = (w >> 1) * 64, wj = (w & 1) * 64;
    const int lr = l & 15, lg = l >> 4;
    const int lda = taps * 128;
    const int K = taps * 128;
    char* lA0 = (char*)As + w * 1024;
    char* lA1 = (char*)As + 4096 + w * 1024;
    char* lB0 = (char*)Bs + w * 1024;
    char* lB1 = (char*)Bs + 4096 + w * 1024;
    f32x4 acc[4][4] = {};
    for (int k0 = 0; k0 < K; k0 += 32) {
        const int tap = k0 >> 7, kc = k0 & 127;
        const int shift = tap - pad;
        __syncthreads();
        gload16(lA0, Wp + (long)srow * lda + k0 + ssg * 8);
        gload16(lA1, Wp + (long)(srow + 64) * lda + k0 + ssg * 8);
        {
            int n0r = j0 + srow + shift;
            int n1r = n0r + 64;
            const u16* s0 = (n0r >= 0 && n0r < 1024) ? (Hb + (long)n0r * 512 + kc + ssg * 8) : zbuf;
            const u16* s1 = (n1r >= 0 && n1r < 1024) ? (Hb + (long)n1r * 512 + kc + ssg * 8) : zbuf;
            gload16(lB0, s0);
            gload16(lB1, s1);
        }
        __syncthreads();
        s16x8 af[4], bf[4];
        #pragma unroll
        for (int f = 0; f < 4; ++f) {
            af[f] = As[lds_chunk(wi + f * 16 + lr, lg)];
            bf[f] = Bs[lds_chunk(wj + f * 16 + lr, lg)];
        }
        #pragma unroll
        for (int fi = 0; fi < 4; ++fi)
            #pragma unroll
            for (int fj = 0; fj < 4; ++fj)
                acc[fi][fj] = __builtin_amdgcn_mfma_f32_16x16x32_bf16(af[fi], bf[fj], acc[fi][fj], 0, 0, 0);
    }
    u16* Db = Y + bb * 524288 + 128 * br;
    #pragma unroll
    for (int fi = 0; fi < 4; ++fi) {
        const int i = wi + fi * 16 + lg * 4;
        #pragma unroll
        for (int fj = 0; fj < 4; ++fj) {
            const int j = j0 + wj + fj * 16 + lr;
            f32x4 d = acc[fi][fj];
            s16x4 o;
            o[0] = (short)f2bf(d[0]); o[1] = (short)f2bf(d[1]);
            o[2] = (short)f2bf(d[2]); o[3] = (short)f2bf(d[3]);
            *(s16x4*)(Db + (long)j * 512 + i) = o;
        }
    }
}

// ================= PS+PL combined GEMM (pure; Y already BN'd) =================
// A = Ybn[bb][n][512], B = [USc;ULc] (1024x512), D = PSL[bb][j][m]
__global__ __launch_bounds__(256) void gemm_psl_k(
    const u16* __restrict__ Ybn,
    const u16* __restrict__ Bmat,
    u16* __restrict__ PSL)
{
    __shared__ s16x8 As[512];
    __shared__ s16x8 Bs[512];
    // XCD-aware bijective swizzle: grid 8x8x64 = 4096 = 8*512
    int flat = blockIdx.x + 8 * (blockIdx.y + 8 * blockIdx.z);
    int swz = (flat & 7) * 512 + (flat >> 3);
    const int j0 = (swz & 7) * 128;
    const int i0 = ((swz >> 3) & 7) * 128;
    const long bb = swz >> 6;
    const int tid = threadIdx.x;
    const u16* Ab = Ybn + bb * 524288;
    const int srow = tid >> 2, sg = tid & 3;
    const int ssg = sg ^ ((srow >> 1) & 3);
    const int l = tid & 63, w = tid >> 6;
    const int wi = (w >> 1) * 64, wj = (w & 1) * 64;
    const int lr = l & 15, lg = l >> 4;
    char* lA0 = (char*)As + w * 1024;
    char* lA1 = (char*)As + 4096 + w * 1024;
    char* lB0 = (char*)Bs + w * 1024;
    char* lB1 = (char*)Bs + 4096 + w * 1024;
    f32x4 acc[4][4] = {};
    for (int k0 = 0; k0 < 512; k0 += 32) {
        __syncthreads();
        gload16(lA0, Ab + (long)(i0 + srow) * 512 + k0 + ssg * 8);
        gload16(lA1, Ab + (long)(i0 + srow + 64) * 512 + k0 + ssg * 8);
        gload16(lB0, Bmat + (long)(j0 + srow) * 512 + k0 + ssg * 8);
        gload16(lB1, Bmat + (long)(j0 + srow + 64) * 512 + k0 + ssg * 8);
        __syncthreads();
        s16x8 af[4], bf[4];
        #pragma unroll
        for (int f = 0; f < 4; ++f) {
            af[f] = As[lds_chunk(wi + f * 16 + lr, lg)];
            bf[f] = Bs[lds_chunk(wj + f * 16 + lr, lg)];
        }
        #pragma unroll
        for (int fi = 0; fi < 4; ++fi)
            #pragma unroll
            for (int fj = 0; fj < 4; ++fj)
                acc[fi][fj] = __builtin_amdgcn_mfma_f32_16x16x32_bf16(af[fi], bf[fj], acc[fi][fj], 0, 0, 0);
    }
    u16* Db = PSL + bb * 1048576;
    #pragma unroll
    for (int fi = 0; fi < 4; ++fi) {
        const int i = i0 + wi + fi * 16 + lg * 4;
        #pragma unroll
        for (int fj = 0; fj < 4; ++fj) {
            const int j = j0 + wj + fj * 16 + lr;
            f32x4 d = acc[fi][fj];
            s16x4 o;
            o[0] = (short)f2bf(d[0]); o[1] = (short)f2bf(d[1]);
            o[2] = (short)f2bf(d[2]); o[3] = (short)f2bf(d[3]);
            *(s16x4*)(Db + (long)j * 1024 + i) = o;
        }
    }
}

// ================= time-axis GEMM (band-limited, dual pass, f32 out) =================
__global__ __launch_bounds__(256) void gemm_time_k(
    const u16* __restrict__ MS, const u16* __restrict__ ML,
    const u16* __restrict__ PSL,
    const float* __restrict__ b2, const float* __restrict__ X,
    float* __restrict__ OUT)
{
    __shared__ s16x8 As[512];
    __shared__ s16x8 Bs[512];
    // XCD-aware bijective swizzle: grid 4x8x64 = 2048 = 8*256
    int flat = blockIdx.x + 4 * (blockIdx.y + 8 * blockIdx.z);
    int swz = (flat & 7) * 256 + (flat >> 3);
    const int j0 = (swz & 3) * 128;          // co tile
    const int i0 = ((swz >> 2) & 7) * 128;   // n tile
    const long bb = swz >> 5;
    const int tid = threadIdx.x;
    const int srow = tid >> 2, sg = tid & 3;
    const int ssg = sg ^ ((srow >> 1) & 3);
    const int l = tid & 63, w = tid >> 6;
    const int wi = (w >> 1) * 64, wj = (w & 1) * 64;
    const int lr = l & 15, lg = l >> 4;
    const int klo = (i0 - 96) > 0 ? (i0 - 96) : 0;
    const int khi = (i0 + 224) < 1024 ? (i0 + 224) : 1024;
    char* lA0 = (char*)As + w * 1024;
    char* lA1 = (char*)As + 4096 + w * 1024;
    char* lB0 = (char*)Bs + w * 1024;
    char* lB1 = (char*)Bs + 4096 + w * 1024;
    f32x4 acc[4][4] = {};
    for (int pass = 0; pass < 2; ++pass) {
        const u16* A = pass ? ML : MS;
        const u16* B = PSL + bb * 1048576 + (long)pass * 524288;
        for (int k0 = klo; k0 < khi; k0 += 32) {
            __syncthreads();
            gload16(lA0, A + (long)(i0 + srow) * 1024 + k0 + ssg * 8);
            gload16(lA1, A + (long)(i0 + srow + 64) * 1024 + k0 + ssg * 8);
            gload16(lB0, B + (long)(j0 + srow) * 1024 + k0 + ssg * 8);
            gload16(lB1, B + (long)(j0 + srow + 64) * 1024 + k0 + ssg * 8);
            __syncthreads();
            s16x8 af[4], bf[4];
            #pragma unroll
            for (int f = 0; f < 4; ++f) {
                af[f] = As[lds_chunk(wi + f * 16 + lr, lg)];
                bf[f] = Bs[lds_chunk(wj + f * 16 + lr, lg)];
            }
            #pragma unroll
            for (int fi = 0; fi < 4; ++fi)
                #pragma unroll
                for (int fj = 0; fj < 4; ++fj)
                    acc[fi][fj] = __builtin_amdgcn_mfma_f32_16x16x32_bf16(af[fi], bf[fj], acc[fi][fj], 0, 0, 0);
        }
    }
    float* Ob = OUT + bb * 524288;
    const float* Xb = X + bb * 524288;
    #pragma unroll
    for (int fi = 0; fi < 4; ++fi) {
        const int i = i0 + wi + fi * 16 + lg * 4;
        #pragma unroll
        for (int fj = 0; fj < 4; ++fj) {
            const int j = j0 + wj + fj * 16 + lr;
            const long a = (long)j * 1024 + i;
            f32x4 d = acc[fi][fj];
            const float bj = b2[j];
            f32x4 xv = *(const f32x4*)(Xb + a);
            f32x4 o;
            o[0] = d[0] + bj + xv[0]; o[1] = d[1] + bj + xv[1];
            o[2] = d[2] + bj + xv[2]; o[3] = d[3] + bj + xv[3];
            *(f32x4*)(Ob + a) = o;
        }
    }
}

// ================= packing / small kernels =================
__global__ __launch_bounds__(256) void cast_bf_k(const float* __restrict__ s, u16* __restrict__ d, int n)
{
    int i = blockIdx.x * 256 + threadIdx.x;
    if (i < n) d[i] = f2bf(s[i]);
}

// d[co*(taps*128) + tap*128 + ci] = s[(co*128+ci)*taps + tap]   (w_b is (co,ci,tap))
__global__ __launch_bounds__(256) void pack_wb2_k(const float* __restrict__ s, u16* __restrict__ d, int taps)
{
    int i = blockIdx.x * 256 + threadIdx.x;
    if (i >= taps * 16384) return;
    int stride = taps * 128;
    int co = i / stride;
    int rem = i - co * stride;
    int tap = rem >> 7, ci = rem & 127;
    d[i] = f2bf(s[(long)(co * 128 + ci) * taps + tap]);
}

// USc[co][128b+cc] = suffix-sum_b of (wfus_b . wpf_S); ULc = prefix-sum of (wfus_b . wpf_L)
__global__ __launch_bounds__(256) void make_Ucum_k(
    const float* __restrict__ wf, const float* __restrict__ wp,
    u16* __restrict__ USc, u16* __restrict__ ULc)
{
    int gid = blockIdx.x * 256 + threadIdx.x;   // 512*128
    int co = gid >> 7, cc = gid & 127;
    float us[4], ul[4];
    #pragma unroll
    for (int b = 0; b < 4; ++b) {
        float s = 0.f, t = 0.f;
        for (int q = 0; q < 128; ++q) {
            float f = wf[(long)co * 512 + b * 128 + q];
            s += f * wp[q * 256 + cc];
            t += f * wp[q * 256 + 128 + cc];
        }
        us[b] = s; ul[b] = t;
    }
    float suf = 0.f;
    for (int b = 3; b >= 0; --b) { suf += us[b]; USc[(long)co * 512 + b * 128 + cc] = f2bf(suf); }
    float pre = 0.f;
    for (int b = 0; b < 4; ++b) { pre += ul[b]; ULc[(long)co * 512 + b * 128 + cc] = f2bf(pre); }
}

__global__ __launch_bounds__(256) void make_bias2_k(
    const float* __restrict__ wf, const float* __restrict__ bpf,
    const float* __restrict__ bfus, float* __restrict__ b2)
{
    int co = blockIdx.x * 256 + threadIdx.x;
    if (co >= 512) return;
    float s = bfus[co];
    for (int j = 0; j < 512; ++j) s += wf[(long)co * 512 + j] * bpf[j & 127];
    b2[co] = s;
}

__global__ __launch_bounds__(256) void eye_k(float* __restrict__ I)
{
    int i = blockIdx.x * 256 + threadIdx.x;
    I[i] = ((i >> 10) == (i & 1023)) ? 1.0f : 0.0f;
}

__global__ __launch_bounds__(256) void zero_k(float* __restrict__ p, int n)
{
    int i = blockIdx.x * 256 + threadIdx.x;
    if (i < n) p[i] = 0.f;
}

// ---------------- DWT / IDWT (f32, used only for M-build on identity) ----------------
__global__ __launch_bounds__(256) void dwt_k(
    const float* __restrict__ x, float* __restrict__ a, float* __restrict__ d,
    int n_in, int n_out)
{
    const int row = blockIdx.y;
    const int m = blockIdx.x * 256 + threadIdx.x;
    if (m >= n_out) return;
    const float* xr = x + (long)row * n_in;
    float sa = 0.f, sd = 0.f;
    #pragma unroll
    for (int j = 0; j < 8; ++j) {
        int t = 2 * m + 1 - j;
        t = (t < 0) ? (-t - 1) : t;
        t = (t >= n_in) ? (2 * n_in - 1 - t) : t;
        const float v = xr[t];
        sa += v * c_lo[j];
        sd += v * c_hi[j];
    }
    a[(long)row * n_out + m] = sa;
    d[(long)row * n_out + m] = sd;
}

__global__ __launch_bounds__(256) void idwt_k(
    const float* __restrict__ lo, const float* __restrict__ hi,
    float* __restrict__ z, int nc, int n_out, long zB, int zN)
{
    const int row = blockIdx.y;
    const int m = blockIdx.x * 256 + threadIdx.x;
    if (m >= n_out) return;
    const float* lor = lo ? lo + (long)row * nc : nullptr;
    const float* hir = hi ? hi + (long)row * nc : nullptr;
    float s = 0.f;
    #pragma unroll
    for (int k = 0; k < 8; ++k) {
        int t = m + k - 1;
        if (t & 1) continue;
        int j = t >> 1;
        if (j >= nc) continue;
        if (lor) s += c_lo[k] * lor[j];
        if (hir) s += c_hi[k] * hir[j];
    }
    z[(long)(row >> 7) * zB + (long)(row & 127) * zN + m] = s;
}

// ---------------- transposes ----------------
__global__ __launch_bounds__(256) void trM_k(
    const float* __restrict__ S, const float* __restrict__ L,
    u16* __restrict__ MS, u16* __restrict__ ML)
{
    __shared__ float sh[32][33];
    const float* src = blockIdx.z ? L : S;
    u16* dst = blockIdx.z ? ML : MS;
    const int n0 = blockIdx.x * 32, m0 = blockIdx.y * 32;
    const int tx = threadIdx.x, ty = threadIdx.y;
    #pragma unroll
    for (int k = 0; k < 4; ++k)
        sh[ty + 8 * k][tx] = src[(long)(m0 + ty + 8 * k) * 1024 + n0 + tx];
    __syncthreads();
    #pragma unroll
    for (int k = 0; k < 4; ++k)
        dst[(long)(n0 + ty + 8 * k) * 1024 + m0 + tx] = f2bf(sh[tx][ty + 8 * k]);
}

// xcl[bb][n][c] = bf16(x[bb][c][n])
__global__ __launch_bounds__(256) void trX_k(const float* __restrict__ x, u16* __restrict__ xcl)
{
    __shared__ float sh[32][33];
    const int n0 = blockIdx.x * 32, c0 = blockIdx.y * 32;
    const long bb = blockIdx.z;
    const int tx = threadIdx.x, ty = threadIdx.y;
    const float* xb = x + bb * 524288;
    u16* ob = xcl + bb * 524288;
    #pragma unroll
    for (int k = 0; k < 4; ++k)
        sh[ty + 8 * k][tx] = xb[(long)(c0 + ty + 8 * k) * 1024 + n0 + tx];
    __syncthreads();
    #pragma unroll
    for (int k = 0; k < 4; ++k)
        ob[(long)(n0 + ty + 8 * k) * 512 + c0 + tx] = f2bf(sh[tx][ty + 8 * k]);
}

// ---------------- BN ----------------
// blockIdx.y = branch
__global__ __launch_bounds__(256) void bn_stats_k(const u16* __restrict__ Y, float* __restrict__ st)
{
    __shared__ float ss[128][16];
    __shared__ float sq[128][16];
    const int br = blockIdx.y;
    const u16* Yb = Y + 128 * br;
    float* stb = st + br * 256;
    const int t = threadIdx.x;
    const int chg = t & 15, rl = t >> 4;
    const long r0 = (long)blockIdx.x * 256;
    float s[8] = {}, q[8] = {};
    for (int k = 0; k < 16; ++k) {
        long r = r0 + rl + k * 16;
        s16x8 v = *(const s16x8*)(Yb + r * 512 + chg * 8);
        #pragma unroll
        for (int e = 0; e < 8; ++e) { float f = bf2f((u16)v[e]); s[e] += f; q[e] += f * f; }
    }
    #pragma unroll
    for (int e = 0; e < 8; ++e) { ss[chg * 8 + e][rl] = s[e]; sq[chg * 8 + e][rl] = q[e]; }
    __syncthreads();
    if (t < 128) {
        float a = 0, b = 0;
        #pragma unroll
        for (int k = 0; k < 16; ++k) { a += ss[t][k]; b += sq[t][k]; }
        atomicAdd(stb + t, a); atomicAdd(stb + 128 + t, b);
    }
}

// scsh[c] = scale, scsh[512+c] = shift, c in [0,512)
__global__ __launch_bounds__(256) void bn_coef_k(
    const float* __restrict__ st, PtrQuad g, PtrQuad be, float* __restrict__ scsh)
{
    int c = blockIdx.x * 256 + threadIdx.x;
    if (c >= 512) return;
    int br = c >> 7, cc = c & 127;
    float mu = st[br * 256 + cc] * (1.0f / 65536.0f);
    float var = st[br * 256 + 128 + cc] * (1.0f / 65536.0f) - mu * mu;
    float sc = g.p[br][cc] * rsqrtf(var + 1e-5f);
    scsh[c] = sc;
    scsh[512 + c] = be.p[br][cc] - mu * sc;
}

// in-place BN+ReLU on Y ([64*1024 rows][512 ch] bf16), one chunk of 8 per thread
__global__ __launch_bounds__(256) void bn_apply_k(
    u16* __restrict__ Y, const float* __restrict__ scsh)
{
    __shared__ float sc_[512];
    __shared__ float sh_[512];
    const int t = threadIdx.x;
    #pragma unroll
    for (int q = 0; q < 2; ++q) {
        sc_[t + q * 256] = scsh[t + q * 256];
        sh_[t + q * 256] = scsh[512 + t + q * 256];
    }
    __syncthreads();
    long gid = (long)blockIdx.x * 256 + t;
    long r = gid >> 6; int cg = (int)(gid & 63);
    u16* p = Y + r * 512 + cg * 8;
    s16x8 v = *(const s16x8*)p;
    #pragma unroll
    for (int e = 0; e < 8; ++e) {
        int c = cg * 8 + e;
        float f = bf2f((u16)v[e]) * sc_[c] + sh_[c];
        v[e] = (short)f2bf(f > 0.f ? f : 0.f);
    }
    *(s16x8*)p = v;
}

// =====================================================================
extern "C" void kernel_launch(void* const* d_in, const int* in_sizes, int n_in,
                              void* d_out, int out_size, void* d_ws, size_t ws_size,
                              hipStream_t stream)
{
    const float* x      = (const float*)d_in[0];
    const float* w_init = (const float*)d_in[1];
    const float* b_init = (const float*)d_in[2];
    const float* w_pf   = (const float*)d_in[3];
    const float* b_pf   = (const float*)d_in[4];
    const float* w_fus  = (const float*)d_in[5];
    const float* b_fus  = (const float*)d_in[6];
    const float *w_b[4];
    PtrQuad g, be;
    for (int i = 0; i < 4; ++i) {
        w_b[i]  = (const float*)d_in[7 + 4 * i];
        g.p[i]  = (const float*)d_in[9 + 4 * i];
        be.p[i] = (const float*)d_in[10 + 4 * i];
    }
    float* outf = (float*)d_out;

    char* p = (char*)d_ws;
    u16* xcl   = (u16*)p;  p += 67108864;
    u16* h     = (u16*)p;  p += 67108864;
    u16* Y     = (u16*)p;  p += 67108864;
    u16* PSL   = (u16*)p;  p += 134217728;
    u16* Wi    = (u16*)p;  p += 524288;
    u16* Wp    = (u16*)p;  p += 786432;
    u16* UScULc= (u16*)p;  p += 1048576;
    u16* MrowS = (u16*)p;  p += 2097152;
    u16* MrowL = (u16*)p;  p += 2097152;
    float* eye = (float*)p; p += 4194304;
    float* Sid = (float*)p; p += 4194304;
    float* Lid = (float*)p; p += 4194304;
    float* a1  = (float*)p; p += 2109440;
    float* d1  = (float*)p; p += 2109440;
    float* a2  = (float*)p; p += 1069056;
    float* d2  = (float*)p; p += 1069056;
    float* la1 = (float*)p; p += 2109440;
    float* sa1 = (float*)p; p += 2109440;
    float* b2  = (float*)p; p += 2048;
    float* st  = (float*)p; p += 4096;   // 1024 floats
    float* zbuf= (float*)p; p += 256;    // 64 floats (zeroed each launch)
    float* scsh= (float*)p; p += 4096;

    const int KS_[4] = {3, 5, 7, 9};
    const long wpOff[4] = {0, 3 * 16384L, 8 * 16384L, 15 * 16384L};

    // ---- weight packing / fused-weight precompute ----
    cast_bf_k<<<1024, 256, 0, stream>>>(w_init, Wi, 262144);
    for (int br = 0; br < 4; ++br)
        pack_wb2_k<<<(KS_[br] * 16384 + 255) / 256, 256, 0, stream>>>(w_b[br], Wp + wpOff[br], KS_[br]);
    make_Ucum_k<<<256, 256, 0, stream>>>(w_fus, w_pf, UScULc, UScULc + 262144);
    make_bias2_k<<<2, 256, 0, stream>>>(w_fus, b_pf, b_fus, b2);

    // ---- build wavelet operators M_S, M_L from identity ----
    eye_k<<<4096, 256, 0, stream>>>(eye);
    dwt_k<<<dim3(3, 1024), 256, 0, stream>>>(eye, a1, d1, 1024, 515);
    dwt_k<<<dim3(2, 1024), 256, 0, stream>>>(a1, a2, d2, 515, 261);
    idwt_k<<<dim3(3, 1024), 256, 0, stream>>>(a2, nullptr, la1, 261, 515, 65920, 515);
    idwt_k<<<dim3(3, 1024), 256, 0, stream>>>(nullptr, d2, sa1, 261, 515, 65920, 515);
    idwt_k<<<dim3(4, 1024), 256, 0, stream>>>(la1, nullptr, Lid, 515, 1024, 131072, 1024);
    idwt_k<<<dim3(4, 1024), 256, 0, stream>>>(sa1, d1, Sid, 515, 1024, 131072, 1024);
    trM_k<<<dim3(32, 32, 2), dim3(32, 8), 0, stream>>>(Sid, Lid, MrowS, MrowL);

    // ---- activations: transpose to channel-last bf16 ----
    trX_k<<<dim3(32, 16, 64), dim3(32, 8), 0, stream>>>(x, xcl);

    // ---- conv1x1: h[n][co] = Wi x + b_init ----
    gemm_nt_k<<<dim3(8, 4, 64), 256, 0, stream>>>(Wi, 0, 512, xcl, 524288, 512, 512,
                                                  h, 524288, 512, b_init);

    // ---- zero stats + zbuf; branches: conv(taps) all-in-one; raw Y out ----
    zero_k<<<5, 256, 0, stream>>>(st, 1088);
    gemm_branch4_k<<<dim3(8, 4, 64), 256, 0, stream>>>(Wp, h, Y, (const u16*)zbuf);

    // ---- BN stats + coefficients + apply (in place) ----
    bn_stats_k<<<dim3(256, 4), 256, 0, stream>>>(Y, st);
    bn_coef_k<<<2, 256, 0, stream>>>(st, g, be, scsh);
    bn_apply_k<<<16384, 256, 0, stream>>>(Y, scsh);

    // ---- PSL = Ybn . [USc;ULc]^T (one launch) ----
    gemm_psl_k<<<dim3(8, 8, 64), 256, 0, stream>>>(Y, UScULc, PSL);

    // ---- out = M_S.PS^T + M_L.PL^T + b2 + x ----
    gemm_time_k<<<dim3(4, 8, 64), 256, 0, stream>>>(MrowS, MrowL, PSL, b2, x, outf);
}

// Round 6
// 557.487 us; speedup vs baseline: 7.1086x; 1.0251x over previous
//
#include <hip/hip_runtime.h>

typedef float  f32x4 __attribute__((ext_vector_type(4)));
typedef short  s16x8 __attribute__((ext_vector_type(8)));
typedef short  s16x4 __attribute__((ext_vector_type(4)));
typedef unsigned short u16;

struct PtrQuad { const float* p[4]; };

// ---------------- db4 filters ----------------
__constant__ float c_lo[8] = {-0.010597401784997278f, 0.032883011666982945f,
                              0.030841381835986965f, -0.18703481171888114f,
                              -0.02798376941698385f, 0.6308807679295904f,
                              0.7148465705525415f,  0.23037781330885523f};
__constant__ float c_hi[8] = {-0.23037781330885523f, 0.7148465705525415f,
                              -0.6308807679295904f, -0.02798376941698385f,
                              0.18703481171888114f, 0.030841381835986965f,
                              -0.032883011666982945f, -0.010597401784997278f};

__device__ __forceinline__ u16 f2bf(float f) {
    unsigned u = __float_as_uint(f);
    u += 0x7fffu + ((u >> 16) & 1u);
    return (u16)(u >> 16);
}
__device__ __forceinline__ float bf2f(u16 h) {
    return __uint_as_float(((unsigned)h) << 16);
}
__device__ __forceinline__ int lds_chunk(int row, int g) {
    return row * 4 + (g ^ ((row >> 1) & 3));
}
// async 16B global->LDS; LDS dest = wave-uniform base + lane*16 (linear).
__device__ __forceinline__ void gload16(void* lds, const void* g) {
    __builtin_amdgcn_global_load_lds(
        (__attribute__((address_space(1))) const void*)g,
        (__attribute__((address_space(3))) void*)lds,
        16, 0, 0);
}

// ================= generic NT MFMA GEMM (conv1x1), 2-phase dbuf =================
// D[i][j] = sum_k A[i][k]*B[j][k]; store bf16 at D + bb*dB + j*dj + i (+bias[i])
__global__ __launch_bounds__(256) void gemm_nt_k(
    const u16* __restrict__ A, long aB, int lda,
    const u16* __restrict__ B, long bB, int ldb,
    int K,
    u16* __restrict__ D, long dB, int dj,
    const float* __restrict__ bias)
{
    __shared__ s16x8 As[2][512];
    __shared__ s16x8 Bs[2][512];
    const int j0 = blockIdx.x * 128, i0 = blockIdx.y * 128;
    const long bb = blockIdx.z;
    const u16* Ab = A + bb * aB;
    const u16* Bb = B + bb * bB;
    const int tid = threadIdx.x;
    const int srow = tid >> 2, sg = tid & 3;
    const int ssg = sg ^ ((srow >> 1) & 3);
    const int l = tid & 63, w = tid >> 6;
    const int wi = (w >> 1) * 64, wj = (w & 1) * 64;
    const int lr = l & 15, lg = l >> 4;
    const long aoff0 = (long)(i0 + srow) * lda + ssg * 8;
    const long aoff1 = (long)(i0 + srow + 64) * lda + ssg * 8;
    const long boff0 = (long)(j0 + srow) * ldb + ssg * 8;
    const long boff1 = (long)(j0 + srow + 64) * ldb + ssg * 8;
    const int nt = K >> 5;
    f32x4 acc[4][4] = {};
    {
        char* a0 = (char*)&As[0][0] + w * 1024;
        char* b0 = (char*)&Bs[0][0] + w * 1024;
        gload16(a0, Ab + aoff0);
        gload16(a0 + 4096, Ab + aoff1);
        gload16(b0, Bb + boff0);
        gload16(b0 + 4096, Bb + boff1);
    }
    __syncthreads();
    for (int t = 0; t < nt; ++t) {
        const int cur = t & 1;
        if (t + 1 < nt) {
            const int k0 = (t + 1) << 5;
            char* a0 = (char*)&As[cur ^ 1][0] + w * 1024;
            char* b0 = (char*)&Bs[cur ^ 1][0] + w * 1024;
            gload16(a0, Ab + aoff0 + k0);
            gload16(a0 + 4096, Ab + aoff1 + k0);
            gload16(b0, Bb + boff0 + k0);
            gload16(b0 + 4096, Bb + boff1 + k0);
        }
        s16x8 af[4], bf[4];
        #pragma unroll
        for (int f = 0; f < 4; ++f) {
            af[f] = As[cur][lds_chunk(wi + f * 16 + lr, lg)];
            bf[f] = Bs[cur][lds_chunk(wj + f * 16 + lr, lg)];
        }
        #pragma unroll
        for (int fi = 0; fi < 4; ++fi)
            #pragma unroll
            for (int fj = 0; fj < 4; ++fj)
                acc[fi][fj] = __builtin_amdgcn_mfma_f32_16x16x32_bf16(af[fi], bf[fj], acc[fi][fj], 0, 0, 0);
        __syncthreads();
    }
    u16* Db = D + bb * dB;
    #pragma unroll
    for (int fi = 0; fi < 4; ++fi) {
        const int i = i0 + wi + fi * 16 + lg * 4;
        float b0 = 0, b1 = 0, b2v = 0, b3 = 0;
        if (bias) { b0 = bias[i]; b1 = bias[i + 1]; b2v = bias[i + 2]; b3 = bias[i + 3]; }
        #pragma unroll
        for (int fj = 0; fj < 4; ++fj) {
            const int j = j0 + wj + fj * 16 + lr;
            f32x4 d = acc[fi][fj];
            s16x4 o;
            o[0] = (short)f2bf(d[0] + b0); o[1] = (short)f2bf(d[1] + b1);
            o[2] = (short)f2bf(d[2] + b2v); o[3] = (short)f2bf(d[3] + b3);
            *(s16x4*)(Db + (long)j * dj + i) = o;
        }
    }
}

// ================= merged branch conv (4 branches) + fused BN partial stats =================
// blockIdx.y = br; taps = 3+2*br; OOB rows read zeroed zbuf line.
// part[(br*512 + bb*8 + jblk)*256 + {co,128+co}] = per-block sum / sumsq over n.
__global__ __launch_bounds__(256) void gemm_branch4_k(
    const u16* __restrict__ WpAll,
    const u16* __restrict__ H,
    u16* __restrict__ Y,
    const u16* __restrict__ zbuf,
    float* __restrict__ part)
{
    __shared__ s16x8 As[2][512];
    __shared__ s16x8 Bs[2][512];
    __shared__ float sred[2][128];
    __shared__ float qred[2][128];
    const int j0 = blockIdx.x * 128;
    const int br = blockIdx.y;
    const long bb = blockIdx.z;
    const int taps = 3 + 2 * br;
    const int pad = 1 + br;
    const u16* Wp = WpAll + (long)(br * br + 2 * br) * 16384;
    const u16* Hb = H + bb * 524288 + 128 * br;
    const int tid = threadIdx.x;
    const int srow = tid >> 2, sg = tid & 3;
    const int ssg = sg ^ ((srow >> 1) & 3);
    const int l = tid & 63, w = tid >> 6;
    const int wi = (w >> 1) * 64, wj = (w & 1) * 64;
    const int lr = l & 15, lg = l >> 4;
    const int lda = taps * 128;
    const int nt = taps * 4;
    auto stage = [&](int buf, int t) {
        const int k0 = t << 5;
        const int tap = k0 >> 7, kc = k0 & 127;
        const int shift = tap - pad;
        char* a0 = (char*)&As[buf][0] + w * 1024;
        char* b0 = (char*)&Bs[buf][0] + w * 1024;
        gload16(a0, Wp + (long)srow * lda + k0 + ssg * 8);
        gload16(a0 + 4096, Wp + (long)(srow + 64) * lda + k0 + ssg * 8);
        int n0r = j0 + srow + shift;
        int n1r = n0r + 64;
        const u16* s0 = (n0r >= 0 && n0r < 1024) ? (Hb + (long)n0r * 512 + kc + ssg * 8) : zbuf;
        const u16* s1 = (n1r >= 0 && n1r < 1024) ? (Hb + (long)n1r * 512 + kc + ssg * 8) : zbuf;
        gload16(b0, s0);
        gload16(b0 + 4096, s1);
    };
    f32x4 acc[4][4] = {};
    stage(0, 0);
    __syncthreads();
    for (int t = 0; t < nt; ++t) {
        const int cur = t & 1;
        if (t + 1 < nt) stage(cur ^ 1, t + 1);
        s16x8 af[4], bf[4];
        #pragma unroll
        for (int f = 0; f < 4; ++f) {
            af[f] = As[cur][lds_chunk(wi + f * 16 + lr, lg)];
            bf[f] = Bs[cur][lds_chunk(wj + f * 16 + lr, lg)];
        }
        #pragma unroll
        for (int fi = 0; fi < 4; ++fi)
            #pragma unroll
            for (int fj = 0; fj < 4; ++fj)
                acc[fi][fj] = __builtin_amdgcn_mfma_f32_16x16x32_bf16(af[fi], bf[fj], acc[fi][fj], 0, 0, 0);
        __syncthreads();
    }
    u16* Db = Y + bb * 524288 + 128 * br;
    #pragma unroll
    for (int fi = 0; fi < 4; ++fi) {
        const int i = wi + fi * 16 + lg * 4;
        #pragma unroll
        for (int fj = 0; fj < 4; ++fj) {
            const int j = j0 + wj + fj * 16 + lr;
            f32x4 d = acc[fi][fj];
            s16x4 o;
            o[0] = (short)f2bf(d[0]); o[1] = (short)f2bf(d[1]);
            o[2] = (short)f2bf(d[2]); o[3] = (short)f2bf(d[3]);
            *(s16x4*)(Db + (long)j * 512 + i) = o;
        }
    }
    // ---- BN partial stats over this block's 128 n positions ----
    float sv[16], qv[16];
    #pragma unroll
    for (int fi = 0; fi < 4; ++fi)
        #pragma unroll
        for (int e = 0; e < 4; ++e) {
            float s = 0.f, q = 0.f;
            #pragma unroll
            for (int fj = 0; fj < 4; ++fj) { float d = acc[fi][fj][e]; s += d; q += d * d; }
            sv[fi * 4 + e] = s; qv[fi * 4 + e] = q;
        }
    #pragma unroll
    for (int m = 1; m < 16; m <<= 1) {
        #pragma unroll
        for (int r = 0; r < 16; ++r) {
            sv[r] += __shfl_xor(sv[r], m, 64);
            qv[r] += __shfl_xor(qv[r], m, 64);
        }
    }
    if (lr == 0) {
        #pragma unroll
        for (int r = 0; r < 16; ++r) {
            int co = wi + (r >> 2) * 16 + lg * 4 + (r & 3);
            sred[w & 1][co] = sv[r];
            qred[w & 1][co] = qv[r];
        }
    }
    __syncthreads();
    if (tid < 128) {
        long blk = (long)br * 512 + bb * 8 + blockIdx.x;
        part[blk * 256 + tid]       = sred[0][tid] + sred[1][tid];
        part[blk * 256 + 128 + tid] = qred[0][tid] + qred[1][tid];
    }
}

// ================= PS+PL combined GEMM (pure; Y already BN'd), 2-phase =================
__global__ __launch_bounds__(256) void gemm_psl_k(
    const u16* __restrict__ Ybn,
    const u16* __restrict__ Bmat,
    u16* __restrict__ PSL)
{
    __shared__ s16x8 As[2][512];
    __shared__ s16x8 Bs[2][512];
    // XCD-aware bijective swizzle: grid 8x8x64 = 4096 = 8*512
    int flat = blockIdx.x + 8 * (blockIdx.y + 8 * blockIdx.z);
    int swz = (flat & 7) * 512 + (flat >> 3);
    const int j0 = (swz & 7) * 128;
    const int i0 = ((swz >> 3) & 7) * 128;
    const long bb = swz >> 6;
    const int tid = threadIdx.x;
    const u16* Ab = Ybn + bb * 524288;
    const int srow = tid >> 2, sg = tid & 3;
    const int ssg = sg ^ ((srow >> 1) & 3);
    const int l = tid & 63, w = tid >> 6;
    const int wi = (w >> 1) * 64, wj = (w & 1) * 64;
    const int lr = l & 15, lg = l >> 4;
    const long aoff0 = (long)(i0 + srow) * 512 + ssg * 8;
    const long aoff1 = (long)(i0 + srow + 64) * 512 + ssg * 8;
    const long boff0 = (long)(j0 + srow) * 512 + ssg * 8;
    const long boff1 = (long)(j0 + srow + 64) * 512 + ssg * 8;
    f32x4 acc[4][4] = {};
    {
        char* a0 = (char*)&As[0][0] + w * 1024;
        char* b0 = (char*)&Bs[0][0] + w * 1024;
        gload16(a0, Ab + aoff0);
        gload16(a0 + 4096, Ab + aoff1);
        gload16(b0, Bmat + boff0);
        gload16(b0 + 4096, Bmat + boff1);
    }
    __syncthreads();
    for (int t = 0; t < 16; ++t) {
        const int cur = t & 1;
        if (t + 1 < 16) {
            const int k0 = (t + 1) << 5;
            char* a0 = (char*)&As[cur ^ 1][0] + w * 1024;
            char* b0 = (char*)&Bs[cur ^ 1][0] + w * 1024;
            gload16(a0, Ab + aoff0 + k0);
            gload16(a0 + 4096, Ab + aoff1 + k0);
            gload16(b0, Bmat + boff0 + k0);
            gload16(b0 + 4096, Bmat + boff1 + k0);
        }
        s16x8 af[4], bf[4];
        #pragma unroll
        for (int f = 0; f < 4; ++f) {
            af[f] = As[cur][lds_chunk(wi + f * 16 + lr, lg)];
            bf[f] = Bs[cur][lds_chunk(wj + f * 16 + lr, lg)];
        }
        #pragma unroll
        for (int fi = 0; fi < 4; ++fi)
            #pragma unroll
            for (int fj = 0; fj < 4; ++fj)
                acc[fi][fj] = __builtin_amdgcn_mfma_f32_16x16x32_bf16(af[fi], bf[fj], acc[fi][fj], 0, 0, 0);
        __syncthreads();
    }
    u16* Db = PSL + bb * 1048576;
    #pragma unroll
    for (int fi = 0; fi < 4; ++fi) {
        const int i = i0 + wi + fi * 16 + lg * 4;
        #pragma unroll
        for (int fj = 0; fj < 4; ++fj) {
            const int j = j0 + wj + fj * 16 + lr;
            f32x4 d = acc[fi][fj];
            s16x4 o;
            o[0] = (short)f2bf(d[0]); o[1] = (short)f2bf(d[1]);
            o[2] = (short)f2bf(d[2]); o[3] = (short)f2bf(d[3]);
            *(s16x4*)(Db + (long)j * 1024 + i) = o;
        }
    }
}

// ================= time-axis GEMM (band ±64, dual pass, f32 out), 2-phase =================
__global__ __launch_bounds__(256) void gemm_time_k(
    const u16* __restrict__ MS, const u16* __restrict__ ML,
    const u16* __restrict__ PSL,
    const float* __restrict__ b2, const float* __restrict__ X,
    float* __restrict__ OUT)
{
    __shared__ s16x8 As[2][512];
    __shared__ s16x8 Bs[2][512];
    // XCD-aware bijective swizzle: grid 4x8x64 = 2048 = 8*256
    int flat = blockIdx.x + 4 * (blockIdx.y + 8 * blockIdx.z);
    int swz = (flat & 7) * 256 + (flat >> 3);
    const int j0 = (swz & 3) * 128;          // co tile
    const int i0 = ((swz >> 2) & 7) * 128;   // n tile
    const long bb = swz >> 5;
    const int tid = threadIdx.x;
    const int srow = tid >> 2, sg = tid & 3;
    const int ssg = sg ^ ((srow >> 1) & 3);
    const int l = tid & 63, w = tid >> 6;
    const int wi = (w >> 1) * 64, wj = (w & 1) * 64;
    const int lr = l & 15, lg = l >> 4;
    // operator support is +-22; band +-64/+192 has 3x margin
    const int klo = (i0 - 64) > 0 ? (i0 - 64) : 0;
    const int khi = (i0 + 192) < 1024 ? (i0 + 192) : 1024;
    const int nk = (khi - klo) >> 5;
    const int nt = nk * 2;
    auto stage = [&](int buf, int t) {
        const int pass = (t >= nk) ? 1 : 0;
        const int k0 = klo + ((t - (pass ? nk : 0)) << 5);
        const u16* A = pass ? ML : MS;
        const u16* B = PSL + bb * 1048576 + (long)pass * 524288;
        char* a0 = (char*)&As[buf][0] + w * 1024;
        char* b0 = (char*)&Bs[buf][0] + w * 1024;
        gload16(a0, A + (long)(i0 + srow) * 1024 + k0 + ssg * 8);
        gload16(a0 + 4096, A + (long)(i0 + srow + 64) * 1024 + k0 + ssg * 8);
        gload16(b0, B + (long)(j0 + srow) * 1024 + k0 + ssg * 8);
        gload16(b0 + 4096, B + (long)(j0 + srow + 64) * 1024 + k0 + ssg * 8);
    };
    f32x4 acc[4][4] = {};
    stage(0, 0);
    __syncthreads();
    for (int t = 0; t < nt; ++t) {
        const int cur = t & 1;
        if (t + 1 < nt) stage(cur ^ 1, t + 1);
        s16x8 af[4], bf[4];
        #pragma unroll
        for (int f = 0; f < 4; ++f) {
            af[f] = As[cur][lds_chunk(wi + f * 16 + lr, lg)];
            bf[f] = Bs[cur][lds_chunk(wj + f * 16 + lr, lg)];
        }
        #pragma unroll
        for (int fi = 0; fi < 4; ++fi)
            #pragma unroll
            for (int fj = 0; fj < 4; ++fj)
                acc[fi][fj] = __builtin_amdgcn_mfma_f32_16x16x32_bf16(af[fi], bf[fj], acc[fi][fj], 0, 0, 0);
        __syncthreads();
    }
    float* Ob = OUT + bb * 524288;
    const float* Xb = X + bb * 524288;
    #pragma unroll
    for (int fi = 0; fi < 4; ++fi) {
        const int i = i0 + wi + fi * 16 + lg * 4;
        #pragma unroll
        for (int fj = 0; fj < 4; ++fj) {
            const int j = j0 + wj + fj * 16 + lr;
            const long a = (long)j * 1024 + i;
            f32x4 d = acc[fi][fj];
            const float bj = b2[j];
            f32x4 xv = *(const f32x4*)(Xb + a);
            f32x4 o;
            o[0] = d[0] + bj + xv[0]; o[1] = d[1] + bj + xv[1];
            o[2] = d[2] + bj + xv[2]; o[3] = d[3] + bj + xv[3];
            *(f32x4*)(Ob + a) = o;
        }
    }
}

// ================= packing / small kernels =================
__global__ __launch_bounds__(256) void cast_bf_k(const float* __restrict__ s, u16* __restrict__ d, int n)
{
    int i = blockIdx.x * 256 + threadIdx.x;
    if (i < n) d[i] = f2bf(s[i]);
}

// d[co*(taps*128) + tap*128 + ci] = s[(co*128+ci)*taps + tap]   (w_b is (co,ci,tap))
__global__ __launch_bounds__(256) void pack_wb2_k(const float* __restrict__ s, u16* __restrict__ d, int taps)
{
    int i = blockIdx.x * 256 + threadIdx.x;
    if (i >= taps * 16384) return;
    int stride = taps * 128;
    int co = i / stride;
    int rem = i - co * stride;
    int tap = rem >> 7, ci = rem & 127;
    d[i] = f2bf(s[(long)(co * 128 + ci) * taps + tap]);
}

// USc[co][128b+cc] = suffix-sum_b of (wfus_b . wpf_S); ULc = prefix-sum of (wfus_b . wpf_L)
__global__ __launch_bounds__(256) void make_Ucum_k(
    const float* __restrict__ wf, const float* __restrict__ wp,
    u16* __restrict__ USc, u16* __restrict__ ULc)
{
    int gid = blockIdx.x * 256 + threadIdx.x;   // 512*128
    int co = gid >> 7, cc = gid & 127;
    float us[4], ul[4];
    #pragma unroll
    for (int b = 0; b < 4; ++b) {
        float s = 0.f, t = 0.f;
        for (int q = 0; q < 128; ++q) {
            float f = wf[(long)co * 512 + b * 128 + q];
            s += f * wp[q * 256 + cc];
            t += f * wp[q * 256 + 128 + cc];
        }
        us[b] = s; ul[b] = t;
    }
    float suf = 0.f;
    for (int b = 3; b >= 0; --b) { suf += us[b]; USc[(long)co * 512 + b * 128 + cc] = f2bf(suf); }
    float pre = 0.f;
    for (int b = 0; b < 4; ++b) { pre += ul[b]; ULc[(long)co * 512 + b * 128 + cc] = f2bf(pre); }
}

__global__ __launch_bounds__(256) void make_bias2_k(
    const float* __restrict__ wf, const float* __restrict__ bpf,
    const float* __restrict__ bfus, float* __restrict__ b2)
{
    int co = blockIdx.x * 256 + threadIdx.x;
    if (co >= 512) return;
    float s = bfus[co];
    for (int j = 0; j < 512; ++j) s += wf[(long)co * 512 + j] * bpf[j & 127];
    b2[co] = s;
}

__global__ __launch_bounds__(256) void eye_k(float* __restrict__ I)
{
    int i = blockIdx.x * 256 + threadIdx.x;
    I[i] = ((i >> 10) == (i & 1023)) ? 1.0f : 0.0f;
}

__global__ __launch_bounds__(256) void zero_k(float* __restrict__ p, int n)
{
    int i = blockIdx.x * 256 + threadIdx.x;
    if (i < n) p[i] = 0.f;
}

// ---------------- DWT / IDWT (f32, used only for M-build on identity) ----------------
__global__ __launch_bounds__(256) void dwt_k(
    const float* __restrict__ x, float* __restrict__ a, float* __restrict__ d,
    int n_in, int n_out)
{
    const int row = blockIdx.y;
    const int m = blockIdx.x * 256 + threadIdx.x;
    if (m >= n_out) return;
    const float* xr = x + (long)row * n_in;
    float sa = 0.f, sd = 0.f;
    #pragma unroll
    for (int j = 0; j < 8; ++j) {
        int t = 2 * m + 1 - j;
        t = (t < 0) ? (-t - 1) : t;
        t = (t >= n_in) ? (2 * n_in - 1 - t) : t;
        const float v = xr[t];
        sa += v * c_lo[j];
        sd += v * c_hi[j];
    }
    a[(long)row * n_out + m] = sa;
    d[(long)row * n_out + m] = sd;
}

__global__ __launch_bounds__(256) void idwt_k(
    const float* __restrict__ lo, const float* __restrict__ hi,
    float* __restrict__ z, int nc, int n_out, long zB, int zN)
{
    const int row = blockIdx.y;
    const int m = blockIdx.x * 256 + threadIdx.x;
    if (m >= n_out) return;
    const float* lor = lo ? lo + (long)row * nc : nullptr;
    const float* hir = hi ? hi + (long)row * nc : nullptr;
    float s = 0.f;
    #pragma unroll
    for (int k = 0; k < 8; ++k) {
        int t = m + k - 1;
        if (t & 1) continue;
        int j = t >> 1;
        if (j >= nc) continue;
        if (lor) s += c_lo[k] * lor[j];
        if (hir) s += c_hi[k] * hir[j];
    }
    z[(long)(row >> 7) * zB + (long)(row & 127) * zN + m] = s;
}

// ---------------- transposes ----------------
__global__ __launch_bounds__(256) void trM_k(
    const float* __restrict__ S, const float* __restrict__ L,
    u16* __restrict__ MS, u16* __restrict__ ML)
{
    __shared__ float sh[32][33];
    const float* src = blockIdx.z ? L : S;
    u16* dst = blockIdx.z ? ML : MS;
    const int n0 = blockIdx.x * 32, m0 = blockIdx.y * 32;
    const int tx = threadIdx.x, ty = threadIdx.y;
    #pragma unroll
    for (int k = 0; k < 4; ++k)
        sh[ty + 8 * k][tx] = src[(long)(m0 + ty + 8 * k) * 1024 + n0 + tx];
    __syncthreads();
    #pragma unroll
    for (int k = 0; k < 4; ++k)
        dst[(long)(n0 + ty + 8 * k) * 1024 + m0 + tx] = f2bf(sh[tx][ty + 8 * k]);
}

// xcl[bb][n][c] = bf16(x[bb][c][n])
__global__ __launch_bounds__(256) void trX_k(const float* __restrict__ x, u16* __restrict__ xcl)
{
    __shared__ float sh[32][33];
    const int n0 = blockIdx.x * 32, c0 = blockIdx.y * 32;
    const long bb = blockIdx.z;
    const int tx = threadIdx.x, ty = threadIdx.y;
    const float* xb = x + bb * 524288;
    u16* ob = xcl + bb * 524288;
    #pragma unroll
    for (int k = 0; k < 4; ++k)
        sh[ty + 8 * k][tx] = xb[(long)(c0 + ty + 8 * k) * 1024 + n0 + tx];
    __syncthreads();
    #pragma unroll
    for (int k = 0; k < 4; ++k)
        ob[(long)(n0 + ty + 8 * k) * 512 + c0 + tx] = f2bf(sh[tx][ty + 8 * k]);
}

// ---------------- BN ----------------
// reduce per-block partials: scsh[c]=scale, scsh[512+c]=shift
__global__ __launch_bounds__(256) void bn_coef_k(
    const float* __restrict__ part, PtrQuad g, PtrQuad be, float* __restrict__ scsh)
{
    int c = blockIdx.x * 256 + threadIdx.x;
    if (c >= 512) return;
    int br = c >> 7, cc = c & 127;
    const float* pb = part + (long)br * 131072;   // 512 blocks * 256
    float s = 0.f, q = 0.f;
    for (int pidx = 0; pidx < 512; ++pidx) {
        s += pb[pidx * 256 + cc];
        q += pb[pidx * 256 + 128 + cc];
    }
    float mu = s * (1.0f / 65536.0f);
    float var = q * (1.0f / 65536.0f) - mu * mu;
    float sc = g.p[br][cc] * rsqrtf(var + 1e-5f);
    scsh[c] = sc;
    scsh[512 + c] = be.p[br][cc] - mu * sc;
}

// in-place BN+ReLU on Y ([64*1024 rows][512 ch] bf16)
__global__ __launch_bounds__(256) void bn_apply_k(
    u16* __restrict__ Y, const float* __restrict__ scsh)
{
    __shared__ float sc_[512];
    __shared__ float sh_[512];
    const int t = threadIdx.x;
    #pragma unroll
    for (int q = 0; q < 2; ++q) {
        sc_[t + q * 256] = scsh[t + q * 256];
        sh_[t + q * 256] = scsh[512 + t + q * 256];
    }
    __syncthreads();
    long gid = (long)blockIdx.x * 256 + t;
    long r = gid >> 6; int cg = (int)(gid & 63);
    u16* p = Y + r * 512 + cg * 8;
    s16x8 v = *(const s16x8*)p;
    #pragma unroll
    for (int e = 0; e < 8; ++e) {
        int c = cg * 8 + e;
        float f = bf2f((u16)v[e]) * sc_[c] + sh_[c];
        v[e] = (short)f2bf(f > 0.f ? f : 0.f);
    }
    *(s16x8*)p = v;
}

// =====================================================================
extern "C" void kernel_launch(void* const* d_in, const int* in_sizes, int n_in,
                              void* d_out, int out_size, void* d_ws, size_t ws_size,
                              hipStream_t stream)
{
    const float* x      = (const float*)d_in[0];
    const float* w_init = (const float*)d_in[1];
    const float* b_init = (const float*)d_in[2];
    const float* w_pf   = (const float*)d_in[3];
    const float* b_pf   = (const float*)d_in[4];
    const float* w_fus  = (const float*)d_in[5];
    const float* b_fus  = (const float*)d_in[6];
    const float *w_b[4];
    PtrQuad g, be;
    for (int i = 0; i < 4; ++i) {
        w_b[i]  = (const float*)d_in[7 + 4 * i];
        g.p[i]  = (const float*)d_in[9 + 4 * i];
        be.p[i] = (const float*)d_in[10 + 4 * i];
    }
    float* outf = (float*)d_out;

    char* p = (char*)d_ws;
    u16* xcl   = (u16*)p;  p += 67108864;
    u16* h     = (u16*)p;  p += 67108864;
    u16* Y     = (u16*)p;  p += 67108864;
    u16* PSL   = (u16*)p;  p += 134217728;
    u16* Wi    = (u16*)p;  p += 524288;
    u16* Wp    = (u16*)p;  p += 786432;
    u16* UScULc= (u16*)p;  p += 1048576;
    u16* MrowS = (u16*)p;  p += 2097152;
    u16* MrowL = (u16*)p;  p += 2097152;
    float* eye = (float*)p; p += 4194304;
    float* Sid = (float*)p; p += 4194304;
    float* Lid = (float*)p; p += 4194304;
    float* a1  = (float*)p; p += 2109440;
    float* d1  = (float*)p; p += 2109440;
    float* a2  = (float*)p; p += 1069056;
    float* d2  = (float*)p; p += 1069056;
    float* la1 = (float*)p; p += 2109440;
    float* sa1 = (float*)p; p += 2109440;
    float* b2  = (float*)p; p += 2048;
    float* zbuf= (float*)p; p += 256;    // 64 floats (zeroed each launch)
    float* scsh= (float*)p; p += 4096;
    float* part= (float*)p; p += 2097152; // 2048 blocks * 256 floats

    const int KS_[4] = {3, 5, 7, 9};
    const long wpOff[4] = {0, 3 * 16384L, 8 * 16384L, 15 * 16384L};

    // ---- weight packing / fused-weight precompute ----
    cast_bf_k<<<1024, 256, 0, stream>>>(w_init, Wi, 262144);
    for (int br = 0; br < 4; ++br)
        pack_wb2_k<<<(KS_[br] * 16384 + 255) / 256, 256, 0, stream>>>(w_b[br], Wp + wpOff[br], KS_[br]);
    make_Ucum_k<<<256, 256, 0, stream>>>(w_fus, w_pf, UScULc, UScULc + 262144);
    make_bias2_k<<<2, 256, 0, stream>>>(w_fus, b_pf, b_fus, b2);

    // ---- build wavelet operators M_S, M_L from identity ----
    eye_k<<<4096, 256, 0, stream>>>(eye);
    dwt_k<<<dim3(3, 1024), 256, 0, stream>>>(eye, a1, d1, 1024, 515);
    dwt_k<<<dim3(2, 1024), 256, 0, stream>>>(a1, a2, d2, 515, 261);
    idwt_k<<<dim3(3, 1024), 256, 0, stream>>>(a2, nullptr, la1, 261, 515, 65920, 515);
    idwt_k<<<dim3(3, 1024), 256, 0, stream>>>(nullptr, d2, sa1, 261, 515, 65920, 515);
    idwt_k<<<dim3(4, 1024), 256, 0, stream>>>(la1, nullptr, Lid, 515, 1024, 131072, 1024);
    idwt_k<<<dim3(4, 1024), 256, 0, stream>>>(sa1, d1, Sid, 515, 1024, 131072, 1024);
    trM_k<<<dim3(32, 32, 2), dim3(32, 8), 0, stream>>>(Sid, Lid, MrowS, MrowL);

    // ---- activations: transpose to channel-last bf16 ----
    trX_k<<<dim3(32, 16, 64), dim3(32, 8), 0, stream>>>(x, xcl);

    // ---- conv1x1: h[n][co] = Wi x + b_init ----
    gemm_nt_k<<<dim3(8, 4, 64), 256, 0, stream>>>(Wi, 0, 512, xcl, 524288, 512, 512,
                                                  h, 524288, 512, b_init);

    // ---- zero zbuf; branches: conv(taps) all-in-one + fused BN partials ----
    zero_k<<<1, 256, 0, stream>>>(zbuf, 64);
    gemm_branch4_k<<<dim3(8, 4, 64), 256, 0, stream>>>(Wp, h, Y, (const u16*)zbuf, part);

    // ---- BN coefficients (reduce partials) + apply (in place) ----
    bn_coef_k<<<2, 256, 0, stream>>>(part, g, be, scsh);
    bn_apply_k<<<16384, 256, 0, stream>>>(Y, scsh);

    // ---- PSL = Ybn . [USc;ULc]^T (one launch) ----
    gemm_psl_k<<<dim3(8, 8, 64), 256, 0, stream>>>(Y, UScULc, PSL);

    // ---- out = M_S.PS^T + M_L.PL^T + b2 + x ----
    gemm_time_k<<<dim3(4, 8, 64), 256, 0, stream>>>(MrowS, MrowL, PSL, b2, x, outf);
}

// Round 7
// 539.366 us; speedup vs baseline: 7.3474x; 1.0336x over previous
//
#include <hip/hip_runtime.h>

typedef float  f32x4 __attribute__((ext_vector_type(4)));
typedef short  s16x8 __attribute__((ext_vector_type(8)));
typedef short  s16x4 __attribute__((ext_vector_type(4)));
typedef unsigned short u16;

struct PtrQuad { const float* p[4]; };

// ---------------- db4 filters ----------------
__constant__ float c_lo[8] = {-0.010597401784997278f, 0.032883011666982945f,
                              0.030841381835986965f, -0.18703481171888114f,
                              -0.02798376941698385f, 0.6308807679295904f,
                              0.7148465705525415f,  0.23037781330885523f};
__constant__ float c_hi[8] = {-0.23037781330885523f, 0.7148465705525415f,
                              -0.6308807679295904f, -0.02798376941698385f,
                              0.18703481171888114f, 0.030841381835986965f,
                              -0.032883011666982945f, -0.010597401784997278f};

__device__ __forceinline__ u16 f2bf(float f) {
    unsigned u = __float_as_uint(f);
    u += 0x7fffu + ((u >> 16) & 1u);
    return (u16)(u >> 16);
}
__device__ __forceinline__ float bf2f(u16 h) {
    return __uint_as_float(((unsigned)h) << 16);
}
__device__ __forceinline__ int lds_chunk(int row, int g) {
    return row * 4 + (g ^ ((row >> 1) & 3));
}
// async 16B global->LDS; LDS dest = wave-uniform base + lane*16 (linear).
__device__ __forceinline__ void gload16(void* lds, const void* g) {
    __builtin_amdgcn_global_load_lds(
        (__attribute__((address_space(1))) const void*)g,
        (__attribute__((address_space(3))) void*)lds,
        16, 0, 0);
}
// counted-vmcnt wait (T4): never drain to 0 mid-loop
__device__ __forceinline__ void pipe_wait(int t, int nt) {
    if (t + 2 < nt)      asm volatile("s_waitcnt vmcnt(8)" ::: "memory");
    else if (t + 1 < nt) asm volatile("s_waitcnt vmcnt(4)" ::: "memory");
    else                 asm volatile("s_waitcnt vmcnt(0)" ::: "memory");
    __builtin_amdgcn_s_barrier();
    __builtin_amdgcn_sched_barrier(0);
}
__device__ __forceinline__ void pipe_endbar() {
    __builtin_amdgcn_sched_barrier(0);
    __builtin_amdgcn_s_barrier();
}

// ================= generic NT MFMA GEMM (conv1x1), depth-3 pipeline =================
// D[i][j] = sum_k A[i][k]*B[j][k]; store bf16 at D + bb*dB + j*dj + i (+bias[i])
__global__ __launch_bounds__(256) void gemm_nt_k(
    const u16* __restrict__ A, long aB, int lda,
    const u16* __restrict__ B, long bB, int ldb,
    int K,
    u16* __restrict__ D, long dB, int dj,
    const float* __restrict__ bias)
{
    __shared__ s16x8 As[3 * 512];
    __shared__ s16x8 Bs[3 * 512];
    // XCD swizzle: grid 8x4x64 = 2048 = 8*256
    int flat = blockIdx.x + 8 * (blockIdx.y + 4 * blockIdx.z);
    int swz = (flat & 7) * 256 + (flat >> 3);
    const int j0 = (swz & 7) * 128;
    const int i0 = ((swz >> 3) & 3) * 128;
    const long bb = swz >> 5;
    const u16* Ab = A + bb * aB;
    const u16* Bb = B + bb * bB;
    const int tid = threadIdx.x;
    const int srow = tid >> 2, sg = tid & 3;
    const int ssg = sg ^ ((srow >> 1) & 3);
    const int l = tid & 63, w = tid >> 6;
    const int wi = (w >> 1) * 64, wj = (w & 1) * 64;
    const int lr = l & 15, lg = l >> 4;
    const long aoff0 = (long)(i0 + srow) * lda + ssg * 8;
    const long aoff1 = (long)(i0 + srow + 64) * lda + ssg * 8;
    const long boff0 = (long)(j0 + srow) * ldb + ssg * 8;
    const long boff1 = (long)(j0 + srow + 64) * ldb + ssg * 8;
    const int nt = K >> 5;
    auto stage = [&](int buf, int t) {
        const int k0 = t << 5;
        char* a0 = (char*)As + buf * 8192 + w * 1024;
        char* b0 = (char*)Bs + buf * 8192 + w * 1024;
        gload16(a0, Ab + aoff0 + k0);
        gload16(a0 + 4096, Ab + aoff1 + k0);
        gload16(b0, Bb + boff0 + k0);
        gload16(b0 + 4096, Bb + boff1 + k0);
    };
    f32x4 acc[4][4] = {};
    stage(0, 0);
    if (nt > 1) stage(1, 1);
    int cur = 0;
    for (int t = 0; t < nt; ++t) {
        if (t + 2 < nt) stage((cur + 2) % 3, t + 2);
        pipe_wait(t, nt);
        s16x8 af[4], bf[4];
        #pragma unroll
        for (int f = 0; f < 4; ++f) {
            af[f] = As[cur * 512 + lds_chunk(wi + f * 16 + lr, lg)];
            bf[f] = Bs[cur * 512 + lds_chunk(wj + f * 16 + lr, lg)];
        }
        #pragma unroll
        for (int fi = 0; fi < 4; ++fi)
            #pragma unroll
            for (int fj = 0; fj < 4; ++fj)
                acc[fi][fj] = __builtin_amdgcn_mfma_f32_16x16x32_bf16(af[fi], bf[fj], acc[fi][fj], 0, 0, 0);
        pipe_endbar();
        cur = (cur + 1) % 3;
    }
    u16* Db = D + bb * dB;
    #pragma unroll
    for (int fi = 0; fi < 4; ++fi) {
        const int i = i0 + wi + fi * 16 + lg * 4;
        float b0 = 0, b1 = 0, b2v = 0, b3 = 0;
        if (bias) { b0 = bias[i]; b1 = bias[i + 1]; b2v = bias[i + 2]; b3 = bias[i + 3]; }
        #pragma unroll
        for (int fj = 0; fj < 4; ++fj) {
            const int j = j0 + wj + fj * 16 + lr;
            f32x4 d = acc[fi][fj];
            s16x4 o;
            o[0] = (short)f2bf(d[0] + b0); o[1] = (short)f2bf(d[1] + b1);
            o[2] = (short)f2bf(d[2] + b2v); o[3] = (short)f2bf(d[3] + b3);
            *(s16x4*)(Db + (long)j * dj + i) = o;
        }
    }
}

// ================= merged branch conv (4 branches) + fused BN partial stats =================
__global__ __launch_bounds__(256) void gemm_branch4_k(
    const u16* __restrict__ WpAll,
    const u16* __restrict__ H,
    u16* __restrict__ Y,
    const u16* __restrict__ zbuf,
    float* __restrict__ part)
{
    __shared__ s16x8 As[3 * 512];
    __shared__ s16x8 Bs[3 * 512];
    __shared__ float sred[2][128];
    __shared__ float qred[2][128];
    // XCD swizzle: grid 8x4x64 = 2048 = 8*256
    int flat = blockIdx.x + 8 * (blockIdx.y + 4 * blockIdx.z);
    int swz = (flat & 7) * 256 + (flat >> 3);
    const int jblk = swz & 7;
    const int br = (swz >> 3) & 3;
    const long bb = swz >> 5;
    const int j0 = jblk * 128;
    const int taps = 3 + 2 * br;
    const int pad = 1 + br;
    const u16* Wp = WpAll + (long)(br * br + 2 * br) * 16384;
    const u16* Hb = H + bb * 524288 + 128 * br;
    const int tid = threadIdx.x;
    const int srow = tid >> 2, sg = tid & 3;
    const int ssg = sg ^ ((srow >> 1) & 3);
    const int l = tid & 63, w = tid >> 6;
    const int wi = (w >> 1) * 64, wj = (w & 1) * 64;
    const int lr = l & 15, lg = l >> 4;
    const int lda = taps * 128;
    const int nt = taps * 4;
    auto stage = [&](int buf, int t) {
        const int k0 = t << 5;
        const int tap = k0 >> 7, kc = k0 & 127;
        const int shift = tap - pad;
        char* a0 = (char*)As + buf * 8192 + w * 1024;
        char* b0 = (char*)Bs + buf * 8192 + w * 1024;
        gload16(a0, Wp + (long)srow * lda + k0 + ssg * 8);
        gload16(a0 + 4096, Wp + (long)(srow + 64) * lda + k0 + ssg * 8);
        int n0r = j0 + srow + shift;
        int n1r = n0r + 64;
        const u16* s0 = (n0r >= 0 && n0r < 1024) ? (Hb + (long)n0r * 512 + kc + ssg * 8) : zbuf;
        const u16* s1 = (n1r >= 0 && n1r < 1024) ? (Hb + (long)n1r * 512 + kc + ssg * 8) : zbuf;
        gload16(b0, s0);
        gload16(b0 + 4096, s1);
    };
    f32x4 acc[4][4] = {};
    stage(0, 0);
    stage(1, 1);
    int cur = 0;
    for (int t = 0; t < nt; ++t) {
        if (t + 2 < nt) stage((cur + 2) % 3, t + 2);
        pipe_wait(t, nt);
        s16x8 af[4], bf[4];
        #pragma unroll
        for (int f = 0; f < 4; ++f) {
            af[f] = As[cur * 512 + lds_chunk(wi + f * 16 + lr, lg)];
            bf[f] = Bs[cur * 512 + lds_chunk(wj + f * 16 + lr, lg)];
        }
        #pragma unroll
        for (int fi = 0; fi < 4; ++fi)
            #pragma unroll
            for (int fj = 0; fj < 4; ++fj)
                acc[fi][fj] = __builtin_amdgcn_mfma_f32_16x16x32_bf16(af[fi], bf[fj], acc[fi][fj], 0, 0, 0);
        pipe_endbar();
        cur = (cur + 1) % 3;
    }
    u16* Db = Y + bb * 524288 + 128 * br;
    #pragma unroll
    for (int fi = 0; fi < 4; ++fi) {
        const int i = wi + fi * 16 + lg * 4;
        #pragma unroll
        for (int fj = 0; fj < 4; ++fj) {
            const int j = j0 + wj + fj * 16 + lr;
            f32x4 d = acc[fi][fj];
            s16x4 o;
            o[0] = (short)f2bf(d[0]); o[1] = (short)f2bf(d[1]);
            o[2] = (short)f2bf(d[2]); o[3] = (short)f2bf(d[3]);
            *(s16x4*)(Db + (long)j * 512 + i) = o;
        }
    }
    // ---- BN partial stats over this block's 128 n positions ----
    float sv[16], qv[16];
    #pragma unroll
    for (int fi = 0; fi < 4; ++fi)
        #pragma unroll
        for (int e = 0; e < 4; ++e) {
            float s = 0.f, q = 0.f;
            #pragma unroll
            for (int fj = 0; fj < 4; ++fj) { float d = acc[fi][fj][e]; s += d; q += d * d; }
            sv[fi * 4 + e] = s; qv[fi * 4 + e] = q;
        }
    #pragma unroll
    for (int m = 1; m < 16; m <<= 1) {
        #pragma unroll
        for (int r = 0; r < 16; ++r) {
            sv[r] += __shfl_xor(sv[r], m, 64);
            qv[r] += __shfl_xor(qv[r], m, 64);
        }
    }
    __syncthreads();
    if (lr == 0) {
        #pragma unroll
        for (int r = 0; r < 16; ++r) {
            int co = wi + (r >> 2) * 16 + lg * 4 + (r & 3);
            sred[w & 1][co] = sv[r];
            qred[w & 1][co] = qv[r];
        }
    }
    __syncthreads();
    if (tid < 128) {
        long blk = (long)br * 512 + bb * 8 + jblk;
        part[blk * 256 + tid]       = sred[0][tid] + sred[1][tid];
        part[blk * 256 + 128 + tid] = qred[0][tid] + qred[1][tid];
    }
}

// ================= PS+PL combined GEMM (pure; Y already BN'd), depth-3 =================
__global__ __launch_bounds__(256) void gemm_psl_k(
    const u16* __restrict__ Ybn,
    const u16* __restrict__ Bmat,
    u16* __restrict__ PSL)
{
    __shared__ s16x8 As[3 * 512];
    __shared__ s16x8 Bs[3 * 512];
    // XCD swizzle: grid 8x8x64 = 4096 = 8*512
    int flat = blockIdx.x + 8 * (blockIdx.y + 8 * blockIdx.z);
    int swz = (flat & 7) * 512 + (flat >> 3);
    const int j0 = (swz & 7) * 128;
    const int i0 = ((swz >> 3) & 7) * 128;
    const long bb = swz >> 6;
    const int tid = threadIdx.x;
    const u16* Ab = Ybn + bb * 524288;
    const int srow = tid >> 2, sg = tid & 3;
    const int ssg = sg ^ ((srow >> 1) & 3);
    const int l = tid & 63, w = tid >> 6;
    const int wi = (w >> 1) * 64, wj = (w & 1) * 64;
    const int lr = l & 15, lg = l >> 4;
    const long aoff0 = (long)(i0 + srow) * 512 + ssg * 8;
    const long aoff1 = (long)(i0 + srow + 64) * 512 + ssg * 8;
    const long boff0 = (long)(j0 + srow) * 512 + ssg * 8;
    const long boff1 = (long)(j0 + srow + 64) * 512 + ssg * 8;
    const int nt = 16;
    auto stage = [&](int buf, int t) {
        const int k0 = t << 5;
        char* a0 = (char*)As + buf * 8192 + w * 1024;
        char* b0 = (char*)Bs + buf * 8192 + w * 1024;
        gload16(a0, Ab + aoff0 + k0);
        gload16(a0 + 4096, Ab + aoff1 + k0);
        gload16(b0, Bmat + boff0 + k0);
        gload16(b0 + 4096, Bmat + boff1 + k0);
    };
    f32x4 acc[4][4] = {};
    stage(0, 0);
    stage(1, 1);
    int cur = 0;
    for (int t = 0; t < nt; ++t) {
        if (t + 2 < nt) stage((cur + 2) % 3, t + 2);
        pipe_wait(t, nt);
        s16x8 af[4], bf[4];
        #pragma unroll
        for (int f = 0; f < 4; ++f) {
            af[f] = As[cur * 512 + lds_chunk(wi + f * 16 + lr, lg)];
            bf[f] = Bs[cur * 512 + lds_chunk(wj + f * 16 + lr, lg)];
        }
        #pragma unroll
        for (int fi = 0; fi < 4; ++fi)
            #pragma unroll
            for (int fj = 0; fj < 4; ++fj)
                acc[fi][fj] = __builtin_amdgcn_mfma_f32_16x16x32_bf16(af[fi], bf[fj], acc[fi][fj], 0, 0, 0);
        pipe_endbar();
        cur = (cur + 1) % 3;
    }
    u16* Db = PSL + bb * 1048576;
    #pragma unroll
    for (int fi = 0; fi < 4; ++fi) {
        const int i = i0 + wi + fi * 16 + lg * 4;
        #pragma unroll
        for (int fj = 0; fj < 4; ++fj) {
            const int j = j0 + wj + fj * 16 + lr;
            f32x4 d = acc[fi][fj];
            s16x4 o;
            o[0] = (short)f2bf(d[0]); o[1] = (short)f2bf(d[1]);
            o[2] = (short)f2bf(d[2]); o[3] = (short)f2bf(d[3]);
            *(s16x4*)(Db + (long)j * 1024 + i) = o;
        }
    }
}

// ================= time-axis GEMM (band = exact support, dual pass, f32 out) =================
__global__ __launch_bounds__(256) void gemm_time_k(
    const u16* __restrict__ MS, const u16* __restrict__ ML,
    const u16* __restrict__ PSL,
    const float* __restrict__ b2, const float* __restrict__ X,
    float* __restrict__ OUT)
{
    __shared__ s16x8 As[3 * 512];
    __shared__ s16x8 Bs[3 * 512];
    // XCD swizzle: grid 4x8x64 = 2048 = 8*256
    int flat = blockIdx.x + 4 * (blockIdx.y + 8 * blockIdx.z);
    int swz = (flat & 7) * 256 + (flat >> 3);
    const int j0 = (swz & 3) * 128;          // co tile
    const int i0 = ((swz >> 2) & 7) * 128;   // n tile
    const long bb = swz >> 5;
    const int tid = threadIdx.x;
    const int srow = tid >> 2, sg = tid & 3;
    const int ssg = sg ^ ((srow >> 1) & 3);
    const int l = tid & 63, w = tid >> 6;
    const int wi = (w >> 1) * 64, wj = (w & 1) * 64;
    const int lr = l & 15, lg = l >> 4;
    // operator support is [n-24, n+21]; band (i0-32, i0+160) covers exactly
    const int klo = (i0 - 32) > 0 ? (i0 - 32) : 0;
    const int khi = (i0 + 160) < 1024 ? (i0 + 160) : 1024;
    const int nk = (khi - klo) >> 5;
    const int nt = nk * 2;
    auto stage = [&](int buf, int t) {
        const int pass = (t >= nk) ? 1 : 0;
        const int k0 = klo + ((t - (pass ? nk : 0)) << 5);
        const u16* A = pass ? ML : MS;
        const u16* B = PSL + bb * 1048576 + (long)pass * 524288;
        char* a0 = (char*)As + buf * 8192 + w * 1024;
        char* b0 = (char*)Bs + buf * 8192 + w * 1024;
        gload16(a0, A + (long)(i0 + srow) * 1024 + k0 + ssg * 8);
        gload16(a0 + 4096, A + (long)(i0 + srow + 64) * 1024 + k0 + ssg * 8);
        gload16(b0, B + (long)(j0 + srow) * 1024 + k0 + ssg * 8);
        gload16(b0 + 4096, B + (long)(j0 + srow + 64) * 1024 + k0 + ssg * 8);
    };
    f32x4 acc[4][4] = {};
    stage(0, 0);
    stage(1, 1);
    int cur = 0;
    for (int t = 0; t < nt; ++t) {
        if (t + 2 < nt) stage((cur + 2) % 3, t + 2);
        pipe_wait(t, nt);
        s16x8 af[4], bf[4];
        #pragma unroll
        for (int f = 0; f < 4; ++f) {
            af[f] = As[cur * 512 + lds_chunk(wi + f * 16 + lr, lg)];
            bf[f] = Bs[cur * 512 + lds_chunk(wj + f * 16 + lr, lg)];
        }
        #pragma unroll
        for (int fi = 0; fi < 4; ++fi)
            #pragma unroll
            for (int fj = 0; fj < 4; ++fj)
                acc[fi][fj] = __builtin_amdgcn_mfma_f32_16x16x32_bf16(af[fi], bf[fj], acc[fi][fj], 0, 0, 0);
        pipe_endbar();
        cur = (cur + 1) % 3;
    }
    float* Ob = OUT + bb * 524288;
    const float* Xb = X + bb * 524288;
    #pragma unroll
    for (int fi = 0; fi < 4; ++fi) {
        const int i = i0 + wi + fi * 16 + lg * 4;
        #pragma unroll
        for (int fj = 0; fj < 4; ++fj) {
            const int j = j0 + wj + fj * 16 + lr;
            const long a = (long)j * 1024 + i;
            f32x4 d = acc[fi][fj];
            const float bj = b2[j];
            f32x4 xv = *(const f32x4*)(Xb + a);
            f32x4 o;
            o[0] = d[0] + bj + xv[0]; o[1] = d[1] + bj + xv[1];
            o[2] = d[2] + bj + xv[2]; o[3] = d[3] + bj + xv[3];
            *(f32x4*)(Ob + a) = o;
        }
    }
}

// ================= packing / small kernels =================
__global__ __launch_bounds__(256) void cast_bf_k(const float* __restrict__ s, u16* __restrict__ d, int n)
{
    int i = blockIdx.x * 256 + threadIdx.x;
    if (i < n) d[i] = f2bf(s[i]);
}

// d[co*(taps*128) + tap*128 + ci] = s[(co*128+ci)*taps + tap]   (w_b is (co,ci,tap))
__global__ __launch_bounds__(256) void pack_wb2_k(const float* __restrict__ s, u16* __restrict__ d, int taps)
{
    int i = blockIdx.x * 256 + threadIdx.x;
    if (i >= taps * 16384) return;
    int stride = taps * 128;
    int co = i / stride;
    int rem = i - co * stride;
    int tap = rem >> 7, ci = rem & 127;
    d[i] = f2bf(s[(long)(co * 128 + ci) * taps + tap]);
}

// USc[co][128b+cc] = suffix-sum_b of (wfus_b . wpf_S); ULc = prefix-sum of (wfus_b . wpf_L)
__global__ __launch_bounds__(256) void make_Ucum_k(
    const float* __restrict__ wf, const float* __restrict__ wp,
    u16* __restrict__ USc, u16* __restrict__ ULc)
{
    int gid = blockIdx.x * 256 + threadIdx.x;   // 512*128
    int co = gid >> 7, cc = gid & 127;
    float us[4], ul[4];
    #pragma unroll
    for (int b = 0; b < 4; ++b) {
        float s = 0.f, t = 0.f;
        for (int q = 0; q < 128; ++q) {
            float f = wf[(long)co * 512 + b * 128 + q];
            s += f * wp[q * 256 + cc];
            t += f * wp[q * 256 + 128 + cc];
        }
        us[b] = s; ul[b] = t;
    }
    float suf = 0.f;
    for (int b = 3; b >= 0; --b) { suf += us[b]; USc[(long)co * 512 + b * 128 + cc] = f2bf(suf); }
    float pre = 0.f;
    for (int b = 0; b < 4; ++b) { pre += ul[b]; ULc[(long)co * 512 + b * 128 + cc] = f2bf(pre); }
}

__global__ __launch_bounds__(256) void make_bias2_k(
    const float* __restrict__ wf, const float* __restrict__ bpf,
    const float* __restrict__ bfus, float* __restrict__ b2)
{
    int co = blockIdx.x * 256 + threadIdx.x;
    if (co >= 512) return;
    float s = bfus[co];
    for (int j = 0; j < 512; ++j) s += wf[(long)co * 512 + j] * bpf[j & 127];
    b2[co] = s;
}

__global__ __launch_bounds__(256) void eye_k(float* __restrict__ I)
{
    int i = blockIdx.x * 256 + threadIdx.x;
    I[i] = ((i >> 10) == (i & 1023)) ? 1.0f : 0.0f;
}

__global__ __launch_bounds__(256) void zero_k(float* __restrict__ p, int n)
{
    int i = blockIdx.x * 256 + threadIdx.x;
    if (i < n) p[i] = 0.f;
}

// ---------------- DWT / IDWT (f32, used only for M-build on identity) ----------------
__global__ __launch_bounds__(256) void dwt_k(
    const float* __restrict__ x, float* __restrict__ a, float* __restrict__ d,
    int n_in, int n_out)
{
    const int row = blockIdx.y;
    const int m = blockIdx.x * 256 + threadIdx.x;
    if (m >= n_out) return;
    const float* xr = x + (long)row * n_in;
    float sa = 0.f, sd = 0.f;
    #pragma unroll
    for (int j = 0; j < 8; ++j) {
        int t = 2 * m + 1 - j;
        t = (t < 0) ? (-t - 1) : t;
        t = (t >= n_in) ? (2 * n_in - 1 - t) : t;
        const float v = xr[t];
        sa += v * c_lo[j];
        sd += v * c_hi[j];
    }
    a[(long)row * n_out + m] = sa;
    d[(long)row * n_out + m] = sd;
}

__global__ __launch_bounds__(256) void idwt_k(
    const float* __restrict__ lo, const float* __restrict__ hi,
    float* __restrict__ z, int nc, int n_out, long zB, int zN)
{
    const int row = blockIdx.y;
    const int m = blockIdx.x * 256 + threadIdx.x;
    if (m >= n_out) return;
    const float* lor = lo ? lo + (long)row * nc : nullptr;
    const float* hir = hi ? hi + (long)row * nc : nullptr;
    float s = 0.f;
    #pragma unroll
    for (int k = 0; k < 8; ++k) {
        int t = m + k - 1;
        if (t & 1) continue;
        int j = t >> 1;
        if (j >= nc) continue;
        if (lor) s += c_lo[k] * lor[j];
        if (hir) s += c_hi[k] * hir[j];
    }
    z[(long)(row >> 7) * zB + (long)(row & 127) * zN + m] = s;
}

// ---------------- transposes ----------------
__global__ __launch_bounds__(256) void trM_k(
    const float* __restrict__ S, const float* __restrict__ L,
    u16* __restrict__ MS, u16* __restrict__ ML)
{
    __shared__ float sh[32][33];
    const float* src = blockIdx.z ? L : S;
    u16* dst = blockIdx.z ? ML : MS;
    const int n0 = blockIdx.x * 32, m0 = blockIdx.y * 32;
    const int tx = threadIdx.x, ty = threadIdx.y;
    #pragma unroll
    for (int k = 0; k < 4; ++k)
        sh[ty + 8 * k][tx] = src[(long)(m0 + ty + 8 * k) * 1024 + n0 + tx];
    __syncthreads();
    #pragma unroll
    for (int k = 0; k < 4; ++k)
        dst[(long)(n0 + ty + 8 * k) * 1024 + m0 + tx] = f2bf(sh[tx][ty + 8 * k]);
}

// xcl[bb][n][c] = bf16(x[bb][c][n])
__global__ __launch_bounds__(256) void trX_k(const float* __restrict__ x, u16* __restrict__ xcl)
{
    __shared__ float sh[32][33];
    const int n0 = blockIdx.x * 32, c0 = blockIdx.y * 32;
    const long bb = blockIdx.z;
    const int tx = threadIdx.x, ty = threadIdx.y;
    const float* xb = x + bb * 524288;
    u16* ob = xcl + bb * 524288;
    #pragma unroll
    for (int k = 0; k < 4; ++k)
        sh[ty + 8 * k][tx] = xb[(long)(c0 + ty + 8 * k) * 1024 + n0 + tx];
    __syncthreads();
    #pragma unroll
    for (int k = 0; k < 4; ++k)
        ob[(long)(n0 + ty + 8 * k) * 512 + c0 + tx] = f2bf(sh[tx][ty + 8 * k]);
}

// ---------------- BN ----------------
// reduce per-block partials: scsh[c]=scale, scsh[512+c]=shift
__global__ __launch_bounds__(256) void bn_coef_k(
    const float* __restrict__ part, PtrQuad g, PtrQuad be, float* __restrict__ scsh)
{
    int c = blockIdx.x * 256 + threadIdx.x;
    if (c >= 512) return;
    int br = c >> 7, cc = c & 127;
    const float* pb = part + (long)br * 131072;   // 512 blocks * 256
    float s = 0.f, q = 0.f;
    for (int pidx = 0; pidx < 512; ++pidx) {
        s += pb[pidx * 256 + cc];
        q += pb[pidx * 256 + 128 + cc];
    }
    float mu = s * (1.0f / 65536.0f);
    float var = q * (1.0f / 65536.0f) - mu * mu;
    float sc = g.p[br][cc] * rsqrtf(var + 1e-5f);
    scsh[c] = sc;
    scsh[512 + c] = be.p[br][cc] - mu * sc;
}

// in-place BN+ReLU on Y ([64*1024 rows][512 ch] bf16)
__global__ __launch_bounds__(256) void bn_apply_k(
    u16* __restrict__ Y, const float* __restrict__ scsh)
{
    __shared__ float sc_[512];
    __shared__ float sh_[512];
    const int t = threadIdx.x;
    #pragma unroll
    for (int q = 0; q < 2; ++q) {
        sc_[t + q * 256] = scsh[t + q * 256];
        sh_[t + q * 256] = scsh[512 + t + q * 256];
    }
    __syncthreads();
    long gid = (long)blockIdx.x * 256 + t;
    long r = gid >> 6; int cg = (int)(gid & 63);
    u16* p = Y + r * 512 + cg * 8;
    s16x8 v = *(const s16x8*)p;
    #pragma unroll
    for (int e = 0; e < 8; ++e) {
        int c = cg * 8 + e;
        float f = bf2f((u16)v[e]) * sc_[c] + sh_[c];
        v[e] = (short)f2bf(f > 0.f ? f : 0.f);
    }
    *(s16x8*)p = v;
}

// =====================================================================
extern "C" void kernel_launch(void* const* d_in, const int* in_sizes, int n_in,
                              void* d_out, int out_size, void* d_ws, size_t ws_size,
                              hipStream_t stream)
{
    const float* x      = (const float*)d_in[0];
    const float* w_init = (const float*)d_in[1];
    const float* b_init = (const float*)d_in[2];
    const float* w_pf   = (const float*)d_in[3];
    const float* b_pf   = (const float*)d_in[4];
    const float* w_fus  = (const float*)d_in[5];
    const float* b_fus  = (const float*)d_in[6];
    const float *w_b[4];
    PtrQuad g, be;
    for (int i = 0; i < 4; ++i) {
        w_b[i]  = (const float*)d_in[7 + 4 * i];
        g.p[i]  = (const float*)d_in[9 + 4 * i];
        be.p[i] = (const float*)d_in[10 + 4 * i];
    }
    float* outf = (float*)d_out;

    char* p = (char*)d_ws;
    u16* xcl   = (u16*)p;  p += 67108864;
    u16* h     = (u16*)p;  p += 67108864;
    u16* Y     = (u16*)p;  p += 67108864;
    u16* PSL   = (u16*)p;  p += 134217728;
    u16* Wi    = (u16*)p;  p += 524288;
    u16* Wp    = (u16*)p;  p += 786432;
    u16* UScULc= (u16*)p;  p += 1048576;
    u16* MrowS = (u16*)p;  p += 2097152;
    u16* MrowL = (u16*)p;  p += 2097152;
    float* eye = (float*)p; p += 4194304;
    float* Sid = (float*)p; p += 4194304;
    float* Lid = (float*)p; p += 4194304;
    float* a1  = (float*)p; p += 2109440;
    float* d1  = (float*)p; p += 2109440;
    float* a2  = (float*)p; p += 1069056;
    float* d2  = (float*)p; p += 1069056;
    float* la1 = (float*)p; p += 2109440;
    float* sa1 = (float*)p; p += 2109440;
    float* b2  = (float*)p; p += 2048;
    float* zbuf= (float*)p; p += 256;    // 64 floats (zeroed each launch)
    float* scsh= (float*)p; p += 4096;
    float* part= (float*)p; p += 2097152; // 2048 blocks * 256 floats

    const int KS_[4] = {3, 5, 7, 9};
    const long wpOff[4] = {0, 3 * 16384L, 8 * 16384L, 15 * 16384L};

    // ---- weight packing / fused-weight precompute ----
    cast_bf_k<<<1024, 256, 0, stream>>>(w_init, Wi, 262144);
    for (int br = 0; br < 4; ++br)
        pack_wb2_k<<<(KS_[br] * 16384 + 255) / 256, 256, 0, stream>>>(w_b[br], Wp + wpOff[br], KS_[br]);
    make_Ucum_k<<<256, 256, 0, stream>>>(w_fus, w_pf, UScULc, UScULc + 262144);
    make_bias2_k<<<2, 256, 0, stream>>>(w_fus, b_pf, b_fus, b2);

    // ---- build wavelet operators M_S, M_L from identity ----
    eye_k<<<4096, 256, 0, stream>>>(eye);
    dwt_k<<<dim3(3, 1024), 256, 0, stream>>>(eye, a1, d1, 1024, 515);
    dwt_k<<<dim3(2, 1024), 256, 0, stream>>>(a1, a2, d2, 515, 261);
    idwt_k<<<dim3(3, 1024), 256, 0, stream>>>(a2, nullptr, la1, 261, 515, 65920, 515);
    idwt_k<<<dim3(3, 1024), 256, 0, stream>>>(nullptr, d2, sa1, 261, 515, 65920, 515);
    idwt_k<<<dim3(4, 1024), 256, 0, stream>>>(la1, nullptr, Lid, 515, 1024, 131072, 1024);
    idwt_k<<<dim3(4, 1024), 256, 0, stream>>>(sa1, d1, Sid, 515, 1024, 131072, 1024);
    trM_k<<<dim3(32, 32, 2), dim3(32, 8), 0, stream>>>(Sid, Lid, MrowS, MrowL);

    // ---- activations: transpose to channel-last bf16 ----
    trX_k<<<dim3(32, 16, 64), dim3(32, 8), 0, stream>>>(x, xcl);

    // ---- conv1x1: h[n][co] = Wi x + b_init ----
    gemm_nt_k<<<dim3(8, 4, 64), 256, 0, stream>>>(Wi, 0, 512, xcl, 524288, 512, 512,
                                                  h, 524288, 512, b_init);

    // ---- zero zbuf; branches: conv(taps) all-in-one + fused BN partials ----
    zero_k<<<1, 256, 0, stream>>>(zbuf, 64);
    gemm_branch4_k<<<dim3(8, 4, 64), 256, 0, stream>>>(Wp, h, Y, (const u16*)zbuf, part);

    // ---- BN coefficients (reduce partials) + apply (in place) ----
    bn_coef_k<<<2, 256, 0, stream>>>(part, g, be, scsh);
    bn_apply_k<<<16384, 256, 0, stream>>>(Y, scsh);

    // ---- PSL = Ybn . [USc;ULc]^T (one launch) ----
    gemm_psl_k<<<dim3(8, 8, 64), 256, 0, stream>>>(Y, UScULc, PSL);

    // ---- out = M_S.PS^T + M_L.PL^T + b2 + x ----
    gemm_time_k<<<dim3(4, 8, 64), 256, 0, stream>>>(MrowS, MrowL, PSL, b2, x, outf);
}

// Round 8
// 503.680 us; speedup vs baseline: 7.8680x; 1.0709x over previous
//
#include <hip/hip_runtime.h>

typedef float  f32x4 __attribute__((ext_vector_type(4)));
typedef short  s16x8 __attribute__((ext_vector_type(8)));
typedef short  s16x4 __attribute__((ext_vector_type(4)));
typedef unsigned short u16;

struct PtrQuad { const float* p[4]; };

// ---------------- db4 filters ----------------
__constant__ float c_lo[8] = {-0.010597401784997278f, 0.032883011666982945f,
                              0.030841381835986965f, -0.18703481171888114f,
                              -0.02798376941698385f, 0.6308807679295904f,
                              0.7148465705525415f,  0.23037781330885523f};
__constant__ float c_hi[8] = {-0.23037781330885523f, 0.7148465705525415f,
                              -0.6308807679295904f, -0.02798376941698385f,
                              0.18703481171888114f, 0.030841381835986965f,
                              -0.032883011666982945f, -0.010597401784997278f};

__device__ __forceinline__ u16 f2bf(float f) {
    unsigned u = __float_as_uint(f);
    u += 0x7fffu + ((u >> 16) & 1u);
    return (u16)(u >> 16);
}
__device__ __forceinline__ float bf2f(u16 h) {
    return __uint_as_float(((unsigned)h) << 16);
}
__device__ __forceinline__ int lds_chunk(int row, int g) {
    return row * 4 + (g ^ ((row >> 1) & 3));
}
// async 16B global->LDS; LDS dest = wave-uniform base + lane*16 (linear).
__device__ __forceinline__ void gload16(void* lds, const void* g) {
    __builtin_amdgcn_global_load_lds(
        (__attribute__((address_space(1))) const void*)g,
        (__attribute__((address_space(3))) void*)lds,
        16, 0, 0);
}
// depth-2 counted-vmcnt wait (T4): retire stage t (4 loads) before reading it
__device__ __forceinline__ void pipe_wait2(int t, int nt) {
    if (t + 1 < nt) asm volatile("s_waitcnt vmcnt(4)" ::: "memory");
    else            asm volatile("s_waitcnt vmcnt(0)" ::: "memory");
    __builtin_amdgcn_s_barrier();
    __builtin_amdgcn_sched_barrier(0);
}
__device__ __forceinline__ void pipe_endbar() {
    __builtin_amdgcn_sched_barrier(0);
    __builtin_amdgcn_s_barrier();
}

// ================= generic NT MFMA GEMM (conv1x1), depth-2 pipeline =================
// D[i][j] = sum_k A[i][k]*B[j][k]; store bf16 at D + bb*dB + j*dj + i (+bias[i])
__global__ __launch_bounds__(256) void gemm_nt_k(
    const u16* __restrict__ A, long aB, int lda,
    const u16* __restrict__ B, long bB, int ldb,
    int K,
    u16* __restrict__ D, long dB, int dj,
    const float* __restrict__ bias)
{
    __shared__ s16x8 As[2 * 512];
    __shared__ s16x8 Bs[2 * 512];
    // XCD swizzle: grid 8x4x64 = 2048 = 8*256
    int flat = blockIdx.x + 8 * (blockIdx.y + 4 * blockIdx.z);
    int swz = (flat & 7) * 256 + (flat >> 3);
    const int j0 = (swz & 7) * 128;
    const int i0 = ((swz >> 3) & 3) * 128;
    const long bb = swz >> 5;
    const u16* Ab = A + bb * aB;
    const u16* Bb = B + bb * bB;
    const int tid = threadIdx.x;
    const int srow = tid >> 2, sg = tid & 3;
    const int ssg = sg ^ ((srow >> 1) & 3);
    const int l = tid & 63, w = tid >> 6;
    const int wi = (w >> 1) * 64, wj = (w & 1) * 64;
    const int lr = l & 15, lg = l >> 4;
    const long aoff0 = (long)(i0 + srow) * lda + ssg * 8;
    const long aoff1 = (long)(i0 + srow + 64) * lda + ssg * 8;
    const long boff0 = (long)(j0 + srow) * ldb + ssg * 8;
    const long boff1 = (long)(j0 + srow + 64) * ldb + ssg * 8;
    const int nt = K >> 5;
    auto stage = [&](int buf, int t) {
        const int k0 = t << 5;
        char* a0 = (char*)As + buf * 8192 + w * 1024;
        char* b0 = (char*)Bs + buf * 8192 + w * 1024;
        gload16(a0, Ab + aoff0 + k0);
        gload16(a0 + 4096, Ab + aoff1 + k0);
        gload16(b0, Bb + boff0 + k0);
        gload16(b0 + 4096, Bb + boff1 + k0);
    };
    f32x4 acc[4][4] = {};
    stage(0, 0);
    for (int t = 0; t < nt; ++t) {
        const int cur = t & 1;
        if (t + 1 < nt) stage(cur ^ 1, t + 1);
        pipe_wait2(t, nt);
        s16x8 af[4], bf[4];
        #pragma unroll
        for (int f = 0; f < 4; ++f) {
            af[f] = As[cur * 512 + lds_chunk(wi + f * 16 + lr, lg)];
            bf[f] = Bs[cur * 512 + lds_chunk(wj + f * 16 + lr, lg)];
        }
        #pragma unroll
        for (int fi = 0; fi < 4; ++fi)
            #pragma unroll
            for (int fj = 0; fj < 4; ++fj)
                acc[fi][fj] = __builtin_amdgcn_mfma_f32_16x16x32_bf16(af[fi], bf[fj], acc[fi][fj], 0, 0, 0);
        pipe_endbar();
    }
    u16* Db = D + bb * dB;
    #pragma unroll
    for (int fi = 0; fi < 4; ++fi) {
        const int i = i0 + wi + fi * 16 + lg * 4;
        float b0 = 0, b1 = 0, b2v = 0, b3 = 0;
        if (bias) { b0 = bias[i]; b1 = bias[i + 1]; b2v = bias[i + 2]; b3 = bias[i + 3]; }
        #pragma unroll
        for (int fj = 0; fj < 4; ++fj) {
            const int j = j0 + wj + fj * 16 + lr;
            f32x4 d = acc[fi][fj];
            s16x4 o;
            o[0] = (short)f2bf(d[0] + b0); o[1] = (short)f2bf(d[1] + b1);
            o[2] = (short)f2bf(d[2] + b2v); o[3] = (short)f2bf(d[3] + b3);
            *(s16x4*)(Db + (long)j * dj + i) = o;
        }
    }
}

// ================= merged branch conv (4 branches) + fused BN partial stats =================
__global__ __launch_bounds__(256) void gemm_branch4_k(
    const u16* __restrict__ WpAll,
    const u16* __restrict__ H,
    u16* __restrict__ Y,
    const u16* __restrict__ zbuf,
    float* __restrict__ part)
{
    __shared__ s16x8 As[2 * 512];
    __shared__ s16x8 Bs[2 * 512];
    __shared__ float sred[2][128];
    __shared__ float qred[2][128];
    // XCD swizzle: grid 8x4x64 = 2048 = 8*256
    int flat = blockIdx.x + 8 * (blockIdx.y + 4 * blockIdx.z);
    int swz = (flat & 7) * 256 + (flat >> 3);
    const int jblk = swz & 7;
    const int br = (swz >> 3) & 3;
    const long bb = swz >> 5;
    const int j0 = jblk * 128;
    const int taps = 3 + 2 * br;
    const int pad = 1 + br;
    const u16* Wp = WpAll + (long)(br * br + 2 * br) * 16384;
    const u16* Hb = H + bb * 524288 + 128 * br;
    const int tid = threadIdx.x;
    const int srow = tid >> 2, sg = tid & 3;
    const int ssg = sg ^ ((srow >> 1) & 3);
    const int l = tid & 63, w = tid >> 6;
    const int wi = (w >> 1) * 64, wj = (w & 1) * 64;
    const int lr = l & 15, lg = l >> 4;
    const int lda = taps * 128;
    const int nt = taps * 4;
    auto stage = [&](int buf, int t) {
        const int k0 = t << 5;
        const int tap = k0 >> 7, kc = k0 & 127;
        const int shift = tap - pad;
        char* a0 = (char*)As + buf * 8192 + w * 1024;
        char* b0 = (char*)Bs + buf * 8192 + w * 1024;
        gload16(a0, Wp + (long)srow * lda + k0 + ssg * 8);
        gload16(a0 + 4096, Wp + (long)(srow + 64) * lda + k0 + ssg * 8);
        int n0r = j0 + srow + shift;
        int n1r = n0r + 64;
        const u16* s0 = (n0r >= 0 && n0r < 1024) ? (Hb + (long)n0r * 512 + kc + ssg * 8) : zbuf;
        const u16* s1 = (n1r >= 0 && n1r < 1024) ? (Hb + (long)n1r * 512 + kc + ssg * 8) : zbuf;
        gload16(b0, s0);
        gload16(b0 + 4096, s1);
    };
    f32x4 acc[4][4] = {};
    stage(0, 0);
    for (int t = 0; t < nt; ++t) {
        const int cur = t & 1;
        if (t + 1 < nt) stage(cur ^ 1, t + 1);
        pipe_wait2(t, nt);
        s16x8 af[4], bf[4];
        #pragma unroll
        for (int f = 0; f < 4; ++f) {
            af[f] = As[cur * 512 + lds_chunk(wi + f * 16 + lr, lg)];
            bf[f] = Bs[cur * 512 + lds_chunk(wj + f * 16 + lr, lg)];
        }
        #pragma unroll
        for (int fi = 0; fi < 4; ++fi)
            #pragma unroll
            for (int fj = 0; fj < 4; ++fj)
                acc[fi][fj] = __builtin_amdgcn_mfma_f32_16x16x32_bf16(af[fi], bf[fj], acc[fi][fj], 0, 0, 0);
        pipe_endbar();
    }
    u16* Db = Y + bb * 524288 + 128 * br;
    #pragma unroll
    for (int fi = 0; fi < 4; ++fi) {
        const int i = wi + fi * 16 + lg * 4;
        #pragma unroll
        for (int fj = 0; fj < 4; ++fj) {
            const int j = j0 + wj + fj * 16 + lr;
            f32x4 d = acc[fi][fj];
            s16x4 o;
            o[0] = (short)f2bf(d[0]); o[1] = (short)f2bf(d[1]);
            o[2] = (short)f2bf(d[2]); o[3] = (short)f2bf(d[3]);
            *(s16x4*)(Db + (long)j * 512 + i) = o;
        }
    }
    // ---- BN partial stats over this block's 128 n positions ----
    float sv[16], qv[16];
    #pragma unroll
    for (int fi = 0; fi < 4; ++fi)
        #pragma unroll
        for (int e = 0; e < 4; ++e) {
            float s = 0.f, q = 0.f;
            #pragma unroll
            for (int fj = 0; fj < 4; ++fj) { float d = acc[fi][fj][e]; s += d; q += d * d; }
            sv[fi * 4 + e] = s; qv[fi * 4 + e] = q;
        }
    #pragma unroll
    for (int m = 1; m < 16; m <<= 1) {
        #pragma unroll
        for (int r = 0; r < 16; ++r) {
            sv[r] += __shfl_xor(sv[r], m, 64);
            qv[r] += __shfl_xor(qv[r], m, 64);
        }
    }
    __syncthreads();
    if (lr == 0) {
        #pragma unroll
        for (int r = 0; r < 16; ++r) {
            int co = wi + (r >> 2) * 16 + lg * 4 + (r & 3);
            sred[w & 1][co] = sv[r];
            qred[w & 1][co] = qv[r];
        }
    }
    __syncthreads();
    if (tid < 128) {
        long blk = (long)br * 512 + bb * 8 + jblk;
        part[blk * 256 + tid]       = sred[0][tid] + sred[1][tid];
        part[blk * 256 + 128 + tid] = qred[0][tid] + qred[1][tid];
    }
}

// ================= PD+PL combined GEMM (pure; Y already BN'd), depth-2 =================
// A = Ybn (65536 x 512), B = [UD;UL] (1024x512), D = PSL[bb][j][m]
__global__ __launch_bounds__(256) void gemm_psl_k(
    const u16* __restrict__ Ybn,
    const u16* __restrict__ Bmat,
    u16* __restrict__ PSL)
{
    __shared__ s16x8 As[2 * 512];
    __shared__ s16x8 Bs[2 * 512];
    // XCD swizzle: grid 8x8x64 = 4096 = 8*512
    int flat = blockIdx.x + 8 * (blockIdx.y + 8 * blockIdx.z);
    int swz = (flat & 7) * 512 + (flat >> 3);
    const int j0 = (swz & 7) * 128;
    const int i0 = ((swz >> 3) & 7) * 128;
    const long bb = swz >> 6;
    const int tid = threadIdx.x;
    const u16* Ab = Ybn + bb * 524288;
    const int srow = tid >> 2, sg = tid & 3;
    const int ssg = sg ^ ((srow >> 1) & 3);
    const int l = tid & 63, w = tid >> 6;
    const int wi = (w >> 1) * 64, wj = (w & 1) * 64;
    const int lr = l & 15, lg = l >> 4;
    const long aoff0 = (long)(i0 + srow) * 512 + ssg * 8;
    const long aoff1 = (long)(i0 + srow + 64) * 512 + ssg * 8;
    const long boff0 = (long)(j0 + srow) * 512 + ssg * 8;
    const long boff1 = (long)(j0 + srow + 64) * 512 + ssg * 8;
    const int nt = 16;
    auto stage = [&](int buf, int t) {
        const int k0 = t << 5;
        char* a0 = (char*)As + buf * 8192 + w * 1024;
        char* b0 = (char*)Bs + buf * 8192 + w * 1024;
        gload16(a0, Ab + aoff0 + k0);
        gload16(a0 + 4096, Ab + aoff1 + k0);
        gload16(b0, Bmat + boff0 + k0);
        gload16(b0 + 4096, Bmat + boff1 + k0);
    };
    f32x4 acc[4][4] = {};
    stage(0, 0);
    for (int t = 0; t < nt; ++t) {
        const int cur = t & 1;
        if (t + 1 < nt) stage(cur ^ 1, t + 1);
        pipe_wait2(t, nt);
        s16x8 af[4], bf[4];
        #pragma unroll
        for (int f = 0; f < 4; ++f) {
            af[f] = As[cur * 512 + lds_chunk(wi + f * 16 + lr, lg)];
            bf[f] = Bs[cur * 512 + lds_chunk(wj + f * 16 + lr, lg)];
        }
        #pragma unroll
        for (int fi = 0; fi < 4; ++fi)
            #pragma unroll
            for (int fj = 0; fj < 4; ++fj)
                acc[fi][fj] = __builtin_amdgcn_mfma_f32_16x16x32_bf16(af[fi], bf[fj], acc[fi][fj], 0, 0, 0);
        pipe_endbar();
    }
    u16* Db = PSL + bb * 1048576;
    #pragma unroll
    for (int fi = 0; fi < 4; ++fi) {
        const int i = i0 + wi + fi * 16 + lg * 4;
        #pragma unroll
        for (int fj = 0; fj < 4; ++fj) {
            const int j = j0 + wj + fj * 16 + lr;
            f32x4 d = acc[fi][fj];
            s16x4 o;
            o[0] = (short)f2bf(d[0]); o[1] = (short)f2bf(d[1]);
            o[2] = (short)f2bf(d[2]); o[3] = (short)f2bf(d[3]);
            *(s16x4*)(Db + (long)j * 1024 + i) = o;
        }
    }
}

// ================= time-axis GEMM: out = MS.PD^T + PL + b2 + x (single pass) =================
__global__ __launch_bounds__(256) void gemm_time_k(
    const u16* __restrict__ MS,
    const u16* __restrict__ PSL,
    const float* __restrict__ b2, const float* __restrict__ X,
    float* __restrict__ OUT)
{
    __shared__ s16x8 As[2 * 512];
    __shared__ s16x8 Bs[2 * 512];
    // XCD swizzle: grid 4x8x64 = 2048 = 8*256
    int flat = blockIdx.x + 4 * (blockIdx.y + 8 * blockIdx.z);
    int swz = (flat & 7) * 256 + (flat >> 3);
    const int j0 = (swz & 3) * 128;          // co tile
    const int i0 = ((swz >> 2) & 7) * 128;   // n tile
    const long bb = swz >> 5;
    const int tid = threadIdx.x;
    const int srow = tid >> 2, sg = tid & 3;
    const int ssg = sg ^ ((srow >> 1) & 3);
    const int l = tid & 63, w = tid >> 6;
    const int wi = (w >> 1) * 64, wj = (w & 1) * 64;
    const int lr = l & 15, lg = l >> 4;
    // MS support is [n-24, n+21]; band [i0-32, i0+160) covers it
    const int klo = (i0 - 32) > 0 ? (i0 - 32) : 0;
    const int khi = (i0 + 160) < 1024 ? (i0 + 160) : 1024;
    const int nt = (khi - klo) >> 5;
    const u16* B = PSL + bb * 1048576;   // PD rows [0,512)
    auto stage = [&](int buf, int t) {
        const int k0 = klo + (t << 5);
        char* a0 = (char*)As + buf * 8192 + w * 1024;
        char* b0 = (char*)Bs + buf * 8192 + w * 1024;
        gload16(a0, MS + (long)(i0 + srow) * 1024 + k0 + ssg * 8);
        gload16(a0 + 4096, MS + (long)(i0 + srow + 64) * 1024 + k0 + ssg * 8);
        gload16(b0, B + (long)(j0 + srow) * 1024 + k0 + ssg * 8);
        gload16(b0 + 4096, B + (long)(j0 + srow + 64) * 1024 + k0 + ssg * 8);
    };
    f32x4 acc[4][4] = {};
    stage(0, 0);
    for (int t = 0; t < nt; ++t) {
        const int cur = t & 1;
        if (t + 1 < nt) stage(cur ^ 1, t + 1);
        pipe_wait2(t, nt);
        s16x8 af[4], bf[4];
        #pragma unroll
        for (int f = 0; f < 4; ++f) {
            af[f] = As[cur * 512 + lds_chunk(wi + f * 16 + lr, lg)];
            bf[f] = Bs[cur * 512 + lds_chunk(wj + f * 16 + lr, lg)];
        }
        #pragma unroll
        for (int fi = 0; fi < 4; ++fi)
            #pragma unroll
            for (int fj = 0; fj < 4; ++fj)
                acc[fi][fj] = __builtin_amdgcn_mfma_f32_16x16x32_bf16(af[fi], bf[fj], acc[fi][fj], 0, 0, 0);
        pipe_endbar();
    }
    float* Ob = OUT + bb * 524288;
    const float* Xb = X + bb * 524288;
    const u16* PLb = PSL + bb * 1048576 + 524288;   // PL rows [512,1024)
    #pragma unroll
    for (int fi = 0; fi < 4; ++fi) {
        const int i = i0 + wi + fi * 16 + lg * 4;
        #pragma unroll
        for (int fj = 0; fj < 4; ++fj) {
            const int j = j0 + wj + fj * 16 + lr;
            const long a = (long)j * 1024 + i;
            f32x4 d = acc[fi][fj];
            const float bj = b2[j];
            f32x4 xv = *(const f32x4*)(Xb + a);
            s16x4 pl4 = *(const s16x4*)(PLb + a);
            f32x4 o;
            o[0] = d[0] + bj + xv[0] + bf2f((u16)pl4[0]);
            o[1] = d[1] + bj + xv[1] + bf2f((u16)pl4[1]);
            o[2] = d[2] + bj + xv[2] + bf2f((u16)pl4[2]);
            o[3] = d[3] + bj + xv[3] + bf2f((u16)pl4[3]);
            *(f32x4*)(Ob + a) = o;
        }
    }
}

// ================= build wavelet operator MS (one block per identity column) =================
// MS[n][r] = S-path response at n to impulse at r. Four stages in LDS.
__global__ __launch_bounds__(256) void build_M_k(u16* __restrict__ MS)
{
    __shared__ float a1[515], d1[515], a2[261], d2[261], sa1[515];
    const int r = blockIdx.x;
    const int t = threadIdx.x;
    // stage 1: dwt of e_r (n=1024) -> a1,d1 (515)
    for (int m = t; m < 515; m += 256) {
        float sa = 0.f, sd = 0.f;
        #pragma unroll
        for (int j = 0; j < 8; ++j) {
            int tt = 2 * m + 1 - j;
            tt = (tt < 0) ? (-tt - 1) : tt;
            tt = (tt >= 1024) ? (2047 - tt) : tt;
            if (tt == r) { sa += c_lo[j]; sd += c_hi[j]; }
        }
        a1[m] = sa; d1[m] = sd;
    }
    __syncthreads();
    // stage 2: dwt(a1) (n=515) -> a2,d2 (261)
    for (int m = t; m < 261; m += 256) {
        float sa = 0.f, sd = 0.f;
        #pragma unroll
        for (int j = 0; j < 8; ++j) {
            int tt = 2 * m + 1 - j;
            tt = (tt < 0) ? (-tt - 1) : tt;
            tt = (tt >= 515) ? (1029 - tt) : tt;
            float v = a1[tt];
            sa += v * c_lo[j]; sd += v * c_hi[j];
        }
        a2[m] = sa; d2[m] = sd;
    }
    __syncthreads();
    // stage 3: sa1 = idwt(0, d2)[:515], nc=261
    for (int m = t; m < 515; m += 256) {
        float ss = 0.f;
        #pragma unroll
        for (int k = 0; k < 8; ++k) {
            int tt = m + k - 1;
            if (tt & 1) continue;
            int j = tt >> 1;
            if (j < 0 || j >= 261) continue;
            ss += c_hi[k] * d2[j];
        }
        sa1[m] = ss;
    }
    __syncthreads();
    // stage 4: S = idwt(sa1, d1)[:1024], nc=515; write MS[n][r]
    for (int n = t; n < 1024; n += 256) {
        float ss = 0.f;
        #pragma unroll
        for (int k = 0; k < 8; ++k) {
            int tt = n + k - 1;
            if (tt & 1) continue;
            int j = tt >> 1;
            if (j < 0 || j >= 515) continue;
            ss += c_lo[k] * sa1[j] + c_hi[k] * d1[j];
        }
        MS[(long)n * 1024 + r] = f2bf(ss);
    }
}

// ================= packing / small kernels =================
// merged: Wi cast + all 4 branch-weight packs
__global__ __launch_bounds__(256) void pack_weights_k(
    const float* __restrict__ wi,
    const float* __restrict__ b1, const float* __restrict__ b2_,
    const float* __restrict__ b3, const float* __restrict__ b4,
    u16* __restrict__ Wi, u16* __restrict__ Wp)
{
    int i = blockIdx.x * 256 + threadIdx.x;
    if (i < 262144) Wi[i] = f2bf(wi[i]);
    if (i < 393216) {
        int base, taps;
        const float* s;
        if (i < 49152)       { base = 0;      taps = 3; s = b1; }
        else if (i < 131072) { base = 49152;  taps = 5; s = b2_; }
        else if (i < 245760) { base = 131072; taps = 7; s = b3; }
        else                 { base = 245760; taps = 9; s = b4; }
        int rem = i - base;
        int stride = taps * 128;
        int co = rem / stride;
        int r2 = rem - co * stride;
        int tap = r2 >> 7, ci = r2 & 127;
        Wp[i] = f2bf(s[(long)(co * 128 + ci) * taps + tap]);
    }
}

// UDUL rows [0,512): UD = USc - ULc (f32 diff, then bf16); rows [512,1024): ULc
__global__ __launch_bounds__(256) void make_Ucum_k(
    const float* __restrict__ wf, const float* __restrict__ wp,
    u16* __restrict__ UDUL)
{
    int gid = blockIdx.x * 256 + threadIdx.x;   // 512*128
    int co = gid >> 7, cc = gid & 127;
    float us[4], ul[4];
    #pragma unroll
    for (int b = 0; b < 4; ++b) {
        float s = 0.f, t = 0.f;
        for (int q = 0; q < 128; ++q) {
            float f = wf[(long)co * 512 + b * 128 + q];
            s += f * wp[q * 256 + cc];
            t += f * wp[q * 256 + 128 + cc];
        }
        us[b] = s; ul[b] = t;
    }
    float suf[4], pre[4];
    float acc = 0.f;
    for (int b = 3; b >= 0; --b) { acc += us[b]; suf[b] = acc; }
    acc = 0.f;
    for (int b = 0; b < 4; ++b) { acc += ul[b]; pre[b] = acc; }
    #pragma unroll
    for (int b = 0; b < 4; ++b) {
        UDUL[(long)co * 512 + b * 128 + cc]         = f2bf(suf[b] - pre[b]);
        UDUL[(long)(512 + co) * 512 + b * 128 + cc] = f2bf(pre[b]);
    }
}

__global__ __launch_bounds__(256) void make_bias2_k(
    const float* __restrict__ wf, const float* __restrict__ bpf,
    const float* __restrict__ bfus, float* __restrict__ b2)
{
    int co = blockIdx.x * 256 + threadIdx.x;
    if (co >= 512) return;
    float s = bfus[co];
    for (int j = 0; j < 512; ++j) s += wf[(long)co * 512 + j] * bpf[j & 127];
    b2[co] = s;
}

__global__ __launch_bounds__(256) void zero_k(float* __restrict__ p, int n)
{
    int i = blockIdx.x * 256 + threadIdx.x;
    if (i < n) p[i] = 0.f;
}

// ---------------- transpose: xcl[bb][n][c] = bf16(x[bb][c][n]) ----------------
__global__ __launch_bounds__(256) void trX_k(const float* __restrict__ x, u16* __restrict__ xcl)
{
    __shared__ float sh[32][33];
    const int n0 = blockIdx.x * 32, c0 = blockIdx.y * 32;
    const long bb = blockIdx.z;
    const int tx = threadIdx.x, ty = threadIdx.y;
    const float* xb = x + bb * 524288;
    u16* ob = xcl + bb * 524288;
    #pragma unroll
    for (int k = 0; k < 4; ++k)
        sh[ty + 8 * k][tx] = xb[(long)(c0 + ty + 8 * k) * 1024 + n0 + tx];
    __syncthreads();
    #pragma unroll
    for (int k = 0; k < 4; ++k)
        ob[(long)(n0 + ty + 8 * k) * 512 + c0 + tx] = f2bf(sh[tx][ty + 8 * k]);
}

// ---------------- BN ----------------
__global__ __launch_bounds__(256) void bn_coef_k(
    const float* __restrict__ part, PtrQuad g, PtrQuad be, float* __restrict__ scsh)
{
    int c = blockIdx.x * 256 + threadIdx.x;
    if (c >= 512) return;
    int br = c >> 7, cc = c & 127;
    const float* pb = part + (long)br * 131072;   // 512 blocks * 256
    float s = 0.f, q = 0.f;
    for (int pidx = 0; pidx < 512; ++pidx) {
        s += pb[pidx * 256 + cc];
        q += pb[pidx * 256 + 128 + cc];
    }
    float mu = s * (1.0f / 65536.0f);
    float var = q * (1.0f / 65536.0f) - mu * mu;
    float sc = g.p[br][cc] * rsqrtf(var + 1e-5f);
    scsh[c] = sc;
    scsh[512 + c] = be.p[br][cc] - mu * sc;
}

// in-place BN+ReLU on Y ([64*1024 rows][512 ch] bf16)
__global__ __launch_bounds__(256) void bn_apply_k(
    u16* __restrict__ Y, const float* __restrict__ scsh)
{
    __shared__ float sc_[512];
    __shared__ float sh_[512];
    const int t = threadIdx.x;
    #pragma unroll
    for (int q = 0; q < 2; ++q) {
        sc_[t + q * 256] = scsh[t + q * 256];
        sh_[t + q * 256] = scsh[512 + t + q * 256];
    }
    __syncthreads();
    long gid = (long)blockIdx.x * 256 + t;
    long r = gid >> 6; int cg = (int)(gid & 63);
    u16* p = Y + r * 512 + cg * 8;
    s16x8 v = *(const s16x8*)p;
    #pragma unroll
    for (int e = 0; e < 8; ++e) {
        int c = cg * 8 + e;
        float f = bf2f((u16)v[e]) * sc_[c] + sh_[c];
        v[e] = (short)f2bf(f > 0.f ? f : 0.f);
    }
    *(s16x8*)p = v;
}

// =====================================================================
extern "C" void kernel_launch(void* const* d_in, const int* in_sizes, int n_in,
                              void* d_out, int out_size, void* d_ws, size_t ws_size,
                              hipStream_t stream)
{
    const float* x      = (const float*)d_in[0];
    const float* w_init = (const float*)d_in[1];
    const float* b_init = (const float*)d_in[2];
    const float* w_pf   = (const float*)d_in[3];
    const float* b_pf   = (const float*)d_in[4];
    const float* w_fus  = (const float*)d_in[5];
    const float* b_fus  = (const float*)d_in[6];
    const float *w_b[4];
    PtrQuad g, be;
    for (int i = 0; i < 4; ++i) {
        w_b[i]  = (const float*)d_in[7 + 4 * i];
        g.p[i]  = (const float*)d_in[9 + 4 * i];
        be.p[i] = (const float*)d_in[10 + 4 * i];
    }
    float* outf = (float*)d_out;

    char* p = (char*)d_ws;
    u16* xcl   = (u16*)p;  p += 67108864;
    u16* h     = (u16*)p;  p += 67108864;
    u16* Y     = (u16*)p;  p += 67108864;
    u16* PSL   = (u16*)p;  p += 134217728;
    u16* Wi    = (u16*)p;  p += 524288;
    u16* Wp    = (u16*)p;  p += 786432;
    u16* UDUL  = (u16*)p;  p += 1048576;
    u16* MrowS = (u16*)p;  p += 2097152;
    float* b2  = (float*)p; p += 2048;
    float* zbuf= (float*)p; p += 256;     // 64 floats, zeroed each launch
    float* scsh= (float*)p; p += 4096;
    float* part= (float*)p; p += 2097152; // 2048 blocks * 256 floats

    // ---- prologue: weights / operators (independent small kernels) ----
    pack_weights_k<<<1536, 256, 0, stream>>>(w_init, w_b[0], w_b[1], w_b[2], w_b[3], Wi, Wp);
    make_Ucum_k<<<256, 256, 0, stream>>>(w_fus, w_pf, UDUL);
    make_bias2_k<<<2, 256, 0, stream>>>(w_fus, b_pf, b_fus, b2);
    build_M_k<<<1024, 256, 0, stream>>>(MrowS);
    zero_k<<<1, 256, 0, stream>>>(zbuf, 64);

    // ---- activations: transpose to channel-last bf16 ----
    trX_k<<<dim3(32, 16, 64), dim3(32, 8), 0, stream>>>(x, xcl);

    // ---- conv1x1: h[n][co] = Wi x + b_init ----
    gemm_nt_k<<<dim3(8, 4, 64), 256, 0, stream>>>(Wi, 0, 512, xcl, 524288, 512, 512,
                                                  h, 524288, 512, b_init);

    // ---- branches: conv(taps) all-in-one + fused BN partials ----
    gemm_branch4_k<<<dim3(8, 4, 64), 256, 0, stream>>>(Wp, h, Y, (const u16*)zbuf, part);

    // ---- BN coefficients (reduce partials) + apply (in place) ----
    bn_coef_k<<<2, 256, 0, stream>>>(part, g, be, scsh);
    bn_apply_k<<<16384, 256, 0, stream>>>(Y, scsh);

    // ---- PSL = Ybn . [UD;UL]^T (one launch) ----
    gemm_psl_k<<<dim3(8, 8, 64), 256, 0, stream>>>(Y, UDUL, PSL);

    // ---- out = MS.PD^T + PL + b2 + x ----
    gemm_time_k<<<dim3(4, 8, 64), 256, 0, stream>>>(MrowS, PSL, b2, x, outf);
}

// Round 10
// 476.523 us; speedup vs baseline: 8.3164x; 1.0570x over previous
//
#include <hip/hip_runtime.h>

typedef float  f32x4 __attribute__((ext_vector_type(4)));
typedef short  s16x8 __attribute__((ext_vector_type(8)));
typedef short  s16x4 __attribute__((ext_vector_type(4)));
typedef unsigned short u16;

struct PtrQuad { const float* p[4]; };

// ---------------- db4 filters ----------------
__constant__ float c_lo[8] = {-0.010597401784997278f, 0.032883011666982945f,
                              0.030841381835986965f, -0.18703481171888114f,
                              -0.02798376941698385f, 0.6308807679295904f,
                              0.7148465705525415f,  0.23037781330885523f};
__constant__ float c_hi[8] = {-0.23037781330885523f, 0.7148465705525415f,
                              -0.6308807679295904f, -0.02798376941698385f,
                              0.18703481171888114f, 0.030841381835986965f,
                              -0.032883011666982945f, -0.010597401784997278f};

__device__ __forceinline__ u16 f2bf(float f) {
    unsigned u = __float_as_uint(f);
    u += 0x7fffu + ((u >> 16) & 1u);
    return (u16)(u >> 16);
}
__device__ __forceinline__ float bf2f(u16 h) {
    return __uint_as_float(((unsigned)h) << 16);
}
__device__ __forceinline__ int lds_chunk(int row, int g) {
    return row * 4 + (g ^ ((row >> 1) & 3));
}
// async 16B global->LDS; LDS dest = wave-uniform base + lane*16 (linear).
__device__ __forceinline__ void gload16(void* lds, const void* g) {
    __builtin_amdgcn_global_load_lds(
        (__attribute__((address_space(1))) const void*)g,
        (__attribute__((address_space(3))) void*)lds,
        16, 0, 0);
}
// depth-2 counted-vmcnt wait (T4)
__device__ __forceinline__ void pipe_wait2(int t, int nt) {
    if (t + 1 < nt) asm volatile("s_waitcnt vmcnt(4)" ::: "memory");
    else            asm volatile("s_waitcnt vmcnt(0)" ::: "memory");
    __builtin_amdgcn_s_barrier();
    __builtin_amdgcn_sched_barrier(0);
}
__device__ __forceinline__ void pipe_endbar() {
    __builtin_amdgcn_sched_barrier(0);
    __builtin_amdgcn_s_barrier();
}

// ================= generic NT MFMA GEMM (conv1x1), depth-2 pipeline =================
__global__ __launch_bounds__(256) void gemm_nt_k(
    const u16* __restrict__ A, long aB, int lda,
    const u16* __restrict__ B, long bB, int ldb,
    int K,
    u16* __restrict__ D, long dB, int dj,
    const float* __restrict__ bias)
{
    __shared__ s16x8 As[2 * 512];
    __shared__ s16x8 Bs[2 * 512];
    int flat = blockIdx.x + 8 * (blockIdx.y + 4 * blockIdx.z);
    int swz = (flat & 7) * 256 + (flat >> 3);
    const int j0 = (swz & 7) * 128;
    const int i0 = ((swz >> 3) & 3) * 128;
    const long bb = swz >> 5;
    const u16* Ab = A + bb * aB;
    const u16* Bb = B + bb * bB;
    const int tid = threadIdx.x;
    const int srow = tid >> 2, sg = tid & 3;
    const int ssg = sg ^ ((srow >> 1) & 3);
    const int l = tid & 63, w = tid >> 6;
    const int wi = (w >> 1) * 64, wj = (w & 1) * 64;
    const int lr = l & 15, lg = l >> 4;
    const long aoff0 = (long)(i0 + srow) * lda + ssg * 8;
    const long aoff1 = (long)(i0 + srow + 64) * lda + ssg * 8;
    const long boff0 = (long)(j0 + srow) * ldb + ssg * 8;
    const long boff1 = (long)(j0 + srow + 64) * ldb + ssg * 8;
    const int nt = K >> 5;
    auto stage = [&](int buf, int t) {
        const int k0 = t << 5;
        char* a0 = (char*)As + buf * 8192 + w * 1024;
        char* b0 = (char*)Bs + buf * 8192 + w * 1024;
        gload16(a0, Ab + aoff0 + k0);
        gload16(a0 + 4096, Ab + aoff1 + k0);
        gload16(b0, Bb + boff0 + k0);
        gload16(b0 + 4096, Bb + boff1 + k0);
    };
    f32x4 acc[4][4] = {};
    stage(0, 0);
    for (int t = 0; t < nt; ++t) {
        const int cur = t & 1;
        if (t + 1 < nt) stage(cur ^ 1, t + 1);
        pipe_wait2(t, nt);
        s16x8 af[4], bf[4];
        #pragma unroll
        for (int f = 0; f < 4; ++f) {
            af[f] = As[cur * 512 + lds_chunk(wi + f * 16 + lr, lg)];
            bf[f] = Bs[cur * 512 + lds_chunk(wj + f * 16 + lr, lg)];
        }
        __builtin_amdgcn_s_setprio(1);
        #pragma unroll
        for (int fi = 0; fi < 4; ++fi)
            #pragma unroll
            for (int fj = 0; fj < 4; ++fj)
                acc[fi][fj] = __builtin_amdgcn_mfma_f32_16x16x32_bf16(af[fi], bf[fj], acc[fi][fj], 0, 0, 0);
        __builtin_amdgcn_s_setprio(0);
        pipe_endbar();
    }
    u16* Db = D + bb * dB;
    #pragma unroll
    for (int fi = 0; fi < 4; ++fi) {
        const int i = i0 + wi + fi * 16 + lg * 4;
        float b0 = 0, b1 = 0, b2v = 0, b3 = 0;
        if (bias) { b0 = bias[i]; b1 = bias[i + 1]; b2v = bias[i + 2]; b3 = bias[i + 3]; }
        #pragma unroll
        for (int fj = 0; fj < 4; ++fj) {
            const int j = j0 + wj + fj * 16 + lr;
            f32x4 d = acc[fi][fj];
            s16x4 o;
            o[0] = (short)f2bf(d[0] + b0); o[1] = (short)f2bf(d[1] + b1);
            o[2] = (short)f2bf(d[2] + b2v); o[3] = (short)f2bf(d[3] + b3);
            *(s16x4*)(Db + (long)j * dj + i) = o;
        }
    }
}

// ================= branch conv: chunk-major, B window staged once per chunk =================
// A: 128co x 32ch dbuf (2x8KB). B: 192-row H window x 32ch dbuf (2x12KB).
// Barrier discipline identical to round-8 (wait -> s_barrier -> sched_barrier -> reads/MFMA -> s_barrier).
__global__ __launch_bounds__(256) void gemm_branch4_k(
    const u16* __restrict__ WpAll,
    const u16* __restrict__ H,
    u16* __restrict__ Y,
    const u16* __restrict__ zbuf,
    float* __restrict__ part)
{
    __shared__ char Alds[2 * 8192];
    __shared__ char Blds[2 * 12288];
    __shared__ float sred[2][128];
    __shared__ float qred[2][128];
    // XCD swizzle: grid 8x4x64 = 2048 = 8*256
    int flat = blockIdx.x + 8 * (blockIdx.y + 4 * blockIdx.z);
    int swz = (flat & 7) * 256 + (flat >> 3);
    const int jblk = swz & 7;
    const int br = (swz >> 3) & 3;
    const long bb = swz >> 5;
    const int j0 = jblk * 128;
    const int taps = 3 + 2 * br;
    const int pad = 1 + br;
    const u16* Wpb = WpAll + (long)(br * br + 2 * br) * 16384;
    const u16* Hb = H + bb * 524288 + 128 * br;
    const int tid = threadIdx.x;
    const int l = tid & 63, w = tid >> 6;
    const int wi = (w >> 1) * 64, wj = (w & 1) * 64;
    const int lr = l & 15, lg = l >> 4;
    const int lrow = l >> 2, lq = l & 3;
    const int ssg2 = lq ^ ((lrow >> 1) & 3);   // pre-swizzled source 8-ch group
    const int lda = taps * 128;

    auto stageA = [&](int buf, int c, int t) {
        char* dst = Alds + buf * 8192 + w * 2048;
        #pragma unroll
        for (int q = 0; q < 2; ++q) {
            int row = w * 32 + q * 16 + lrow;       // (row>>1)&3 == (lrow>>1)&3
            gload16(dst + q * 1024,
                    Wpb + (long)row * lda + t * 128 + c * 32 + ssg2 * 8);
        }
    };
    auto stageB = [&](int buf, int c) {
        char* dst = Blds + buf * 12288 + w * 3072;
        #pragma unroll
        for (int q = 0; q < 3; ++q) {
            int winrow = w * 48 + q * 16 + lrow;    // (winrow>>1)&3 == (lrow>>1)&3
            int grow = j0 - 32 + winrow;
            const u16* src = (grow >= 0 && grow < 1024)
                           ? (Hb + (long)grow * 512 + c * 32 + ssg2 * 8) : zbuf;
            gload16(dst + q * 1024, src);
        }
    };

    f32x4 acc[4][4] = {};
    int abuf = 0, bbuf = 0;
    stageB(0, 0);          // 3 loads/wave
    stageA(0, 0, 0);       // 2 loads/wave
    for (int c = 0; c < 4; ++c) {
        for (int t = 0; t < taps; ++t) {
            if (t + 1 < taps) {
                stageA(abuf ^ 1, c, t + 1);
                asm volatile("s_waitcnt vmcnt(2)" ::: "memory");
            } else if (c + 1 < 4) {
                stageB(bbuf ^ 1, c + 1);
                stageA(abuf ^ 1, c + 1, 0);
                asm volatile("s_waitcnt vmcnt(5)" ::: "memory");
            } else {
                asm volatile("s_waitcnt vmcnt(0)" ::: "memory");
            }
            __builtin_amdgcn_s_barrier();
            __builtin_amdgcn_sched_barrier(0);
            const char* Al = Alds + abuf * 8192;
            const char* Bl = Blds + bbuf * 12288;
            const int shift2 = t - pad + 32;
            s16x8 af[4], bf[4];
            #pragma unroll
            for (int f = 0; f < 4; ++f) {
                int arow = wi + f * 16 + lr;
                af[f] = *(const s16x8*)(Al + arow * 64 + (lg ^ ((arow >> 1) & 3)) * 16);
                int brow = wj + f * 16 + lr + shift2;
                bf[f] = *(const s16x8*)(Bl + brow * 64 + (lg ^ ((brow >> 1) & 3)) * 16);
            }
            __builtin_amdgcn_s_setprio(1);
            #pragma unroll
            for (int fi = 0; fi < 4; ++fi)
                #pragma unroll
                for (int fj = 0; fj < 4; ++fj)
                    acc[fi][fj] = __builtin_amdgcn_mfma_f32_16x16x32_bf16(af[fi], bf[fj], acc[fi][fj], 0, 0, 0);
            __builtin_amdgcn_s_setprio(0);
            __builtin_amdgcn_sched_barrier(0);
            __builtin_amdgcn_s_barrier();
            abuf ^= 1;
            if (t == taps - 1) bbuf ^= 1;
        }
    }
    u16* Db = Y + bb * 524288 + 128 * br;
    #pragma unroll
    for (int fi = 0; fi < 4; ++fi) {
        const int i = wi + fi * 16 + lg * 4;
        #pragma unroll
        for (int fj = 0; fj < 4; ++fj) {
            const int j = j0 + wj + fj * 16 + lr;
            f32x4 d = acc[fi][fj];
            s16x4 o;
            o[0] = (short)f2bf(d[0]); o[1] = (short)f2bf(d[1]);
            o[2] = (short)f2bf(d[2]); o[3] = (short)f2bf(d[3]);
            *(s16x4*)(Db + (long)j * 512 + i) = o;
        }
    }
    // ---- BN partial stats over this block's 128 n positions ----
    float sv[16], qv[16];
    #pragma unroll
    for (int fi = 0; fi < 4; ++fi)
        #pragma unroll
        for (int e = 0; e < 4; ++e) {
            float s = 0.f, q = 0.f;
            #pragma unroll
            for (int fj = 0; fj < 4; ++fj) { float d = acc[fi][fj][e]; s += d; q += d * d; }
            sv[fi * 4 + e] = s; qv[fi * 4 + e] = q;
        }
    #pragma unroll
    for (int m = 1; m < 16; m <<= 1) {
        #pragma unroll
        for (int r = 0; r < 16; ++r) {
            sv[r] += __shfl_xor(sv[r], m, 64);
            qv[r] += __shfl_xor(qv[r], m, 64);
        }
    }
    __syncthreads();
    if (lr == 0) {
        #pragma unroll
        for (int r = 0; r < 16; ++r) {
            int co = wi + (r >> 2) * 16 + lg * 4 + (r & 3);
            sred[w & 1][co] = sv[r];
            qred[w & 1][co] = qv[r];
        }
    }
    __syncthreads();
    if (tid < 128) {
        long blk = (long)br * 512 + bb * 8 + jblk;
        part[blk * 256 + tid]       = sred[0][tid] + sred[1][tid];
        part[blk * 256 + 128 + tid] = qred[0][tid] + qred[1][tid];
    }
}

// ================= PD+PL combined GEMM (pure; Y already BN'd), depth-2 =================
__global__ __launch_bounds__(256) void gemm_psl_k(
    const u16* __restrict__ Ybn,
    const u16* __restrict__ Bmat,
    u16* __restrict__ PSL)
{
    __shared__ s16x8 As[2 * 512];
    __shared__ s16x8 Bs[2 * 512];
    int flat = blockIdx.x + 8 * (blockIdx.y + 8 * blockIdx.z);
    int swz = (flat & 7) * 512 + (flat >> 3);
    const int j0 = (swz & 7) * 128;
    const int i0 = ((swz >> 3) & 7) * 128;
    const long bb = swz >> 6;
    const int tid = threadIdx.x;
    const u16* Ab = Ybn + bb * 524288;
    const int srow = tid >> 2, sg = tid & 3;
    const int ssg = sg ^ ((srow >> 1) & 3);
    const int l = tid & 63, w = tid >> 6;
    const int wi = (w >> 1) * 64, wj = (w & 1) * 64;
    const int lr = l & 15, lg = l >> 4;
    const long aoff0 = (long)(i0 + srow) * 512 + ssg * 8;
    const long aoff1 = (long)(i0 + srow + 64) * 512 + ssg * 8;
    const long boff0 = (long)(j0 + srow) * 512 + ssg * 8;
    const long boff1 = (long)(j0 + srow + 64) * 512 + ssg * 8;
    const int nt = 16;
    auto stage = [&](int buf, int t) {
        const int k0 = t << 5;
        char* a0 = (char*)As + buf * 8192 + w * 1024;
        char* b0 = (char*)Bs + buf * 8192 + w * 1024;
        gload16(a0, Ab + aoff0 + k0);
        gload16(a0 + 4096, Ab + aoff1 + k0);
        gload16(b0, Bmat + boff0 + k0);
        gload16(b0 + 4096, Bmat + boff1 + k0);
    };
    f32x4 acc[4][4] = {};
    stage(0, 0);
    for (int t = 0; t < nt; ++t) {
        const int cur = t & 1;
        if (t + 1 < nt) stage(cur ^ 1, t + 1);
        pipe_wait2(t, nt);
        s16x8 af[4], bf[4];
        #pragma unroll
        for (int f = 0; f < 4; ++f) {
            af[f] = As[cur * 512 + lds_chunk(wi + f * 16 + lr, lg)];
            bf[f] = Bs[cur * 512 + lds_chunk(wj + f * 16 + lr, lg)];
        }
        __builtin_amdgcn_s_setprio(1);
        #pragma unroll
        for (int fi = 0; fi < 4; ++fi)
            #pragma unroll
            for (int fj = 0; fj < 4; ++fj)
                acc[fi][fj] = __builtin_amdgcn_mfma_f32_16x16x32_bf16(af[fi], bf[fj], acc[fi][fj], 0, 0, 0);
        __builtin_amdgcn_s_setprio(0);
        pipe_endbar();
    }
    u16* Db = PSL + bb * 1048576;
    #pragma unroll
    for (int fi = 0; fi < 4; ++fi) {
        const int i = i0 + wi + fi * 16 + lg * 4;
        #pragma unroll
        for (int fj = 0; fj < 4; ++fj) {
            const int j = j0 + wj + fj * 16 + lr;
            f32x4 d = acc[fi][fj];
            s16x4 o;
            o[0] = (short)f2bf(d[0]); o[1] = (short)f2bf(d[1]);
            o[2] = (short)f2bf(d[2]); o[3] = (short)f2bf(d[3]);
            *(s16x4*)(Db + (long)j * 1024 + i) = o;
        }
    }
}

// ================= time-axis GEMM: out = MS.PD^T + PL + b2 + x (single pass) =================
__global__ __launch_bounds__(256) void gemm_time_k(
    const u16* __restrict__ MS,
    const u16* __restrict__ PSL,
    const float* __restrict__ b2, const float* __restrict__ X,
    float* __restrict__ OUT)
{
    __shared__ s16x8 As[2 * 512];
    __shared__ s16x8 Bs[2 * 512];
    int flat = blockIdx.x + 4 * (blockIdx.y + 8 * blockIdx.z);
    int swz = (flat & 7) * 256 + (flat >> 3);
    const int j0 = (swz & 3) * 128;          // co tile
    const int i0 = ((swz >> 2) & 7) * 128;   // n tile
    const long bb = swz >> 5;
    const int tid = threadIdx.x;
    const int srow = tid >> 2, sg = tid & 3;
    const int ssg = sg ^ ((srow >> 1) & 3);
    const int l = tid & 63, w = tid >> 6;
    const int wi = (w >> 1) * 64, wj = (w & 1) * 64;
    const int lr = l & 15, lg = l >> 4;
    const int klo = (i0 - 32) > 0 ? (i0 - 32) : 0;
    const int khi = (i0 + 160) < 1024 ? (i0 + 160) : 1024;
    const int nt = (khi - klo) >> 5;
    const u16* B = PSL + bb * 1048576;   // PD rows [0,512)
    auto stage = [&](int buf, int t) {
        const int k0 = klo + (t << 5);
        char* a0 = (char*)As + buf * 8192 + w * 1024;
        char* b0 = (char*)Bs + buf * 8192 + w * 1024;
        gload16(a0, MS + (long)(i0 + srow) * 1024 + k0 + ssg * 8);
        gload16(a0 + 4096, MS + (long)(i0 + srow + 64) * 1024 + k0 + ssg * 8);
        gload16(b0, B + (long)(j0 + srow) * 1024 + k0 + ssg * 8);
        gload16(b0 + 4096, B + (long)(j0 + srow + 64) * 1024 + k0 + ssg * 8);
    };
    f32x4 acc[4][4] = {};
    stage(0, 0);
    for (int t = 0; t < nt; ++t) {
        const int cur = t & 1;
        if (t + 1 < nt) stage(cur ^ 1, t + 1);
        pipe_wait2(t, nt);
        s16x8 af[4], bf[4];
        #pragma unroll
        for (int f = 0; f < 4; ++f) {
            af[f] = As[cur * 512 + lds_chunk(wi + f * 16 + lr, lg)];
            bf[f] = Bs[cur * 512 + lds_chunk(wj + f * 16 + lr, lg)];
        }
        __builtin_amdgcn_s_setprio(1);
        #pragma unroll
        for (int fi = 0; fi < 4; ++fi)
            #pragma unroll
            for (int fj = 0; fj < 4; ++fj)
                acc[fi][fj] = __builtin_amdgcn_mfma_f32_16x16x32_bf16(af[fi], bf[fj], acc[fi][fj], 0, 0, 0);
        __builtin_amdgcn_s_setprio(0);
        pipe_endbar();
    }
    float* Ob = OUT + bb * 524288;
    const float* Xb = X + bb * 524288;
    const u16* PLb = PSL + bb * 1048576 + 524288;   // PL rows [512,1024)
    #pragma unroll
    for (int fi = 0; fi < 4; ++fi) {
        const int i = i0 + wi + fi * 16 + lg * 4;
        #pragma unroll
        for (int fj = 0; fj < 4; ++fj) {
            const int j = j0 + wj + fj * 16 + lr;
            const long a = (long)j * 1024 + i;
            f32x4 d = acc[fi][fj];
            const float bj = b2[j];
            f32x4 xv = *(const f32x4*)(Xb + a);
            s16x4 pl4 = *(const s16x4*)(PLb + a);
            f32x4 o;
            o[0] = d[0] + bj + xv[0] + bf2f((u16)pl4[0]);
            o[1] = d[1] + bj + xv[1] + bf2f((u16)pl4[1]);
            o[2] = d[2] + bj + xv[2] + bf2f((u16)pl4[2]);
            o[3] = d[3] + bj + xv[3] + bf2f((u16)pl4[3]);
            *(f32x4*)(Ob + a) = o;
        }
    }
}

// ================= build wavelet operator MS (one block per identity column) =================
__global__ __launch_bounds__(256) void build_M_k(u16* __restrict__ MS)
{
    __shared__ float a1[515], d1[515], a2[261], d2[261], sa1[515];
    const int r = blockIdx.x;
    const int t = threadIdx.x;
    for (int m = t; m < 515; m += 256) {
        float sa = 0.f, sd = 0.f;
        #pragma unroll
        for (int j = 0; j < 8; ++j) {
            int tt = 2 * m + 1 - j;
            tt = (tt < 0) ? (-tt - 1) : tt;
            tt = (tt >= 1024) ? (2047 - tt) : tt;
            if (tt == r) { sa += c_lo[j]; sd += c_hi[j]; }
        }
        a1[m] = sa; d1[m] = sd;
    }
    __syncthreads();
    for (int m = t; m < 261; m += 256) {
        float sa = 0.f, sd = 0.f;
        #pragma unroll
        for (int j = 0; j < 8; ++j) {
            int tt = 2 * m + 1 - j;
            tt = (tt < 0) ? (-tt - 1) : tt;
            tt = (tt >= 515) ? (1029 - tt) : tt;
            float v = a1[tt];
            sa += v * c_lo[j]; sd += v * c_hi[j];
        }
        a2[m] = sa; d2[m] = sd;
    }
    __syncthreads();
    for (int m = t; m < 515; m += 256) {
        float ss = 0.f;
        #pragma unroll
        for (int k = 0; k < 8; ++k) {
            int tt = m + k - 1;
            if (tt & 1) continue;
            int j = tt >> 1;
            if (j < 0 || j >= 261) continue;
            ss += c_hi[k] * d2[j];
        }
        sa1[m] = ss;
    }
    __syncthreads();
    for (int n = t; n < 1024; n += 256) {
        float ss = 0.f;
        #pragma unroll
        for (int k = 0; k < 8; ++k) {
            int tt = n + k - 1;
            if (tt & 1) continue;
            int j = tt >> 1;
            if (j < 0 || j >= 515) continue;
            ss += c_lo[k] * sa1[j] + c_hi[k] * d1[j];
        }
        MS[(long)n * 1024 + r] = f2bf(ss);
    }
}

// ================= packing / small kernels =================
__global__ __launch_bounds__(256) void pack_weights_k(
    const float* __restrict__ wi,
    const float* __restrict__ b1, const float* __restrict__ b2_,
    const float* __restrict__ b3, const float* __restrict__ b4,
    u16* __restrict__ Wi, u16* __restrict__ Wp)
{
    int i = blockIdx.x * 256 + threadIdx.x;
    if (i < 262144) Wi[i] = f2bf(wi[i]);
    if (i < 393216) {
        int base, taps;
        const float* s;
        if (i < 49152)       { base = 0;      taps = 3; s = b1; }
        else if (i < 131072) { base = 49152;  taps = 5; s = b2_; }
        else if (i < 245760) { base = 131072; taps = 7; s = b3; }
        else                 { base = 245760; taps = 9; s = b4; }
        int rem = i - base;
        int stride = taps * 128;
        int co = rem / stride;
        int r2 = rem - co * stride;
        int tap = r2 >> 7, ci = r2 & 127;
        Wp[i] = f2bf(s[(long)(co * 128 + ci) * taps + tap]);
    }
}

__global__ __launch_bounds__(256) void make_Ucum_k(
    const float* __restrict__ wf, const float* __restrict__ wp,
    u16* __restrict__ UDUL)
{
    int gid = blockIdx.x * 256 + threadIdx.x;   // 512*128
    int co = gid >> 7, cc = gid & 127;
    float us[4], ul[4];
    #pragma unroll
    for (int b = 0; b < 4; ++b) {
        float s = 0.f, t = 0.f;
        for (int q = 0; q < 128; ++q) {
            float f = wf[(long)co * 512 + b * 128 + q];
            s += f * wp[q * 256 + cc];
            t += f * wp[q * 256 + 128 + cc];
        }
        us[b] = s; ul[b] = t;
    }
    float suf[4], pre[4];
    float acc = 0.f;
    for (int b = 3; b >= 0; --b) { acc += us[b]; suf[b] = acc; }
    acc = 0.f;
    for (int b = 0; b < 4; ++b) { acc += ul[b]; pre[b] = acc; }
    #pragma unroll
    for (int b = 0; b < 4; ++b) {
        UDUL[(long)co * 512 + b * 128 + cc]         = f2bf(suf[b] - pre[b]);
        UDUL[(long)(512 + co) * 512 + b * 128 + cc] = f2bf(pre[b]);
    }
}

__global__ __launch_bounds__(256) void make_bias2_k(
    const float* __restrict__ wf, const float* __restrict__ bpf,
    const float* __restrict__ bfus, float* __restrict__ b2)
{
    int co = blockIdx.x * 256 + threadIdx.x;
    if (co >= 512) return;
    float s = bfus[co];
    for (int j = 0; j < 512; ++j) s += wf[(long)co * 512 + j] * bpf[j & 127];
    b2[co] = s;
}

__global__ __launch_bounds__(256) void zero_k(float* __restrict__ p, int n)
{
    int i = blockIdx.x * 256 + threadIdx.x;
    if (i < n) p[i] = 0.f;
}

// ---------------- transpose: xcl[bb][n][c] = bf16(x[bb][c][n]) ----------------
__global__ __launch_bounds__(256) void trX_k(const float* __restrict__ x, u16* __restrict__ xcl)
{
    __shared__ float sh[32][33];
    const int n0 = blockIdx.x * 32, c0 = blockIdx.y * 32;
    const long bb = blockIdx.z;
    const int tx = threadIdx.x, ty = threadIdx.y;
    const float* xb = x + bb * 524288;
    u16* ob = xcl + bb * 524288;
    #pragma unroll
    for (int k = 0; k < 4; ++k)
        sh[ty + 8 * k][tx] = xb[(long)(c0 + ty + 8 * k) * 1024 + n0 + tx];
    __syncthreads();
    #pragma unroll
    for (int k = 0; k < 4; ++k)
        ob[(long)(n0 + ty + 8 * k) * 512 + c0 + tx] = f2bf(sh[tx][ty + 8 * k]);
}

// ---------------- BN ----------------
// one block per channel: tree-reduce 512 partials
__global__ __launch_bounds__(256) void bn_coef_k(
    const float* __restrict__ part, PtrQuad g, PtrQuad be, float* __restrict__ scsh)
{
    __shared__ float rs[256], rq[256];
    int c = blockIdx.x;              // 0..511
    int br = c >> 7, cc = c & 127;
    const float* pb = part + (long)br * 131072;   // 512 blocks * 256
    int t = threadIdx.x;
    float s = pb[(2 * t) * 256 + cc]       + pb[(2 * t + 1) * 256 + cc];
    float q = pb[(2 * t) * 256 + 128 + cc] + pb[(2 * t + 1) * 256 + 128 + cc];
    rs[t] = s; rq[t] = q;
    __syncthreads();
    for (int off = 128; off > 0; off >>= 1) {
        if (t < off) { rs[t] += rs[t + off]; rq[t] += rq[t + off]; }
        __syncthreads();
    }
    if (t == 0) {
        float mu = rs[0] * (1.0f / 65536.0f);
        float var = rq[0] * (1.0f / 65536.0f) - mu * mu;
        float sc = g.p[br][cc] * rsqrtf(var + 1e-5f);
        scsh[c] = sc;
        scsh[512 + c] = be.p[br][cc] - mu * sc;
    }
}

__global__ __launch_bounds__(256) void bn_apply_k(
    u16* __restrict__ Y, const float* __restrict__ scsh)
{
    __shared__ float sc_[512];
    __shared__ float sh_[512];
    const int t = threadIdx.x;
    #pragma unroll
    for (int q = 0; q < 2; ++q) {
        sc_[t + q * 256] = scsh[t + q * 256];
        sh_[t + q * 256] = scsh[512 + t + q * 256];
    }
    __syncthreads();
    long gid = (long)blockIdx.x * 256 + t;
    long r = gid >> 6; int cg = (int)(gid & 63);
    u16* p = Y + r * 512 + cg * 8;
    s16x8 v = *(const s16x8*)p;
    #pragma unroll
    for (int e = 0; e < 8; ++e) {
        int c = cg * 8 + e;
        float f = bf2f((u16)v[e]) * sc_[c] + sh_[c];
        v[e] = (short)f2bf(f > 0.f ? f : 0.f);
    }
    *(s16x8*)p = v;
}

// =====================================================================
extern "C" void kernel_launch(void* const* d_in, const int* in_sizes, int n_in,
                              void* d_out, int out_size, void* d_ws, size_t ws_size,
                              hipStream_t stream)
{
    const float* x      = (const float*)d_in[0];
    const float* w_init = (const float*)d_in[1];
    const float* b_init = (const float*)d_in[2];
    const float* w_pf   = (const float*)d_in[3];
    const float* b_pf   = (const float*)d_in[4];
    const float* w_fus  = (const float*)d_in[5];
    const float* b_fus  = (const float*)d_in[6];
    const float *w_b[4];
    PtrQuad g, be;
    for (int i = 0; i < 4; ++i) {
        w_b[i]  = (const float*)d_in[7 + 4 * i];
        g.p[i]  = (const float*)d_in[9 + 4 * i];
        be.p[i] = (const float*)d_in[10 + 4 * i];
    }
    float* outf = (float*)d_out;

    char* p = (char*)d_ws;
    u16* xcl   = (u16*)p;  p += 67108864;
    u16* h     = (u16*)p;  p += 67108864;
    u16* Y     = (u16*)p;  p += 67108864;
    u16* PSL   = (u16*)p;  p += 134217728;
    u16* Wi    = (u16*)p;  p += 524288;
    u16* Wp    = (u16*)p;  p += 786432;
    u16* UDUL  = (u16*)p;  p += 1048576;
    u16* MrowS = (u16*)p;  p += 2097152;
    float* b2  = (float*)p; p += 2048;
    float* zbuf= (float*)p; p += 256;     // 64 floats, zeroed each launch
    float* scsh= (float*)p; p += 4096;
    float* part= (float*)p; p += 2097152; // 2048 blocks * 256 floats

    // ---- prologue: weights / operators ----
    pack_weights_k<<<1536, 256, 0, stream>>>(w_init, w_b[0], w_b[1], w_b[2], w_b[3], Wi, Wp);
    make_Ucum_k<<<256, 256, 0, stream>>>(w_fus, w_pf, UDUL);
    make_bias2_k<<<2, 256, 0, stream>>>(w_fus, b_pf, b_fus, b2);
    build_M_k<<<1024, 256, 0, stream>>>(MrowS);
    zero_k<<<1, 256, 0, stream>>>(zbuf, 64);

    // ---- activations: transpose to channel-last bf16 ----
    trX_k<<<dim3(32, 16, 64), dim3(32, 8), 0, stream>>>(x, xcl);

    // ---- conv1x1: h[n][co] = Wi x + b_init ----
    gemm_nt_k<<<dim3(8, 4, 64), 256, 0, stream>>>(Wi, 0, 512, xcl, 524288, 512, 512,
                                                  h, 524288, 512, b_init);

    // ---- branches: chunk-major conv + fused BN partials ----
    gemm_branch4_k<<<dim3(8, 4, 64), 256, 0, stream>>>(Wp, h, Y, (const u16*)zbuf, part);

    // ---- BN coefficients (parallel reduce) + apply (in place) ----
    bn_coef_k<<<512, 256, 0, stream>>>(part, g, be, scsh);
    bn_apply_k<<<16384, 256, 0, stream>>>(Y, scsh);

    // ---- PSL = Ybn . [UD;UL]^T (one launch) ----
    gemm_psl_k<<<dim3(8, 8, 64), 256, 0, stream>>>(Y, UDUL, PSL);

    // ---- out = MS.PD^T + PL + b2 + x ----
    gemm_time_k<<<dim3(4, 8, 64), 256, 0, stream>>>(MrowS, PSL, b2, x, outf);
}